// Round 6
// baseline (955.649 us; speedup 1.0000x reference)
//
#include <hip/hip_runtime.h>
#include <stdint.h>

#define C_DIM 2048
#define H_NUM 16
#define DH    128
#define S_LEN 1024
#define T_LEN 256
#define B_SZ  4
#define L_ROWS 4096   // B*S
#define LY_ROWS 1024  // B*T
#define F_DIM 8192

typedef __attribute__((ext_vector_type(4))) float f32x4;
typedef __attribute__((ext_vector_type(8))) __bf16 bf16x8;
typedef __attribute__((ext_vector_type(4))) unsigned short us4;
typedef __attribute__((ext_vector_type(8))) unsigned short us8;
typedef unsigned short u16;

__device__ __forceinline__ u16 f2bf(float f) {
  union { float f; uint32_t u; } v; v.f = f;
  uint32_t r = v.u + 0x7FFFu + ((v.u >> 16) & 1u);
  return (u16)(r >> 16);
}
__device__ __forceinline__ float bf2f(u16 h) {
  union { uint32_t u; float f; } v; v.u = ((uint32_t)h) << 16;
  return v.f;
}

typedef __attribute__((address_space(1))) void gvoid;
typedef __attribute__((address_space(3))) void lvoid;
__device__ __forceinline__ void gl_lds16(const void* g, void* l) {
  __builtin_amdgcn_global_load_lds((gvoid*)g, (lvoid*)l, 16, 0, 0);
}

template<int N> __device__ __forceinline__ void wait_vmcnt() {
  if constexpr (N == 0) asm volatile("s_waitcnt vmcnt(0)" ::: "memory");
  else if constexpr (N == 5) asm volatile("s_waitcnt vmcnt(5)" ::: "memory");
  else if constexpr (N == 6) asm volatile("s_waitcnt vmcnt(6)" ::: "memory");
}
__device__ __forceinline__ void barrier_raw() {
  asm volatile("s_barrier" ::: "memory");
}
__device__ __forceinline__ void sb0() { __builtin_amdgcn_sched_barrier(0); }

// ---------------- fp32 -> bf16 conversion ----------------
__global__ void k_cvt(const float* __restrict__ src, u16* __restrict__ dst, int n) {
  int i = (blockIdx.x * blockDim.x + threadIdx.x) * 4;
  int stride = gridDim.x * blockDim.x * 4;
  for (; i < n; i += stride) {
    float4 v = *(const float4*)(src + i);
    us4 o;
    o[0] = f2bf(v.x); o[1] = f2bf(v.y); o[2] = f2bf(v.z); o[3] = f2bf(v.w);
    *(us4*)(dst + i) = o;
  }
}

// ---------------- LN + adaLN modulation ----------------
__global__ __launch_bounds__(256)
void k_modln(const float* __restrict__ x, const float* __restrict__ t,
             const float* __restrict__ tab, u16* __restrict__ out,
             int scale_idx, int shift_idx) {
  int row = blockIdx.x;
  int tid = threadIdx.x;
  const float* xr = x + (size_t)row * C_DIM;
  int c0 = tid * 8;
  float4 a = *(const float4*)(xr + c0);
  float4 b = *(const float4*)(xr + c0 + 4);
  float v[8] = {a.x, a.y, a.z, a.w, b.x, b.y, b.z, b.w};
  float s = 0.f, ss = 0.f;
#pragma unroll
  for (int j = 0; j < 8; ++j) { s += v[j]; ss += v[j] * v[j]; }
#pragma unroll
  for (int m = 1; m < 64; m <<= 1) { s += __shfl_xor(s, m); ss += __shfl_xor(ss, m); }
  __shared__ float red[8];
  int wid = tid >> 6;
  if ((tid & 63) == 0) { red[wid * 2] = s; red[wid * 2 + 1] = ss; }
  __syncthreads();
  s  = red[0] + red[2] + red[4] + red[6];
  ss = red[1] + red[3] + red[5] + red[7];
  float mean = s * (1.f / C_DIM);
  float var  = ss * (1.f / C_DIM) - mean * mean;
  float rstd = rsqrtf(var + 1e-6f);
  const float* trow = t + (size_t)row * (6 * C_DIM);
  const float* tsc = trow + scale_idx * C_DIM + c0;
  const float* tsh = trow + shift_idx * C_DIM + c0;
  const float* gsc = tab + scale_idx * C_DIM + c0;
  const float* gsh = tab + shift_idx * C_DIM + c0;
  us8 o;
#pragma unroll
  for (int j = 0; j < 8; ++j) {
    float scv = 1.f + gsc[j] + tsc[j];
    float shv = gsh[j] + tsh[j];
    o[j] = f2bf((v[j] - mean) * rstd * scv + shv);
  }
  *(us8*)(out + (size_t)row * C_DIM + c0) = o;
}

// ======== GEMM v4: 128x256 tile, BK=64, register-pipelined, 2 barriers/tile ==
// out = A[M,K](lda) @ W[N,K](ldw)^T (+epilogue). 512 thr = 8 waves (2M x 4N).
// 3-bit LDS slot swizzle (verified conflict-free R5). Compiler emits counted
// lgkmcnt waits; sched_barrier(0) pins issue clusters (no manual lgkm0 —
// R5's forced lgkm(0)+4 barriers/tile exposed ds latency every phase).
// Per tile: [G1 aLow+b0 | stage A1(kt+1) | G2 b1] P1 | [G3 aHigh] P2 |
// barrier | [stage B0,B1,A0(kt+2)] P3 P4 | vmcnt(5) barrier.
// Hazards: stages to parity-p regions (B[p], A[p]low) issue only after the
// mid barrier which post-dates all waves' reads of them; A[p]high never
// written during even-distance tiles. Distance-2 ledger: VMN = 4+ACALLS = 5.
template<int BM, int EPI>
__global__ __launch_bounds__(512, 2)
void k_gemm4(const u16* __restrict__ A, const u16* __restrict__ W,
             const float* __restrict__ bias0, const float* __restrict__ bias1,
             const float* __restrict__ bias2,
             u16* __restrict__ o0, u16* __restrict__ o1, u16* __restrict__ o2,
             int sec_shift, int out_ld,
             float* __restrict__ outF, const float* __restrict__ resid,
             const float* __restrict__ gate_t, const float* __restrict__ gate_tab,
             const float* __restrict__ partial,
             int M, int N, int K, int lda, int ldw, int nbx) {
  constexpr int HTA = (BM / 2) * 64;
  constexpr int HTB = 128 * 64;
  constexpr int ACALLS = BM / 128;
  constexpr int QM = BM / 64;
  constexpr int MFR = BM / 32;
  constexpr int VMN = 4 + ACALLS;
  constexpr int BOFF = 4 * HTA;
  __shared__ __align__(16) u16 lds[BOFF + 4 * HTB];

  int tid = threadIdx.x;
  int nwg = gridDim.x;
  int q8 = nwg >> 3, r8 = nwg & 7;
  int xcd = blockIdx.x & 7, local = blockIdx.x >> 3;
  int wgid = (xcd < r8 ? xcd * (q8 + 1) : r8 * (q8 + 1) + (xcd - r8) * q8) + local;
  int bx = wgid % nbx, by = wgid / nbx;
  int m0 = by * BM, n0 = bx * 256;

  int wid = tid >> 6, lane = tid & 63;
  int wm = wid >> 2, wn = wid & 3;
  int lr = lane & 15, lg = lane >> 4;
  int xorslot = lr & 7;
  int bcol = (wn & 1) * 64;

  int srow = tid >> 3;
  int scol = ((tid ^ (tid >> 3)) & 7) * 8;

  auto stA = [&](int h, int kt2) {
    int pt = kt2 & 1;
    u16* dst = lds + (pt * 2 + h) * HTA + tid * 8;
#pragma unroll
    for (int call = 0; call < ACALLS; ++call) {
      int grow = m0 + h * (BM / 2) + call * 64 + srow;
      gl_lds16(A + (size_t)grow * lda + kt2 * 64 + scol, dst + call * 4096);
    }
  };
  auto stB = [&](int h, int kt2) {
    int pt = kt2 & 1;
    u16* dst = lds + BOFF + (pt * 2 + h) * HTB + tid * 8;
#pragma unroll
    for (int call = 0; call < 2; ++call) {
      int grow = n0 + h * 128 + call * 64 + srow;
      gl_lds16(W + (size_t)grow * ldw + kt2 * 64 + scol, dst + call * 4096);
    }
  };

  f32x4 zero4 = {0.f, 0.f, 0.f, 0.f};
  f32x4 acc[MFR][4];
#pragma unroll
  for (int m = 0; m < MFR; ++m)
#pragma unroll
    for (int n = 0; n < 4; ++n) acc[m][n] = zero4;

  int NT2 = K >> 6;
  stA(0, 0); stA(1, 0); stB(0, 0); stB(1, 0);
  stB(0, 1); stB(1, 1); stA(0, 1);
  wait_vmcnt<VMN>();
  barrier_raw();

  for (int kt = 0; kt < NT2; ++kt) {
    int p = kt & 1;
    const u16* Ah = lds + (p * 2 + wm) * HTA;
    const u16* Bh = lds + BOFF + (p * 2 + (wn >> 1)) * HTB;
    bf16x8 aL[QM][2], aH[QM][2], b0[2][2], b1[2][2];
    bool st1 = (kt + 1) < NT2, st2 = (kt + 2) < NT2;

    // G1: aLow + b0
#pragma unroll
    for (int m = 0; m < QM; ++m) {
      int r = m * 16 + lr;
#pragma unroll
      for (int kk = 0; kk < 2; ++kk)
        aL[m][kk] = *(const bf16x8*)(Ah + r * 64 + (((kk << 2) | lg) ^ xorslot) * 8);
    }
#pragma unroll
    for (int n = 0; n < 2; ++n) {
      int r = bcol + n * 16 + lr;
#pragma unroll
      for (int kk = 0; kk < 2; ++kk)
        b0[n][kk] = *(const bf16x8*)(Bh + r * 64 + (((kk << 2) | lg) ^ xorslot) * 8);
    }
    if (st1) stA(1, kt + 1);
    // G2: b1
#pragma unroll
    for (int n = 0; n < 2; ++n) {
      int r = bcol + 32 + n * 16 + lr;
#pragma unroll
      for (int kk = 0; kk < 2; ++kk)
        b1[n][kk] = *(const bf16x8*)(Bh + r * 64 + (((kk << 2) | lg) ^ xorslot) * 8);
    }
    sb0();
    // P1: aLow x b0  (compiler waits lgkmcnt(G2-outstanding))
    __builtin_amdgcn_s_setprio(1);
#pragma unroll
    for (int kk = 0; kk < 2; ++kk)
#pragma unroll
      for (int m = 0; m < QM; ++m)
#pragma unroll
        for (int n = 0; n < 2; ++n)
          acc[m][n] = __builtin_amdgcn_mfma_f32_16x16x32_bf16(aL[m][kk], b0[n][kk], acc[m][n], 0, 0, 0);
    __builtin_amdgcn_s_setprio(0);
    sb0();
    // G3: aHigh
#pragma unroll
    for (int m = 0; m < QM; ++m) {
      int r = (BM / 4) + m * 16 + lr;
#pragma unroll
      for (int kk = 0; kk < 2; ++kk)
        aH[m][kk] = *(const bf16x8*)(Ah + r * 64 + (((kk << 2) | lg) ^ xorslot) * 8);
    }
    sb0();
    // P2: aLow x b1
    __builtin_amdgcn_s_setprio(1);
#pragma unroll
    for (int kk = 0; kk < 2; ++kk)
#pragma unroll
      for (int m = 0; m < QM; ++m)
#pragma unroll
        for (int n = 0; n < 2; ++n)
          acc[m][2 + n] = __builtin_amdgcn_mfma_f32_16x16x32_bf16(aL[m][kk], b1[n][kk], acc[m][2 + n], 0, 0, 0);
    __builtin_amdgcn_s_setprio(0);
    barrier_raw();   // all waves done reading B[p] and A[p]low
    if (st2) { stB(0, kt + 2); stB(1, kt + 2); stA(0, kt + 2); }
    sb0();
    // P3 + P4: aHigh x b1, aHigh x b0
    __builtin_amdgcn_s_setprio(1);
#pragma unroll
    for (int kk = 0; kk < 2; ++kk)
#pragma unroll
      for (int m = 0; m < QM; ++m)
#pragma unroll
        for (int n = 0; n < 2; ++n)
          acc[QM + m][2 + n] = __builtin_amdgcn_mfma_f32_16x16x32_bf16(aH[m][kk], b1[n][kk], acc[QM + m][2 + n], 0, 0, 0);
#pragma unroll
    for (int kk = 0; kk < 2; ++kk)
#pragma unroll
      for (int m = 0; m < QM; ++m)
#pragma unroll
        for (int n = 0; n < 2; ++n)
          acc[QM + m][n] = __builtin_amdgcn_mfma_f32_16x16x32_bf16(aH[m][kk], b0[n][kk], acc[QM + m][n], 0, 0, 0);
    __builtin_amdgcn_s_setprio(0);
    if (st2) wait_vmcnt<VMN>(); else wait_vmcnt<0>();
    barrier_raw();
  }

  // ---- epilogue ----
#pragma unroll
  for (int mf = 0; mf < MFR; ++mf) {
    int row0 = m0 + wm * (BM / 2) + mf * 16 + lg * 4;
#pragma unroll
    for (int nf = 0; nf < 4; ++nf) {
      int col = n0 + wn * 64 + nf * 16 + lr;
      if constexpr (EPI == 0) {
        int sec = col >> sec_shift;
        const float* bp = sec == 0 ? bias0 : (sec == 1 ? bias1 : bias2);
        u16* op = sec == 0 ? o0 : (sec == 1 ? o1 : o2);
        int cs = col & ((1 << sec_shift) - 1);
        float bv = bp[cs];
#pragma unroll
        for (int r = 0; r < 4; ++r)
          op[(size_t)(row0 + r) * out_ld + cs] = f2bf(acc[mf][nf][r] + bv);
      } else if constexpr (EPI == 1) {
        float bv = bias0[col];
#pragma unroll
        for (int r = 0; r < 4; ++r) {
          float val = acc[mf][nf][r] + bv;
          float x3 = val * val * val;
          float g = 0.5f * val * (1.f + tanhf(0.7978845608f * (val + 0.044715f * x3)));
          o0[(size_t)(row0 + r) * out_ld + col] = f2bf(g);
        }
      } else if constexpr (EPI == 2) {
        float bv = bias0[col];
        float gt = gate_tab[col];
#pragma unroll
        for (int r = 0; r < 4; ++r) {
          int row = row0 + r;
          size_t idx = (size_t)row * N + col;
          float g = gt + gate_t[(size_t)row * (6 * C_DIM) + col];
          float o = resid[idx] + g * (acc[mf][nf][r] + bv);
          outF[idx] = o;
          if (o0) o0[idx] = f2bf(o);
        }
      } else if constexpr (EPI == 3) {
        float bv = bias0[col];
#pragma unroll
        for (int r = 0; r < 4; ++r) {
          size_t idx = (size_t)(row0 + r) * N + col;
          outF[idx] = resid[idx] + (acc[mf][nf][r] + bv);
        }
      } else if constexpr (EPI == 4) {
#pragma unroll
        for (int r = 0; r < 4; ++r)
          outF[(size_t)(row0 + r) * N + col] = acc[mf][nf][r];
      } else {  // EPI == 5: split-K finish + gate residual
        float bv = bias0[col];
        float gt = gate_tab[col];
#pragma unroll
        for (int r = 0; r < 4; ++r) {
          int row = row0 + r;
          size_t idx = (size_t)row * N + col;
          float val = acc[mf][nf][r] + partial[idx] + bv;
          float g = gt + gate_t[(size_t)row * (6 * C_DIM) + col];
          outF[idx] = resid[idx] + g * val;
        }
      }
    }
  }
}

// ---------------- RoPE on q and k (in place, bf16) ----------------
__global__ void k_rope(u16* __restrict__ q, u16* __restrict__ k,
                       const float* __restrict__ freqs) {
  int idx = blockIdx.x * blockDim.x + threadIdx.x;
  int total = L_ROWS * C_DIM / 8;
  for (; idx < total; idx += gridDim.x * blockDim.x) {
    int e = idx * 8;
    int row = e >> 11;
    int col = e & (C_DIM - 1);
    int s = row & (S_LEN - 1);
    int i0 = (col & (DH - 1)) >> 1;
    float4 fr = *(const float4*)(freqs + s * (DH / 2) + i0);
    float cs[4], sn[4];
    float fv[4] = {fr.x, fr.y, fr.z, fr.w};
#pragma unroll
    for (int j = 0; j < 4; ++j) sincosf(fv[j], &sn[j], &cs[j]);
    us8 qa = *(us8*)(q + e);
    us8 ka = *(us8*)(k + e);
#pragma unroll
    for (int p = 0; p < 4; ++p) {
      float a = bf2f(qa[2 * p]), b = bf2f(qa[2 * p + 1]);
      qa[2 * p]     = f2bf(a * cs[p] - b * sn[p]);
      qa[2 * p + 1] = f2bf(a * sn[p] + b * cs[p]);
      float a2 = bf2f(ka[2 * p]), b2 = bf2f(ka[2 * p + 1]);
      ka[2 * p]     = f2bf(a2 * cs[p] - b2 * sn[p]);
      ka[2 * p + 1] = f2bf(a2 * sn[p] + b2 * cs[p]);
    }
    *(us8*)(q + e) = qa;
    *(us8*)(k + e) = ka;
  }
}

// ---------------- V transpose: [b*Lkv+kv][h*DH+d] -> [bh][d][kv] ----------------
__global__ void k_transpose_v(const u16* __restrict__ v, u16* __restrict__ vt, int Lkv) {
  __shared__ u16 tile[32][33];
  int bh = blockIdx.x, b = bh >> 4, h = bh & 15;
  int k0 = blockIdx.y * 32, d0 = blockIdx.z * 32;
  int tx = threadIdx.x, ty = threadIdx.y;
  const u16* src = v + (size_t)(b * Lkv) * C_DIM + h * DH;
#pragma unroll
  for (int j = 0; j < 32; j += 8)
    tile[ty + j][tx] = src[(size_t)(k0 + ty + j) * C_DIM + d0 + tx];
  __syncthreads();
  u16* dst = vt + (size_t)bh * DH * Lkv;
#pragma unroll
  for (int j = 0; j < 32; j += 8)
    dst[(size_t)(d0 + ty + j) * Lkv + k0 + tx] = tile[tx][ty + j];
}

// ---------------- flash attention ----------------
__global__ __launch_bounds__(256)
void k_flash(const u16* __restrict__ Q, const u16* __restrict__ K,
             const u16* __restrict__ Vt, u16* __restrict__ O,
             int Lq, int Lkv, float scale) {
  __shared__ __align__(16) u16 lK[64 * 128];
  __shared__ __align__(16) u16 lV[128 * 64];
  __shared__ __align__(16) u16 lP[4][16 * 72];
  int bh = blockIdx.x, b = bh >> 4, h = bh & 15;
  int tid = threadIdx.x, wid = tid >> 6, lane = tid & 63;
  int lr = lane & 15, lg = lane >> 4;
  int q0 = blockIdx.y * 64 + wid * 16;
  const u16* Qb = Q + ((size_t)(b * Lq) + q0) * C_DIM + h * DH;
  const u16* Kb = K + (size_t)(b * Lkv) * C_DIM + h * DH;
  const u16* Vb = Vt + (size_t)bh * DH * Lkv;

  bf16x8 qf[4];
#pragma unroll
  for (int ks = 0; ks < 4; ++ks)
    qf[ks] = *(const bf16x8*)(Qb + (size_t)lr * C_DIM + ks * 32 + lg * 8);

  f32x4 zero4 = {0.f, 0.f, 0.f, 0.f};
  f32x4 o[8];
#pragma unroll
  for (int n = 0; n < 8; ++n) o[n] = zero4;
  float mrow[4] = {-3.0e38f, -3.0e38f, -3.0e38f, -3.0e38f};
  float lrow[4] = {0.f, 0.f, 0.f, 0.f};

  int nsteps = Lkv >> 6;
  for (int kt = 0; kt < nsteps; ++kt) {
#pragma unroll
    for (int i = 0; i < 4; ++i) {
      int flat = i * 4096 + tid * 16;
      int key = flat >> 8, inner = flat & 255;
      int ksrc = inner ^ ((key & 7) << 4);
      gl_lds16((const char*)Kb + ((size_t)(kt * 64 + key) * C_DIM) * 2 + ksrc, (char*)lK + flat);
      int d = flat >> 7, keyb = flat & 127;
      int vsrc = keyb ^ ((d & 7) << 4);
      gl_lds16((const char*)Vb + ((size_t)d * Lkv) * 2 + kt * 128 + vsrc, (char*)lV + flat);
    }
    __syncthreads();

    f32x4 sc[4];
#pragma unroll
    for (int c = 0; c < 4; ++c) sc[c] = zero4;
#pragma unroll
    for (int c = 0; c < 4; ++c) {
      int key = c * 16 + lr;
#pragma unroll
      for (int ks = 0; ks < 4; ++ks) {
        int off = (ks * 64 + lg * 16) ^ ((key & 7) << 4);
        bf16x8 kf = *(const bf16x8*)((const char*)lK + key * 256 + off);
        sc[c] = __builtin_amdgcn_mfma_f32_16x16x32_bf16(qf[ks], kf, sc[c], 0, 0, 0);
      }
    }
#pragma unroll
    for (int r = 0; r < 4; ++r) {
      float s0 = sc[0][r] * scale, s1 = sc[1][r] * scale;
      float s2 = sc[2][r] * scale, s3 = sc[3][r] * scale;
      float mx = fmaxf(fmaxf(s0, s1), fmaxf(s2, s3));
#pragma unroll
      for (int m = 1; m < 16; m <<= 1) mx = fmaxf(mx, __shfl_xor(mx, m));
      float mnew = fmaxf(mrow[r], mx);
      float alpha = exp2f((mrow[r] - mnew) * 1.44269504f);
      mrow[r] = mnew;
      float p0 = exp2f((s0 - mnew) * 1.44269504f);
      float p1 = exp2f((s1 - mnew) * 1.44269504f);
      float p2 = exp2f((s2 - mnew) * 1.44269504f);
      float p3 = exp2f((s3 - mnew) * 1.44269504f);
      float psum = p0 + p1 + p2 + p3;
#pragma unroll
      for (int m = 1; m < 16; m <<= 1) psum += __shfl_xor(psum, m);
      lrow[r] = lrow[r] * alpha + psum;
#pragma unroll
      for (int n = 0; n < 8; ++n) o[n][r] *= alpha;
      u16* pr = lP[wid] + (4 * lg + r) * 72;
      pr[lr]      = f2bf(p0);
      pr[16 + lr] = f2bf(p1);
      pr[32 + lr] = f2bf(p2);
      pr[48 + lr] = f2bf(p3);
    }
    asm volatile("s_waitcnt lgkmcnt(0)" ::: "memory");
    __builtin_amdgcn_sched_barrier(0);
#pragma unroll
    for (int half = 0; half < 2; ++half) {
      bf16x8 pf = *(const bf16x8*)(lP[wid] + lr * 72 + half * 32 + lg * 8);
#pragma unroll
      for (int n = 0; n < 8; ++n) {
        int d = n * 16 + lr;
        int off = (half * 64 + lg * 16) ^ ((d & 7) << 4);
        bf16x8 vf = *(const bf16x8*)((const char*)lV + d * 128 + off);
        o[n] = __builtin_amdgcn_mfma_f32_16x16x32_bf16(pf, vf, o[n], 0, 0, 0);
      }
    }
    __syncthreads();
  }

  u16* Ob = O + ((size_t)(b * Lq) + q0) * C_DIM + h * DH;
#pragma unroll
  for (int n = 0; n < 8; ++n) {
    int d = n * 16 + lr;
#pragma unroll
    for (int r = 0; r < 4; ++r) {
      int qr = 4 * lg + r;
      Ob[(size_t)qr * C_DIM + d] = f2bf(o[n][r] / lrow[r]);
    }
  }
}

// ---------------- host ----------------
extern "C" void kernel_launch(void* const* d_in, const int* in_sizes, int n_in,
                              void* d_out, int out_size, void* d_ws, size_t ws_size,
                              hipStream_t stream) {
  const float* x     = (const float*)d_in[0];
  const float* y     = (const float*)d_in[1];
  const float* t     = (const float*)d_in[2];
  const float* freqs = (const float*)d_in[3];
  const float* tab   = (const float*)d_in[4];
  const float* Wq_s = (const float*)d_in[5];
  const float* bq_s = (const float*)d_in[6];
  const float* Wk_s = (const float*)d_in[7];
  const float* bk_s = (const float*)d_in[8];
  const float* Wv_s = (const float*)d_in[9];
  const float* bv_s = (const float*)d_in[10];
  const float* Wo_s = (const float*)d_in[11];
  const float* bo_s = (const float*)d_in[12];
  const float* Wq_c = (const float*)d_in[13];
  const float* bq_c = (const float*)d_in[14];
  const float* Wk_c = (const float*)d_in[15];
  const float* bk_c = (const float*)d_in[16];
  const float* Wv_c = (const float*)d_in[17];
  const float* bv_c = (const float*)d_in[18];
  const float* Wo_c = (const float*)d_in[19];
  const float* bo_c = (const float*)d_in[20];
  const float* W_fc1 = (const float*)d_in[21];
  const float* b_fc1 = (const float*)d_in[22];
  const float* W_fc2 = (const float*)d_in[23];
  const float* b_fc2 = (const float*)d_in[24];

  const size_t SZ_CC  = (size_t)C_DIM * C_DIM * 2;
  const size_t SZ_FC  = (size_t)F_DIM * C_DIM * 2;
  const size_t SZ_LC  = (size_t)L_ROWS * C_DIM * 2;
  const size_t SZ_YC  = (size_t)LY_ROWS * C_DIM * 2;
  char* ws = (char*)d_ws;
  size_t off = 0;
  u16* wq_s = (u16*)(ws + off); off += SZ_CC;   // wq_s..wv_s contiguous = QKV concat
  u16* wk_s = (u16*)(ws + off); off += SZ_CC;
  u16* wv_s = (u16*)(ws + off); off += SZ_CC;
  u16* wo_s = (u16*)(ws + off); off += SZ_CC;
  u16* wq_c = (u16*)(ws + off); off += SZ_CC;
  u16* wk_c = (u16*)(ws + off); off += SZ_CC;   // wk_c,wv_c contiguous = KV concat
  u16* wv_c = (u16*)(ws + off); off += SZ_CC;
  u16* wo_c = (u16*)(ws + off); off += SZ_CC;
  u16* wfc1 = (u16*)(ws + off); off += SZ_FC;
  u16* wfc2 = (u16*)(ws + off); off += SZ_FC;
  u16* ybf  = (u16*)(ws + off); off += SZ_YC;
  u16* xm   = (u16*)(ws + off); off += SZ_LC;
  u16* qb   = (u16*)(ws + off); off += SZ_LC;
  u16* kb   = (u16*)(ws + off); off += SZ_LC;
  u16* vb   = (u16*)(ws + off); off += SZ_LC;
  u16* ao   = (u16*)(ws + off); off += SZ_LC;
  u16* hbuf = qb;                               // [L, F] bf16 overlay (qb..ao)
  float* x1 = (float*)(ws + off); off += (size_t)L_ROWS * C_DIM * 4;
  u16* x1bf = (u16*)(ws + off); off += SZ_LC;
  u16* kc   = (u16*)(ws + off); off += SZ_YC;
  u16* vc   = (u16*)(ws + off); off += SZ_YC;
  u16* vt   = (u16*)(ws + off); off += SZ_LC;
  u16* vtc  = (u16*)(ws + off); off += SZ_YC;
  float* part = (float*)x1bf;   // fc2 split-K partial overlays dead x1bf..vtc
  if (ws_size < off) return;

  auto cvt = [&](const float* s, u16* d, int n) {
    int blocks = (n / 4 + 255) / 256; if (blocks > 4096) blocks = 4096;
    k_cvt<<<blocks, 256, 0, stream>>>(s, d, n);
  };
  cvt(Wq_s, wq_s, C_DIM * C_DIM);
  cvt(Wk_s, wk_s, C_DIM * C_DIM);
  cvt(Wv_s, wv_s, C_DIM * C_DIM);
  cvt(Wo_s, wo_s, C_DIM * C_DIM);
  cvt(Wq_c, wq_c, C_DIM * C_DIM);
  cvt(Wk_c, wk_c, C_DIM * C_DIM);
  cvt(Wv_c, wv_c, C_DIM * C_DIM);
  cvt(Wo_c, wo_c, C_DIM * C_DIM);
  cvt(W_fc1, wfc1, F_DIM * C_DIM);
  cvt(W_fc2, wfc2, F_DIM * C_DIM);
  cvt(y, ybf, LY_ROWS * C_DIM);

  const float ascale = 0.08838834764831845f;

  k_modln<<<L_ROWS, 256, 0, stream>>>(x, t, tab, xm, 1, 0);
  // fused self QKV: N = 6144
  k_gemm4<128, 0><<<32 * 24, 512, 0, stream>>>(
      xm, wq_s, bq_s, bk_s, bv_s, qb, kb, vb, 11, C_DIM,
      nullptr, nullptr, nullptr, nullptr, nullptr, L_ROWS, 6144, C_DIM, C_DIM, C_DIM, 24);
  k_rope<<<2048, 256, 0, stream>>>(qb, kb, freqs);
  k_transpose_v<<<dim3(B_SZ * H_NUM, S_LEN / 32, DH / 32), dim3(32, 8), 0, stream>>>(vb, vt, S_LEN);
  k_flash<<<dim3(B_SZ * H_NUM, S_LEN / 64), 256, 0, stream>>>(qb, kb, vt, ao, S_LEN, S_LEN, ascale);
  // x1 = x + gate_msa*(ao@Wo_s^T+bo_s); bf16 mirror x1bf
  k_gemm4<128, 2><<<32 * 8, 512, 0, stream>>>(
      ao, wo_s, bo_s, nullptr, nullptr, x1bf, nullptr, nullptr, 30, C_DIM,
      x1, x, t + 2 * C_DIM, tab + 2 * C_DIM, nullptr, L_ROWS, C_DIM, C_DIM, C_DIM, C_DIM, 8);
  // cross q
  k_gemm4<128, 0><<<32 * 8, 512, 0, stream>>>(
      x1bf, wq_c, bq_c, nullptr, nullptr, qb, nullptr, nullptr, 30, C_DIM,
      nullptr, nullptr, nullptr, nullptr, nullptr, L_ROWS, C_DIM, C_DIM, C_DIM, C_DIM, 8);
  // fused cross KV: N = 4096
  k_gemm4<128, 0><<<8 * 16, 512, 0, stream>>>(
      ybf, wk_c, bk_c, bv_c, bv_c, kc, vc, vc, 11, C_DIM,
      nullptr, nullptr, nullptr, nullptr, nullptr, LY_ROWS, 4096, C_DIM, C_DIM, C_DIM, 16);
  k_transpose_v<<<dim3(B_SZ * H_NUM, T_LEN / 32, DH / 32), dim3(32, 8), 0, stream>>>(vc, vtc, T_LEN);
  k_flash<<<dim3(B_SZ * H_NUM, S_LEN / 64), 256, 0, stream>>>(qb, kc, vtc, ao, S_LEN, T_LEN, ascale);
  // x1 += ao@Wo_c^T + bo_c
  k_gemm4<128, 3><<<32 * 8, 512, 0, stream>>>(
      ao, wo_c, bo_c, nullptr, nullptr, nullptr, nullptr, nullptr, 30, C_DIM,
      x1, x1, nullptr, nullptr, nullptr, L_ROWS, C_DIM, C_DIM, C_DIM, C_DIM, 8);
  // MLP
  k_modln<<<L_ROWS, 256, 0, stream>>>(x1, t, tab, xm, 4, 3);
  k_gemm4<128, 1><<<32 * 32, 512, 0, stream>>>(
      xm, wfc1, b_fc1, nullptr, nullptr, hbuf, nullptr, nullptr, 30, F_DIM,
      nullptr, nullptr, nullptr, nullptr, nullptr, L_ROWS, F_DIM, C_DIM, C_DIM, C_DIM, 32);
  // fc2 split-K=2: phase 1 -> fp32 partial (k in [0,4096))
  k_gemm4<128, 4><<<32 * 8, 512, 0, stream>>>(
      hbuf, wfc2, nullptr, nullptr, nullptr, nullptr, nullptr, nullptr, 30, C_DIM,
      part, nullptr, nullptr, nullptr, nullptr, L_ROWS, C_DIM, F_DIM / 2, F_DIM, F_DIM, 8);
  // fc2 phase 2: k in [4096,8192) + partial + bias + gate residual -> d_out
  k_gemm4<128, 5><<<32 * 8, 512, 0, stream>>>(
      hbuf + F_DIM / 2, wfc2 + F_DIM / 2, b_fc2, nullptr, nullptr, nullptr, nullptr, nullptr, 30, C_DIM,
      (float*)d_out, x1, t + 5 * C_DIM, tab + 5 * C_DIM, part,
      L_ROWS, C_DIM, F_DIM / 2, F_DIM, F_DIM, 8);
}

// Round 8
// 922.484 us; speedup vs baseline: 1.0360x; 1.0360x over previous
//
#include <hip/hip_runtime.h>
#include <stdint.h>

#define C_DIM 2048
#define H_NUM 16
#define DH    128
#define S_LEN 1024
#define T_LEN 256
#define B_SZ  4
#define L_ROWS 4096   // B*S
#define LY_ROWS 1024  // B*T
#define F_DIM 8192

typedef __attribute__((ext_vector_type(4))) float f32x4;
typedef __attribute__((ext_vector_type(8))) __bf16 bf16x8;
typedef __attribute__((ext_vector_type(4))) unsigned short us4;
typedef __attribute__((ext_vector_type(8))) unsigned short us8;
typedef unsigned short u16;

__device__ __forceinline__ u16 f2bf(float f) {
  union { float f; uint32_t u; } v; v.f = f;
  uint32_t r = v.u + 0x7FFFu + ((v.u >> 16) & 1u);
  return (u16)(r >> 16);
}
__device__ __forceinline__ float bf2f(u16 h) {
  union { uint32_t u; float f; } v; v.u = ((uint32_t)h) << 16;
  return v.f;
}

typedef __attribute__((address_space(1))) void gvoid;
typedef __attribute__((address_space(3))) void lvoid;
__device__ __forceinline__ void gl_lds16(const void* g, void* l) {
  __builtin_amdgcn_global_load_lds((gvoid*)g, (lvoid*)l, 16, 0, 0);
}

template<int N> __device__ __forceinline__ void wait_vmcnt() {
  if constexpr (N == 0) asm volatile("s_waitcnt vmcnt(0)" ::: "memory");
  else if constexpr (N == 4) asm volatile("s_waitcnt vmcnt(4)" ::: "memory");
  else if constexpr (N == 5) asm volatile("s_waitcnt vmcnt(5)" ::: "memory");
  else if constexpr (N == 6) asm volatile("s_waitcnt vmcnt(6)" ::: "memory");
}
__device__ __forceinline__ void barrier_raw() {
  asm volatile("s_barrier" ::: "memory");
}
__device__ __forceinline__ void lgkm0_pin() {
  asm volatile("s_waitcnt lgkmcnt(0)" ::: "memory");
  __builtin_amdgcn_sched_barrier(0);
}

// ---------------- fp32 -> bf16 conversion ----------------
__global__ void k_cvt(const float* __restrict__ src, u16* __restrict__ dst, int n) {
  int i = (blockIdx.x * blockDim.x + threadIdx.x) * 4;
  int stride = gridDim.x * blockDim.x * 4;
  for (; i < n; i += stride) {
    float4 v = *(const float4*)(src + i);
    us4 o;
    o[0] = f2bf(v.x); o[1] = f2bf(v.y); o[2] = f2bf(v.z); o[3] = f2bf(v.w);
    *(us4*)(dst + i) = o;
  }
}

// ---------------- LN + adaLN modulation ----------------
__global__ __launch_bounds__(256)
void k_modln(const float* __restrict__ x, const float* __restrict__ t,
             const float* __restrict__ tab, u16* __restrict__ out,
             int scale_idx, int shift_idx) {
  int row = blockIdx.x;
  int tid = threadIdx.x;
  const float* xr = x + (size_t)row * C_DIM;
  int c0 = tid * 8;
  float4 a = *(const float4*)(xr + c0);
  float4 b = *(const float4*)(xr + c0 + 4);
  float v[8] = {a.x, a.y, a.z, a.w, b.x, b.y, b.z, b.w};
  float s = 0.f, ss = 0.f;
#pragma unroll
  for (int j = 0; j < 8; ++j) { s += v[j]; ss += v[j] * v[j]; }
#pragma unroll
  for (int m = 1; m < 64; m <<= 1) { s += __shfl_xor(s, m); ss += __shfl_xor(ss, m); }
  __shared__ float red[8];
  int wid = tid >> 6;
  if ((tid & 63) == 0) { red[wid * 2] = s; red[wid * 2 + 1] = ss; }
  __syncthreads();
  s  = red[0] + red[2] + red[4] + red[6];
  ss = red[1] + red[3] + red[5] + red[7];
  float mean = s * (1.f / C_DIM);
  float var  = ss * (1.f / C_DIM) - mean * mean;
  float rstd = rsqrtf(var + 1e-6f);
  const float* trow = t + (size_t)row * (6 * C_DIM);
  const float* tsc = trow + scale_idx * C_DIM + c0;
  const float* tsh = trow + shift_idx * C_DIM + c0;
  const float* gsc = tab + scale_idx * C_DIM + c0;
  const float* gsh = tab + shift_idx * C_DIM + c0;
  us8 o;
#pragma unroll
  for (int j = 0; j < 8; ++j) {
    float scv = 1.f + gsc[j] + tsc[j];
    float shv = gsh[j] + tsh[j];
    o[j] = f2bf((v[j] - mean) * rstd * scv + shv);
  }
  *(us8*)(out + (size_t)row * C_DIM + c0) = o;
}

// ======== GEMM v5b: 256x256 tile, BK=64, 2 K-tiles/iter, 8-phase ============
// CORRECTED ledger (R7 bug: A-half h is read in BOTH ph1 (aL) and ph3 (aH)
// by wm=h waves; B-half h in ph1 (b0) and ph2 (b1) => A overwrite >= its
// ph4, B overwrite >= its ph3).
// Stage slots (iter j, t1=2j+1, t2=2j+2, t3=2j+3):
//   ph1: A1h1(t1)  ph2: B1h1(t1)  ph3: B0h0(t2)  ph4: A0h0(t2) + vmcnt(4)
//   ph5: A0h1(t2)  ph6: B0h1(t2)  ph7: B1h0(t3)  ph8: A1h0(t3) + vmcnt(4)
// vmcnt(4)@ph4 retires all 4 buf1-t1 halves (read ph5..ph8); vmcnt(4)@ph8
// retires all 4 buf0-t2 halves (read next ph1..ph4); carryover = {B1h0,A1h0}.
// Prologue: A0h0,A0h1,B0h0,B0h1 (t0), B1h0,A1h0 (t1), vmcnt(4) — same state.
// Every overwrite is >=1 barrier after its region's last ds_read (audited).
template<int EPI>
__global__ __launch_bounds__(512, 2)
void k_gemm5(const u16* __restrict__ A, const u16* __restrict__ W,
             const float* __restrict__ bias0, const float* __restrict__ bias1,
             const float* __restrict__ bias2,
             u16* __restrict__ o0, u16* __restrict__ o1, u16* __restrict__ o2,
             int sec_shift, int out_ld,
             int M, int N, int K, int lda, int ldw, int nbx) {
  __shared__ __align__(16) u16 lds[65536];   // A: (buf*2+half)*8192; B: +32768

  int tid = threadIdx.x;
  int nwg = gridDim.x;
  int q8 = nwg >> 3, r8 = nwg & 7;
  int xcd = blockIdx.x & 7, local = blockIdx.x >> 3;
  int wgid = (xcd < r8 ? xcd * (q8 + 1) : r8 * (q8 + 1) + (xcd - r8) * q8) + local;
  int bx = wgid % nbx, by = wgid / nbx;
  int m0 = by * 256, n0 = bx * 256;

  int wid = tid >> 6, lane = tid & 63;
  int wm = wid >> 2, wn = wid & 3;
  int lr = lane & 15, lg = lane >> 4;
  int xorslot = lr & 7;
  int bcol = (wn & 1) * 64;

  int srow = tid >> 3;
  int scol = ((tid ^ (tid >> 3)) & 7) * 8;

  auto stA = [&](int buf, int h, int kt) {
    u16* dst = lds + (buf * 2 + h) * 8192 + tid * 8;
#pragma unroll
    for (int call = 0; call < 2; ++call) {
      int grow = m0 + h * 128 + call * 64 + srow;
      gl_lds16(A + (size_t)grow * lda + kt * 64 + scol, dst + call * 4096);
    }
  };
  auto stB = [&](int buf, int h, int kt) {
    u16* dst = lds + 32768 + (buf * 2 + h) * 8192 + tid * 8;
#pragma unroll
    for (int call = 0; call < 2; ++call) {
      int grow = n0 + h * 128 + call * 64 + srow;
      gl_lds16(W + (size_t)grow * ldw + kt * 64 + scol, dst + call * 4096);
    }
  };

  f32x4 zero4 = {0.f, 0.f, 0.f, 0.f};
  f32x4 acc[8][4];
#pragma unroll
  for (int m = 0; m < 8; ++m)
#pragma unroll
    for (int n = 0; n < 4; ++n) acc[m][n] = zero4;

  int NT = K >> 6, NJ = NT >> 1;
  // prologue: tile0 fully + {B1h0, A1h0} of tile1; carryover = newest 2 st*
  stA(0, 0, 0); stA(0, 1, 0); stB(0, 0, 0); stB(0, 1, 0);
  stB(1, 0, 1); stA(1, 0, 1);
  wait_vmcnt<4>();
  barrier_raw();

  for (int j = 0; j < NJ; ++j) {
    bool nlast = (j + 1 < NJ);
    int t1 = 2 * j + 1, t2 = 2 * j + 2, t3 = 2 * j + 3;
#pragma unroll
    for (int buf = 0; buf < 2; ++buf) {
      const u16* Ah = lds + (buf * 2 + wm) * 8192;
      const u16* Bh = lds + 32768 + (buf * 2 + (wn >> 1)) * 8192;
      bf16x8 aR[4][2], b0[2][2], b1[2][2];

      // ---- ph1/ph5: read aL + b0; stage; barrier; MFMA lo x b0 ----
#pragma unroll
      for (int m = 0; m < 4; ++m) {
        int r = m * 16 + lr;
#pragma unroll
        for (int kk = 0; kk < 2; ++kk)
          aR[m][kk] = *(const bf16x8*)(Ah + r * 64 + (((kk << 2) | lg) ^ xorslot) * 8);
      }
#pragma unroll
      for (int n = 0; n < 2; ++n) {
        int r = bcol + n * 16 + lr;
#pragma unroll
        for (int kk = 0; kk < 2; ++kk)
          b0[n][kk] = *(const bf16x8*)(Bh + r * 64 + (((kk << 2) | lg) ^ xorslot) * 8);
      }
      if (buf == 0) stA(1, 1, t1);
      else if (nlast) stA(0, 1, t2);
      barrier_raw();
      lgkm0_pin();
      __builtin_amdgcn_s_setprio(1);
#pragma unroll
      for (int kk = 0; kk < 2; ++kk)
#pragma unroll
        for (int m = 0; m < 4; ++m)
#pragma unroll
          for (int n = 0; n < 2; ++n)
            acc[m][n] = __builtin_amdgcn_mfma_f32_16x16x32_bf16(aR[m][kk], b0[n][kk], acc[m][n], 0, 0, 0);
      __builtin_amdgcn_s_setprio(0);
      barrier_raw();

      // ---- ph2/ph6: read b1; stage; barrier; MFMA lo x b1 ----
#pragma unroll
      for (int n = 0; n < 2; ++n) {
        int r = bcol + 32 + n * 16 + lr;
#pragma unroll
        for (int kk = 0; kk < 2; ++kk)
          b1[n][kk] = *(const bf16x8*)(Bh + r * 64 + (((kk << 2) | lg) ^ xorslot) * 8);
      }
      if (buf == 0) stB(1, 1, t1);
      else if (nlast) stB(0, 1, t2);
      barrier_raw();
      lgkm0_pin();
      __builtin_amdgcn_s_setprio(1);
#pragma unroll
      for (int kk = 0; kk < 2; ++kk)
#pragma unroll
        for (int m = 0; m < 4; ++m)
#pragma unroll
          for (int n = 0; n < 2; ++n)
            acc[m][2 + n] = __builtin_amdgcn_mfma_f32_16x16x32_bf16(aR[m][kk], b1[n][kk], acc[m][2 + n], 0, 0, 0);
      __builtin_amdgcn_s_setprio(0);
      barrier_raw();

      // ---- ph3/ph7: read aH; stage; barrier; MFMA hi x b1 ----
#pragma unroll
      for (int m = 0; m < 4; ++m) {
        int r = 64 + m * 16 + lr;
#pragma unroll
        for (int kk = 0; kk < 2; ++kk)
          aR[m][kk] = *(const bf16x8*)(Ah + r * 64 + (((kk << 2) | lg) ^ xorslot) * 8);
      }
      if (nlast) { if (buf == 0) stB(0, 0, t2); else stB(1, 0, t3); }
      barrier_raw();
      lgkm0_pin();
      __builtin_amdgcn_s_setprio(1);
#pragma unroll
      for (int kk = 0; kk < 2; ++kk)
#pragma unroll
        for (int m = 0; m < 4; ++m)
#pragma unroll
          for (int n = 0; n < 2; ++n)
            acc[4 + m][2 + n] = __builtin_amdgcn_mfma_f32_16x16x32_bf16(aR[m][kk], b1[n][kk], acc[4 + m][2 + n], 0, 0, 0);
      __builtin_amdgcn_s_setprio(0);
      barrier_raw();

      // ---- ph4/ph8: stage; barrier; MFMA hi x b0; vmcnt; barrier ----
      if (nlast) { if (buf == 0) stA(0, 0, t2); else stA(1, 0, t3); }
      barrier_raw();
      __builtin_amdgcn_s_setprio(1);
#pragma unroll
      for (int kk = 0; kk < 2; ++kk)
#pragma unroll
        for (int m = 0; m < 4; ++m)
#pragma unroll
          for (int n = 0; n < 2; ++n)
            acc[4 + m][n] = __builtin_amdgcn_mfma_f32_16x16x32_bf16(aR[m][kk], b0[n][kk], acc[4 + m][n], 0, 0, 0);
      __builtin_amdgcn_s_setprio(0);
      if (nlast) wait_vmcnt<4>(); else wait_vmcnt<0>();
      barrier_raw();
    }
  }

  // ---- epilogue ----
#pragma unroll
  for (int mf = 0; mf < 8; ++mf) {
    int row0 = m0 + wm * 128 + mf * 16 + lg * 4;
#pragma unroll
    for (int nf = 0; nf < 4; ++nf) {
      int col = n0 + wn * 64 + nf * 16 + lr;
      if constexpr (EPI == 0) {
        int sec = col >> sec_shift;
        const float* bp = sec == 0 ? bias0 : (sec == 1 ? bias1 : bias2);
        u16* op = sec == 0 ? o0 : (sec == 1 ? o1 : o2);
        int cs = col & ((1 << sec_shift) - 1);
        float bv = bp[cs];
#pragma unroll
        for (int r = 0; r < 4; ++r)
          op[(size_t)(row0 + r) * out_ld + cs] = f2bf(acc[mf][nf][r] + bv);
      } else {
        float bv = bias0[col];
#pragma unroll
        for (int r = 0; r < 4; ++r) {
          float val = acc[mf][nf][r] + bv;
          float x3 = val * val * val;
          float g = 0.5f * val * (1.f + tanhf(0.7978845608f * (val + 0.044715f * x3)));
          o0[(size_t)(row0 + r) * out_ld + col] = f2bf(g);
        }
      }
    }
  }
}

// ======== GEMM v3b (R5, proven): BMx256, BK=64, 4-phase, 3-bit swizzle ====
template<int BM, int EPI>
__global__ __launch_bounds__(512, 2)
void k_gemm3(const u16* __restrict__ A, const u16* __restrict__ W,
             const float* __restrict__ bias0, const float* __restrict__ bias1,
             const float* __restrict__ bias2,
             u16* __restrict__ o0, u16* __restrict__ o1, u16* __restrict__ o2,
             int sec_shift, int out_ld,
             float* __restrict__ outF, const float* __restrict__ resid,
             const float* __restrict__ gate_t, const float* __restrict__ gate_tab,
             int M, int N, int K, int lda, int ldw, int nbx) {
  constexpr int HTA = (BM / 2) * 64;
  constexpr int HTB = 128 * 64;
  constexpr int ACALLS = BM / 128;
  constexpr int QM = BM / 64;
  constexpr int MFR = BM / 32;
  constexpr int VMN = 4 + ACALLS;
  constexpr int BOFF = 4 * HTA;
  __shared__ __align__(16) u16 lds[BOFF + 4 * HTB];

  int tid = threadIdx.x;
  int nwg = gridDim.x;
  int q8 = nwg >> 3, r8 = nwg & 7;
  int xcd = blockIdx.x & 7, local = blockIdx.x >> 3;
  int wgid = (xcd < r8 ? xcd * (q8 + 1) : r8 * (q8 + 1) + (xcd - r8) * q8) + local;
  int bx = wgid % nbx, by = wgid / nbx;
  int m0 = by * BM, n0 = bx * 256;

  int wid = tid >> 6, lane = tid & 63;
  int wm = wid >> 2, wn = wid & 3;
  int lr = lane & 15, lg = lane >> 4;
  int xorslot = lr & 7;
  int bcol = (wn & 1) * 64;

  int srow = tid >> 3;
  int scol = ((tid ^ (tid >> 3)) & 7) * 8;

  auto stA = [&](int h, int kt2) {
    int pt = kt2 & 1;
    u16* dst = lds + (pt * 2 + h) * HTA + tid * 8;
#pragma unroll
    for (int call = 0; call < ACALLS; ++call) {
      int grow = m0 + h * (BM / 2) + call * 64 + srow;
      gl_lds16(A + (size_t)grow * lda + kt2 * 64 + scol, dst + call * 4096);
    }
  };
  auto stB = [&](int h, int kt2) {
    int pt = kt2 & 1;
    u16* dst = lds + BOFF + (pt * 2 + h) * HTB + tid * 8;
#pragma unroll
    for (int call = 0; call < 2; ++call) {
      int grow = n0 + h * 128 + call * 64 + srow;
      gl_lds16(W + (size_t)grow * ldw + kt2 * 64 + scol, dst + call * 4096);
    }
  };

  f32x4 zero4 = {0.f, 0.f, 0.f, 0.f};
  f32x4 acc[MFR][4];
#pragma unroll
  for (int m = 0; m < MFR; ++m)
#pragma unroll
    for (int n = 0; n < 4; ++n) acc[m][n] = zero4;

  int NT2 = K >> 6;
  stA(0, 0); stA(1, 0); stB(0, 0); stB(1, 0);
  stB(0, 1); stB(1, 1); stA(0, 1);
  wait_vmcnt<VMN>();
  barrier_raw();

  for (int kt = 0; kt < NT2; ++kt) {
    int p = kt & 1;
    const u16* Ah = lds + (p * 2 + wm) * HTA;
    const u16* Bh = lds + BOFF + (p * 2 + (wn >> 1)) * HTB;
    bf16x8 aR[QM][2], bR0[2][2], bR1[2][2];
    bool st1 = (kt + 1) < NT2, st2 = (kt + 2) < NT2;

#pragma unroll
    for (int m = 0; m < QM; ++m) {
      int r = m * 16 + lr;
#pragma unroll
      for (int kk = 0; kk < 2; ++kk)
        aR[m][kk] = *(const bf16x8*)(Ah + r * 64 + (((kk << 2) | lg) ^ xorslot) * 8);
    }
#pragma unroll
    for (int n = 0; n < 2; ++n) {
      int r = bcol + n * 16 + lr;
#pragma unroll
      for (int kk = 0; kk < 2; ++kk)
        bR0[n][kk] = *(const bf16x8*)(Bh + r * 64 + (((kk << 2) | lg) ^ xorslot) * 8);
    }
    if (st1) stA(1, kt + 1);
    lgkm0_pin();
    __builtin_amdgcn_s_setprio(1);
#pragma unroll
    for (int kk = 0; kk < 2; ++kk)
#pragma unroll
      for (int m = 0; m < QM; ++m)
#pragma unroll
        for (int n = 0; n < 2; ++n)
          acc[m][n] = __builtin_amdgcn_mfma_f32_16x16x32_bf16(aR[m][kk], bR0[n][kk], acc[m][n], 0, 0, 0);
    __builtin_amdgcn_s_setprio(0);
    barrier_raw();

#pragma unroll
    for (int n = 0; n < 2; ++n) {
      int r = bcol + 32 + n * 16 + lr;
#pragma unroll
      for (int kk = 0; kk < 2; ++kk)
        bR1[n][kk] = *(const bf16x8*)(Bh + r * 64 + (((kk << 2) | lg) ^ xorslot) * 8);
    }
    lgkm0_pin();
    __builtin_amdgcn_s_setprio(1);
#pragma unroll
    for (int kk = 0; kk < 2; ++kk)
#pragma unroll
      for (int m = 0; m < QM; ++m)
#pragma unroll
        for (int n = 0; n < 2; ++n)
          acc[m][2 + n] = __builtin_amdgcn_mfma_f32_16x16x32_bf16(aR[m][kk], bR1[n][kk], acc[m][2 + n], 0, 0, 0);
    __builtin_amdgcn_s_setprio(0);
    barrier_raw();

#pragma unroll
    for (int m = 0; m < QM; ++m) {
      int r = (BM / 4) + m * 16 + lr;
#pragma unroll
      for (int kk = 0; kk < 2; ++kk)
        aR[m][kk] = *(const bf16x8*)(Ah + r * 64 + (((kk << 2) | lg) ^ xorslot) * 8);
    }
    if (st2) { stB(0, kt + 2); stB(1, kt + 2); }
    lgkm0_pin();
    __builtin_amdgcn_s_setprio(1);
#pragma unroll
    for (int kk = 0; kk < 2; ++kk)
#pragma unroll
      for (int m = 0; m < QM; ++m)
#pragma unroll
        for (int n = 0; n < 2; ++n)
          acc[QM + m][2 + n] = __builtin_amdgcn_mfma_f32_16x16x32_bf16(aR[m][kk], bR1[n][kk], acc[QM + m][2 + n], 0, 0, 0);
    __builtin_amdgcn_s_setprio(0);
    barrier_raw();

    if (st2) stA(0, kt + 2);
    __builtin_amdgcn_s_setprio(1);
#pragma unroll
    for (int kk = 0; kk < 2; ++kk)
#pragma unroll
      for (int m = 0; m < QM; ++m)
#pragma unroll
        for (int n = 0; n < 2; ++n)
          acc[QM + m][n] = __builtin_amdgcn_mfma_f32_16x16x32_bf16(aR[m][kk], bR0[n][kk], acc[QM + m][n], 0, 0, 0);
    __builtin_amdgcn_s_setprio(0);
    if (st2) wait_vmcnt<VMN>(); else wait_vmcnt<0>();
    barrier_raw();
  }

  // ---- epilogue ----
#pragma unroll
  for (int mf = 0; mf < MFR; ++mf) {
    int row0 = m0 + wm * (BM / 2) + mf * 16 + lg * 4;
#pragma unroll
    for (int nf = 0; nf < 4; ++nf) {
      int col = n0 + wn * 64 + nf * 16 + lr;
      if constexpr (EPI == 0) {
        int sec = col >> sec_shift;
        const float* bp = sec == 0 ? bias0 : (sec == 1 ? bias1 : bias2);
        u16* op = sec == 0 ? o0 : (sec == 1 ? o1 : o2);
        int cs = col & ((1 << sec_shift) - 1);
        float bv = bp[cs];
#pragma unroll
        for (int r = 0; r < 4; ++r)
          op[(size_t)(row0 + r) * out_ld + cs] = f2bf(acc[mf][nf][r] + bv);
      } else if constexpr (EPI == 2) {
        float bv = bias0[col];
        float gt = gate_tab[col];
#pragma unroll
        for (int r = 0; r < 4; ++r) {
          int row = row0 + r;
          size_t idx = (size_t)row * N + col;
          float g = gt + gate_t[(size_t)row * (6 * C_DIM) + col];
          float o = resid[idx] + g * (acc[mf][nf][r] + bv);
          outF[idx] = o;
          if (o0) o0[idx] = f2bf(o);
        }
      } else {
        float bv = bias0[col];
#pragma unroll
        for (int r = 0; r < 4; ++r) {
          size_t idx = (size_t)(row0 + r) * N + col;
          outF[idx] = resid[idx] + (acc[mf][nf][r] + bv);
        }
      }
    }
  }
}

// ---------------- RoPE on q and k (in place, bf16) ----------------
__global__ void k_rope(u16* __restrict__ q, u16* __restrict__ k,
                       const float* __restrict__ freqs) {
  int idx = blockIdx.x * blockDim.x + threadIdx.x;
  int total = L_ROWS * C_DIM / 8;
  for (; idx < total; idx += gridDim.x * blockDim.x) {
    int e = idx * 8;
    int row = e >> 11;
    int col = e & (C_DIM - 1);
    int s = row & (S_LEN - 1);
    int i0 = (col & (DH - 1)) >> 1;
    float4 fr = *(const float4*)(freqs + s * (DH / 2) + i0);
    float cs[4], sn[4];
    float fv[4] = {fr.x, fr.y, fr.z, fr.w};
#pragma unroll
    for (int j = 0; j < 4; ++j) sincosf(fv[j], &sn[j], &cs[j]);
    us8 qa = *(us8*)(q + e);
    us8 ka = *(us8*)(k + e);
#pragma unroll
    for (int p = 0; p < 4; ++p) {
      float a = bf2f(qa[2 * p]), b = bf2f(qa[2 * p + 1]);
      qa[2 * p]     = f2bf(a * cs[p] - b * sn[p]);
      qa[2 * p + 1] = f2bf(a * sn[p] + b * cs[p]);
      float a2 = bf2f(ka[2 * p]), b2 = bf2f(ka[2 * p + 1]);
      ka[2 * p]     = f2bf(a2 * cs[p] - b2 * sn[p]);
      ka[2 * p + 1] = f2bf(a2 * sn[p] + b2 * cs[p]);
    }
    *(us8*)(q + e) = qa;
    *(us8*)(k + e) = ka;
  }
}

// ---------------- V transpose: [b*Lkv+kv][h*DH+d] -> [bh][d][kv] ----------------
__global__ void k_transpose_v(const u16* __restrict__ v, u16* __restrict__ vt, int Lkv) {
  __shared__ u16 tile[32][33];
  int bh = blockIdx.x, b = bh >> 4, h = bh & 15;
  int k0 = blockIdx.y * 32, d0 = blockIdx.z * 32;
  int tx = threadIdx.x, ty = threadIdx.y;
  const u16* src = v + (size_t)(b * Lkv) * C_DIM + h * DH;
#pragma unroll
  for (int j = 0; j < 32; j += 8)
    tile[ty + j][tx] = src[(size_t)(k0 + ty + j) * C_DIM + d0 + tx];
  __syncthreads();
  u16* dst = vt + (size_t)bh * DH * Lkv;
#pragma unroll
  for (int j = 0; j < 32; j += 8)
    dst[(size_t)(d0 + ty + j) * Lkv + k0 + tx] = tile[tx][ty + j];
}

// ---------------- flash attention ----------------
__global__ __launch_bounds__(256)
void k_flash(const u16* __restrict__ Q, const u16* __restrict__ K,
             const u16* __restrict__ Vt, u16* __restrict__ O,
             int Lq, int Lkv, float scale) {
  __shared__ __align__(16) u16 lK[64 * 128];
  __shared__ __align__(16) u16 lV[128 * 64];
  __shared__ __align__(16) u16 lP[4][16 * 72];
  int bh = blockIdx.x, b = bh >> 4, h = bh & 15;
  int tid = threadIdx.x, wid = tid >> 6, lane = tid & 63;
  int lr = lane & 15, lg = lane >> 4;
  int q0 = blockIdx.y * 64 + wid * 16;
  const u16* Qb = Q + ((size_t)(b * Lq) + q0) * C_DIM + h * DH;
  const u16* Kb = K + (size_t)(b * Lkv) * C_DIM + h * DH;
  const u16* Vb = Vt + (size_t)bh * DH * Lkv;

  bf16x8 qf[4];
#pragma unroll
  for (int ks = 0; ks < 4; ++ks)
    qf[ks] = *(const bf16x8*)(Qb + (size_t)lr * C_DIM + ks * 32 + lg * 8);

  f32x4 zero4 = {0.f, 0.f, 0.f, 0.f};
  f32x4 o[8];
#pragma unroll
  for (int n = 0; n < 8; ++n) o[n] = zero4;
  float mrow[4] = {-3.0e38f, -3.0e38f, -3.0e38f, -3.0e38f};
  float lrow[4] = {0.f, 0.f, 0.f, 0.f};

  int nsteps = Lkv >> 6;
  for (int kt = 0; kt < nsteps; ++kt) {
#pragma unroll
    for (int i = 0; i < 4; ++i) {
      int flat = i * 4096 + tid * 16;
      int key = flat >> 8, inner = flat & 255;
      int ksrc = inner ^ ((key & 7) << 4);
      gl_lds16((const char*)Kb + ((size_t)(kt * 64 + key) * C_DIM) * 2 + ksrc, (char*)lK + flat);
      int d = flat >> 7, keyb = flat & 127;
      int vsrc = keyb ^ ((d & 7) << 4);
      gl_lds16((const char*)Vb + ((size_t)d * Lkv) * 2 + kt * 128 + vsrc, (char*)lV + flat);
    }
    __syncthreads();

    f32x4 sc[4];
#pragma unroll
    for (int c = 0; c < 4; ++c) sc[c] = zero4;
#pragma unroll
    for (int c = 0; c < 4; ++c) {
      int key = c * 16 + lr;
#pragma unroll
      for (int ks = 0; ks < 4; ++ks) {
        int off = (ks * 64 + lg * 16) ^ ((key & 7) << 4);
        bf16x8 kf = *(const bf16x8*)((const char*)lK + key * 256 + off);
        sc[c] = __builtin_amdgcn_mfma_f32_16x16x32_bf16(qf[ks], kf, sc[c], 0, 0, 0);
      }
    }
#pragma unroll
    for (int r = 0; r < 4; ++r) {
      float s0 = sc[0][r] * scale, s1 = sc[1][r] * scale;
      float s2 = sc[2][r] * scale, s3 = sc[3][r] * scale;
      float mx = fmaxf(fmaxf(s0, s1), fmaxf(s2, s3));
#pragma unroll
      for (int m = 1; m < 16; m <<= 1) mx = fmaxf(mx, __shfl_xor(mx, m));
      float mnew = fmaxf(mrow[r], mx);
      float alpha = exp2f((mrow[r] - mnew) * 1.44269504f);
      mrow[r] = mnew;
      float p0 = exp2f((s0 - mnew) * 1.44269504f);
      float p1 = exp2f((s1 - mnew) * 1.44269504f);
      float p2 = exp2f((s2 - mnew) * 1.44269504f);
      float p3 = exp2f((s3 - mnew) * 1.44269504f);
      float psum = p0 + p1 + p2 + p3;
#pragma unroll
      for (int m = 1; m < 16; m <<= 1) psum += __shfl_xor(psum, m);
      lrow[r] = lrow[r] * alpha + psum;
#pragma unroll
      for (int n = 0; n < 8; ++n) o[n][r] *= alpha;
      u16* pr = lP[wid] + (4 * lg + r) * 72;
      pr[lr]      = f2bf(p0);
      pr[16 + lr] = f2bf(p1);
      pr[32 + lr] = f2bf(p2);
      pr[48 + lr] = f2bf(p3);
    }
    asm volatile("s_waitcnt lgkmcnt(0)" ::: "memory");
    __builtin_amdgcn_sched_barrier(0);
#pragma unroll
    for (int half = 0; half < 2; ++half) {
      bf16x8 pf = *(const bf16x8*)(lP[wid] + lr * 72 + half * 32 + lg * 8);
#pragma unroll
      for (int n = 0; n < 8; ++n) {
        int d = n * 16 + lr;
        int off = (half * 64 + lg * 16) ^ ((d & 7) << 4);
        bf16x8 vf = *(const bf16x8*)((const char*)lV + d * 128 + off);
        o[n] = __builtin_amdgcn_mfma_f32_16x16x32_bf16(pf, vf, o[n], 0, 0, 0);
      }
    }
    __syncthreads();
  }

  u16* Ob = O + ((size_t)(b * Lq) + q0) * C_DIM + h * DH;
#pragma unroll
  for (int n = 0; n < 8; ++n) {
    int d = n * 16 + lr;
#pragma unroll
    for (int r = 0; r < 4; ++r) {
      int qr = 4 * lg + r;
      Ob[(size_t)qr * C_DIM + d] = f2bf(o[n][r] / lrow[r]);
    }
  }
}

// ---------------- host ----------------
extern "C" void kernel_launch(void* const* d_in, const int* in_sizes, int n_in,
                              void* d_out, int out_size, void* d_ws, size_t ws_size,
                              hipStream_t stream) {
  const float* x     = (const float*)d_in[0];
  const float* y     = (const float*)d_in[1];
  const float* t     = (const float*)d_in[2];
  const float* freqs = (const float*)d_in[3];
  const float* tab   = (const float*)d_in[4];
  const float* Wq_s = (const float*)d_in[5];
  const float* bq_s = (const float*)d_in[6];
  const float* Wk_s = (const float*)d_in[7];
  const float* bk_s = (const float*)d_in[8];
  const float* Wv_s = (const float*)d_in[9];
  const float* bv_s = (const float*)d_in[10];
  const float* Wo_s = (const float*)d_in[11];
  const float* bo_s = (const float*)d_in[12];
  const float* Wq_c = (const float*)d_in[13];
  const float* bq_c = (const float*)d_in[14];
  const float* Wk_c = (const float*)d_in[15];
  const float* bk_c = (const float*)d_in[16];
  const float* Wv_c = (const float*)d_in[17];
  const float* bv_c = (const float*)d_in[18];
  const float* Wo_c = (const float*)d_in[19];
  const float* bo_c = (const float*)d_in[20];
  const float* W_fc1 = (const float*)d_in[21];
  const float* b_fc1 = (const float*)d_in[22];
  const float* W_fc2 = (const float*)d_in[23];
  const float* b_fc2 = (const float*)d_in[24];

  const size_t SZ_CC  = (size_t)C_DIM * C_DIM * 2;
  const size_t SZ_FC  = (size_t)F_DIM * C_DIM * 2;
  const size_t SZ_LC  = (size_t)L_ROWS * C_DIM * 2;
  const size_t SZ_YC  = (size_t)LY_ROWS * C_DIM * 2;
  char* ws = (char*)d_ws;
  size_t off = 0;
  u16* wq_s = (u16*)(ws + off); off += SZ_CC;   // wq_s..wv_s contiguous = QKV concat
  u16* wk_s = (u16*)(ws + off); off += SZ_CC;
  u16* wv_s = (u16*)(ws + off); off += SZ_CC;
  u16* wo_s = (u16*)(ws + off); off += SZ_CC;
  u16* wq_c = (u16*)(ws + off); off += SZ_CC;
  u16* wk_c = (u16*)(ws + off); off += SZ_CC;   // wk_c,wv_c contiguous = KV concat
  u16* wv_c = (u16*)(ws + off); off += SZ_CC;
  u16* wo_c = (u16*)(ws + off); off += SZ_CC;
  u16* wfc1 = (u16*)(ws + off); off += SZ_FC;
  u16* wfc2 = (u16*)(ws + off); off += SZ_FC;
  u16* ybf  = (u16*)(ws + off); off += SZ_YC;
  u16* xm   = (u16*)(ws + off); off += SZ_LC;
  u16* qb   = (u16*)(ws + off); off += SZ_LC;
  u16* kb   = (u16*)(ws + off); off += SZ_LC;
  u16* vb   = (u16*)(ws + off); off += SZ_LC;
  u16* ao   = (u16*)(ws + off); off += SZ_LC;
  u16* hbuf = qb;                               // [L, F] bf16 overlay (qb..ao)
  float* x1 = (float*)(ws + off); off += (size_t)L_ROWS * C_DIM * 4;
  u16* x1bf = (u16*)(ws + off); off += SZ_LC;
  u16* kc   = (u16*)(ws + off); off += SZ_YC;
  u16* vc   = (u16*)(ws + off); off += SZ_YC;
  u16* vt   = (u16*)(ws + off); off += SZ_LC;
  u16* vtc  = (u16*)(ws + off); off += SZ_YC;
  if (ws_size < off) return;

  auto cvt = [&](const float* s, u16* d, int n) {
    int blocks = (n / 4 + 255) / 256; if (blocks > 4096) blocks = 4096;
    k_cvt<<<blocks, 256, 0, stream>>>(s, d, n);
  };
  cvt(Wq_s, wq_s, C_DIM * C_DIM);
  cvt(Wk_s, wk_s, C_DIM * C_DIM);
  cvt(Wv_s, wv_s, C_DIM * C_DIM);
  cvt(Wo_s, wo_s, C_DIM * C_DIM);
  cvt(Wq_c, wq_c, C_DIM * C_DIM);
  cvt(Wk_c, wk_c, C_DIM * C_DIM);
  cvt(Wv_c, wv_c, C_DIM * C_DIM);
  cvt(Wo_c, wo_c, C_DIM * C_DIM);
  cvt(W_fc1, wfc1, F_DIM * C_DIM);
  cvt(W_fc2, wfc2, F_DIM * C_DIM);
  cvt(y, ybf, LY_ROWS * C_DIM);

  const float ascale = 0.08838834764831845f;

  k_modln<<<L_ROWS, 256, 0, stream>>>(x, t, tab, xm, 1, 0);
  // fused self QKV: N = 6144 (8-phase 256x256)
  k_gemm5<0><<<16 * 24, 512, 0, stream>>>(
      xm, wq_s, bq_s, bk_s, bv_s, qb, kb, vb, 11, C_DIM,
      L_ROWS, 6144, C_DIM, C_DIM, C_DIM, 24);
  k_rope<<<2048, 256, 0, stream>>>(qb, kb, freqs);
  k_transpose_v<<<dim3(B_SZ * H_NUM, S_LEN / 32, DH / 32), dim3(32, 8), 0, stream>>>(vb, vt, S_LEN);
  k_flash<<<dim3(B_SZ * H_NUM, S_LEN / 64), 256, 0, stream>>>(qb, kb, vt, ao, S_LEN, S_LEN, ascale);
  // x1 = x + gate_msa*(ao@Wo_s^T+bo_s); bf16 mirror x1bf
  k_gemm3<128, 2><<<32 * 8, 512, 0, stream>>>(
      ao, wo_s, bo_s, nullptr, nullptr, x1bf, nullptr, nullptr, 30, C_DIM,
      x1, x, t + 2 * C_DIM, tab + 2 * C_DIM, L_ROWS, C_DIM, C_DIM, C_DIM, C_DIM, 8);
  // cross q
  k_gemm3<128, 0><<<32 * 8, 512, 0, stream>>>(
      x1bf, wq_c, bq_c, nullptr, nullptr, qb, nullptr, nullptr, 30, C_DIM,
      nullptr, nullptr, nullptr, nullptr, L_ROWS, C_DIM, C_DIM, C_DIM, C_DIM, 8);
  // fused cross KV: N = 4096
  k_gemm3<128, 0><<<8 * 16, 512, 0, stream>>>(
      ybf, wk_c, bk_c, bv_c, bv_c, kc, vc, vc, 11, C_DIM,
      nullptr, nullptr, nullptr, nullptr, LY_ROWS, 4096, C_DIM, C_DIM, C_DIM, 16);
  k_transpose_v<<<dim3(B_SZ * H_NUM, T_LEN / 32, DH / 32), dim3(32, 8), 0, stream>>>(vc, vtc, T_LEN);
  k_flash<<<dim3(B_SZ * H_NUM, S_LEN / 64), 256, 0, stream>>>(qb, kc, vtc, ao, S_LEN, T_LEN, ascale);
  // x1 += ao@Wo_c^T + bo_c
  k_gemm3<128, 3><<<32 * 8, 512, 0, stream>>>(
      ao, wo_c, bo_c, nullptr, nullptr, nullptr, nullptr, nullptr, 30, C_DIM,
      x1, x1, nullptr, nullptr, L_ROWS, C_DIM, C_DIM, C_DIM, C_DIM, 8);
  // MLP
  k_modln<<<L_ROWS, 256, 0, stream>>>(x1, t, tab, xm, 4, 3);
  k_gemm5<1><<<16 * 32, 512, 0, stream>>>(
      xm, wfc1, b_fc1, nullptr, nullptr, hbuf, nullptr, nullptr, 30, F_DIM,
      L_ROWS, F_DIM, C_DIM, C_DIM, C_DIM, 32);
  // fc2 single dispatch: d_out = x1 + gate_mlp*(h@W_fc2^T + b_fc2)
  k_gemm3<128, 2><<<32 * 8, 512, 0, stream>>>(
      hbuf, wfc2, b_fc2, nullptr, nullptr, nullptr, nullptr, nullptr, 30, C_DIM,
      (float*)d_out, x1, t + 5 * C_DIM, tab + 5 * C_DIM, L_ROWS, C_DIM, F_DIM, F_DIM, F_DIM, 8);
}

// Round 9
// 856.486 us; speedup vs baseline: 1.1158x; 1.0771x over previous
//
#include <hip/hip_runtime.h>
#include <stdint.h>

#define C_DIM 2048
#define H_NUM 16
#define DH    128
#define S_LEN 1024
#define T_LEN 256
#define B_SZ  4
#define L_ROWS 4096   // B*S
#define LY_ROWS 1024  // B*T
#define F_DIM 8192

typedef __attribute__((ext_vector_type(4))) float f32x4;
typedef __attribute__((ext_vector_type(8))) __bf16 bf16x8;
typedef __attribute__((ext_vector_type(4))) unsigned short us4;
typedef __attribute__((ext_vector_type(8))) unsigned short us8;
typedef unsigned short u16;

__device__ __forceinline__ u16 f2bf(float f) {
  union { float f; uint32_t u; } v; v.f = f;
  uint32_t r = v.u + 0x7FFFu + ((v.u >> 16) & 1u);
  return (u16)(r >> 16);
}
__device__ __forceinline__ float bf2f(u16 h) {
  union { uint32_t u; float f; } v; v.u = ((uint32_t)h) << 16;
  return v.f;
}

typedef __attribute__((address_space(1))) void gvoid;
typedef __attribute__((address_space(3))) void lvoid;
__device__ __forceinline__ void gl_lds16(const void* g, void* l) {
  __builtin_amdgcn_global_load_lds((gvoid*)g, (lvoid*)l, 16, 0, 0);
}

template<int N> __device__ __forceinline__ void wait_vmcnt() {
  if constexpr (N == 0) asm volatile("s_waitcnt vmcnt(0)" ::: "memory");
  else if constexpr (N == 4) asm volatile("s_waitcnt vmcnt(4)" ::: "memory");
  else if constexpr (N == 5) asm volatile("s_waitcnt vmcnt(5)" ::: "memory");
  else if constexpr (N == 6) asm volatile("s_waitcnt vmcnt(6)" ::: "memory");
}
__device__ __forceinline__ void barrier_raw() {
  asm volatile("s_barrier" ::: "memory");
}
__device__ __forceinline__ void lgkm0_pin() {
  asm volatile("s_waitcnt lgkmcnt(0)" ::: "memory");
  __builtin_amdgcn_sched_barrier(0);
}

__device__ __forceinline__ float gelu_fast(float val) {
  float z = 0.7978845608f * (val + 0.044715f * val * val * val);
  float e = __expf(2.f * z);              // v_exp_f32 fast path
  float th = 1.f - 2.f / (e + 1.f);
  return 0.5f * val * (1.f + th);
}

// ---------------- fp32 -> bf16 conversion ----------------
__global__ void k_cvt(const float* __restrict__ src, u16* __restrict__ dst, int n) {
  int i = (blockIdx.x * blockDim.x + threadIdx.x) * 4;
  int stride = gridDim.x * blockDim.x * 4;
  for (; i < n; i += stride) {
    float4 v = *(const float4*)(src + i);
    us4 o;
    o[0] = f2bf(v.x); o[1] = f2bf(v.y); o[2] = f2bf(v.z); o[3] = f2bf(v.w);
    *(us4*)(dst + i) = o;
  }
}

// ---------------- LN + adaLN modulation (fp32 or bf16 input) ----------------
template<int INBF>
__global__ __launch_bounds__(256)
void k_modln(const void* __restrict__ xin, const float* __restrict__ t,
             const float* __restrict__ tab, u16* __restrict__ out,
             int scale_idx, int shift_idx) {
  int row = blockIdx.x;
  int tid = threadIdx.x;
  int c0 = tid * 8;
  float v[8];
  if constexpr (INBF) {
    us8 a = *(const us8*)((const u16*)xin + (size_t)row * C_DIM + c0);
#pragma unroll
    for (int j = 0; j < 8; ++j) v[j] = bf2f(a[j]);
  } else {
    const float* xr = (const float*)xin + (size_t)row * C_DIM;
    float4 a = *(const float4*)(xr + c0);
    float4 b = *(const float4*)(xr + c0 + 4);
    v[0] = a.x; v[1] = a.y; v[2] = a.z; v[3] = a.w;
    v[4] = b.x; v[5] = b.y; v[6] = b.z; v[7] = b.w;
  }
  float s = 0.f, ss = 0.f;
#pragma unroll
  for (int j = 0; j < 8; ++j) { s += v[j]; ss += v[j] * v[j]; }
#pragma unroll
  for (int m = 1; m < 64; m <<= 1) { s += __shfl_xor(s, m); ss += __shfl_xor(ss, m); }
  __shared__ float red[8];
  int wid = tid >> 6;
  if ((tid & 63) == 0) { red[wid * 2] = s; red[wid * 2 + 1] = ss; }
  __syncthreads();
  s  = red[0] + red[2] + red[4] + red[6];
  ss = red[1] + red[3] + red[5] + red[7];
  float mean = s * (1.f / C_DIM);
  float var  = ss * (1.f / C_DIM) - mean * mean;
  float rstd = rsqrtf(var + 1e-6f);
  const float* trow = t + (size_t)row * (6 * C_DIM);
  const float* tsc = trow + scale_idx * C_DIM + c0;
  const float* tsh = trow + shift_idx * C_DIM + c0;
  const float* gsc = tab + scale_idx * C_DIM + c0;
  const float* gsh = tab + shift_idx * C_DIM + c0;
  us8 o;
#pragma unroll
  for (int j = 0; j < 8; ++j) {
    float scv = 1.f + gsc[j] + tsc[j];
    float shv = gsh[j] + tsh[j];
    o[j] = f2bf((v[j] - mean) * rstd * scv + shv);
  }
  *(us8*)(out + (size_t)row * C_DIM + c0) = o;
}

// ======== GEMM v5b: 256x256 tile, BK=64, 2 K-tiles/iter, 8-phase ============
// (R8-proven ledger; see R8 comments.) EPI 0: bf16(acc+bias)->o{0,1,2};
// EPI 1: fast-gelu->o0.
template<int EPI>
__global__ __launch_bounds__(512, 2)
void k_gemm5(const u16* __restrict__ A, const u16* __restrict__ W,
             const float* __restrict__ bias0, const float* __restrict__ bias1,
             const float* __restrict__ bias2,
             u16* __restrict__ o0, u16* __restrict__ o1, u16* __restrict__ o2,
             int sec_shift, int out_ld,
             int M, int N, int K, int lda, int ldw, int nbx) {
  __shared__ __align__(16) u16 lds[65536];

  int tid = threadIdx.x;
  int nwg = gridDim.x;
  int q8 = nwg >> 3, r8 = nwg & 7;
  int xcd = blockIdx.x & 7, local = blockIdx.x >> 3;
  int wgid = (xcd < r8 ? xcd * (q8 + 1) : r8 * (q8 + 1) + (xcd - r8) * q8) + local;
  int bx = wgid % nbx, by = wgid / nbx;
  int m0 = by * 256, n0 = bx * 256;

  int wid = tid >> 6, lane = tid & 63;
  int wm = wid >> 2, wn = wid & 3;
  int lr = lane & 15, lg = lane >> 4;
  int xorslot = lr & 7;
  int bcol = (wn & 1) * 64;

  int srow = tid >> 3;
  int scol = ((tid ^ (tid >> 3)) & 7) * 8;

  auto stA = [&](int buf, int h, int kt) {
    u16* dst = lds + (buf * 2 + h) * 8192 + tid * 8;
#pragma unroll
    for (int call = 0; call < 2; ++call) {
      int grow = m0 + h * 128 + call * 64 + srow;
      gl_lds16(A + (size_t)grow * lda + kt * 64 + scol, dst + call * 4096);
    }
  };
  auto stB = [&](int buf, int h, int kt) {
    u16* dst = lds + 32768 + (buf * 2 + h) * 8192 + tid * 8;
#pragma unroll
    for (int call = 0; call < 2; ++call) {
      int grow = n0 + h * 128 + call * 64 + srow;
      gl_lds16(W + (size_t)grow * ldw + kt * 64 + scol, dst + call * 4096);
    }
  };

  f32x4 zero4 = {0.f, 0.f, 0.f, 0.f};
  f32x4 acc[8][4];
#pragma unroll
  for (int m = 0; m < 8; ++m)
#pragma unroll
    for (int n = 0; n < 4; ++n) acc[m][n] = zero4;

  int NT = K >> 6, NJ = NT >> 1;
  stA(0, 0, 0); stA(0, 1, 0); stB(0, 0, 0); stB(0, 1, 0);
  stB(1, 0, 1); stA(1, 0, 1);
  wait_vmcnt<4>();
  barrier_raw();

  for (int j = 0; j < NJ; ++j) {
    bool nlast = (j + 1 < NJ);
    int t1 = 2 * j + 1, t2 = 2 * j + 2, t3 = 2 * j + 3;
#pragma unroll
    for (int buf = 0; buf < 2; ++buf) {
      const u16* Ah = lds + (buf * 2 + wm) * 8192;
      const u16* Bh = lds + 32768 + (buf * 2 + (wn >> 1)) * 8192;
      bf16x8 aR[4][2], b0[2][2], b1[2][2];

#pragma unroll
      for (int m = 0; m < 4; ++m) {
        int r = m * 16 + lr;
#pragma unroll
        for (int kk = 0; kk < 2; ++kk)
          aR[m][kk] = *(const bf16x8*)(Ah + r * 64 + (((kk << 2) | lg) ^ xorslot) * 8);
      }
#pragma unroll
      for (int n = 0; n < 2; ++n) {
        int r = bcol + n * 16 + lr;
#pragma unroll
        for (int kk = 0; kk < 2; ++kk)
          b0[n][kk] = *(const bf16x8*)(Bh + r * 64 + (((kk << 2) | lg) ^ xorslot) * 8);
      }
      if (buf == 0) stA(1, 1, t1);
      else if (nlast) stA(0, 1, t2);
      barrier_raw();
      lgkm0_pin();
      __builtin_amdgcn_s_setprio(1);
#pragma unroll
      for (int kk = 0; kk < 2; ++kk)
#pragma unroll
        for (int m = 0; m < 4; ++m)
#pragma unroll
          for (int n = 0; n < 2; ++n)
            acc[m][n] = __builtin_amdgcn_mfma_f32_16x16x32_bf16(aR[m][kk], b0[n][kk], acc[m][n], 0, 0, 0);
      __builtin_amdgcn_s_setprio(0);
      barrier_raw();

#pragma unroll
      for (int n = 0; n < 2; ++n) {
        int r = bcol + 32 + n * 16 + lr;
#pragma unroll
        for (int kk = 0; kk < 2; ++kk)
          b1[n][kk] = *(const bf16x8*)(Bh + r * 64 + (((kk << 2) | lg) ^ xorslot) * 8);
      }
      if (buf == 0) stB(1, 1, t1);
      else if (nlast) stB(0, 1, t2);
      barrier_raw();
      lgkm0_pin();
      __builtin_amdgcn_s_setprio(1);
#pragma unroll
      for (int kk = 0; kk < 2; ++kk)
#pragma unroll
        for (int m = 0; m < 4; ++m)
#pragma unroll
          for (int n = 0; n < 2; ++n)
            acc[m][2 + n] = __builtin_amdgcn_mfma_f32_16x16x32_bf16(aR[m][kk], b1[n][kk], acc[m][2 + n], 0, 0, 0);
      __builtin_amdgcn_s_setprio(0);
      barrier_raw();

#pragma unroll
      for (int m = 0; m < 4; ++m) {
        int r = 64 + m * 16 + lr;
#pragma unroll
        for (int kk = 0; kk < 2; ++kk)
          aR[m][kk] = *(const bf16x8*)(Ah + r * 64 + (((kk << 2) | lg) ^ xorslot) * 8);
      }
      if (nlast) { if (buf == 0) stB(0, 0, t2); else stB(1, 0, t3); }
      barrier_raw();
      lgkm0_pin();
      __builtin_amdgcn_s_setprio(1);
#pragma unroll
      for (int kk = 0; kk < 2; ++kk)
#pragma unroll
        for (int m = 0; m < 4; ++m)
#pragma unroll
          for (int n = 0; n < 2; ++n)
            acc[4 + m][2 + n] = __builtin_amdgcn_mfma_f32_16x16x32_bf16(aR[m][kk], b1[n][kk], acc[4 + m][2 + n], 0, 0, 0);
      __builtin_amdgcn_s_setprio(0);
      barrier_raw();

      if (nlast) { if (buf == 0) stA(0, 0, t2); else stA(1, 0, t3); }
      barrier_raw();
      __builtin_amdgcn_s_setprio(1);
#pragma unroll
      for (int kk = 0; kk < 2; ++kk)
#pragma unroll
        for (int m = 0; m < 4; ++m)
#pragma unroll
          for (int n = 0; n < 2; ++n)
            acc[4 + m][n] = __builtin_amdgcn_mfma_f32_16x16x32_bf16(aR[m][kk], b0[n][kk], acc[4 + m][n], 0, 0, 0);
      __builtin_amdgcn_s_setprio(0);
      if (nlast) wait_vmcnt<4>(); else wait_vmcnt<0>();
      barrier_raw();
    }
  }

#pragma unroll
  for (int mf = 0; mf < 8; ++mf) {
    int row0 = m0 + wm * 128 + mf * 16 + lg * 4;
#pragma unroll
    for (int nf = 0; nf < 4; ++nf) {
      int col = n0 + wn * 64 + nf * 16 + lr;
      if constexpr (EPI == 0) {
        int sec = col >> sec_shift;
        const float* bp = sec == 0 ? bias0 : (sec == 1 ? bias1 : bias2);
        u16* op = sec == 0 ? o0 : (sec == 1 ? o1 : o2);
        int cs = col & ((1 << sec_shift) - 1);
        float bv = bp[cs];
#pragma unroll
        for (int r = 0; r < 4; ++r)
          op[(size_t)(row0 + r) * out_ld + cs] = f2bf(acc[mf][nf][r] + bv);
      } else {
        float bv = bias0[col];
#pragma unroll
        for (int r = 0; r < 4; ++r)
          o0[(size_t)(row0 + r) * out_ld + col] = f2bf(gelu_fast(acc[mf][nf][r] + bv));
      }
    }
  }
}

// ======== GEMM v3c: BMx256, BK=64, 4-phase, 3-bit swizzle (R5-proven) ======
// EPI 0: bf16(acc+bias)->o{0,1,2} split by col>>sec_shift
// EPI 6: o0 = bf16(residF + gate*(acc+bias))              (wo_s -> x1bf)
// EPI 7: o0 = bf16(bf2f(o0) + acc + bias)  in-place RMW   (wo_c)
// EPI 8: outF = bf2f(o1[idx]) + gate*(acc+bias)           (fc2 final fp32)
template<int BM, int EPI>
__global__ __launch_bounds__(512, 2)
void k_gemm3(const u16* __restrict__ A, const u16* __restrict__ W,
             const float* __restrict__ bias0, const float* __restrict__ bias1,
             const float* __restrict__ bias2,
             u16* __restrict__ o0, u16* __restrict__ o1, u16* __restrict__ o2,
             int sec_shift, int out_ld,
             float* __restrict__ outF, const float* __restrict__ resid,
             const float* __restrict__ gate_t, const float* __restrict__ gate_tab,
             int M, int N, int K, int lda, int ldw, int nbx) {
  constexpr int HTA = (BM / 2) * 64;
  constexpr int HTB = 128 * 64;
  constexpr int ACALLS = BM / 128;
  constexpr int QM = BM / 64;
  constexpr int MFR = BM / 32;
  constexpr int VMN = 4 + ACALLS;
  constexpr int BOFF = 4 * HTA;
  __shared__ __align__(16) u16 lds[BOFF + 4 * HTB];

  int tid = threadIdx.x;
  int nwg = gridDim.x;
  int q8 = nwg >> 3, r8 = nwg & 7;
  int xcd = blockIdx.x & 7, local = blockIdx.x >> 3;
  int wgid = (xcd < r8 ? xcd * (q8 + 1) : r8 * (q8 + 1) + (xcd - r8) * q8) + local;
  int bx = wgid % nbx, by = wgid / nbx;
  int m0 = by * BM, n0 = bx * 256;

  int wid = tid >> 6, lane = tid & 63;
  int wm = wid >> 2, wn = wid & 3;
  int lr = lane & 15, lg = lane >> 4;
  int xorslot = lr & 7;
  int bcol = (wn & 1) * 64;

  int srow = tid >> 3;
  int scol = ((tid ^ (tid >> 3)) & 7) * 8;

  auto stA = [&](int h, int kt2) {
    int pt = kt2 & 1;
    u16* dst = lds + (pt * 2 + h) * HTA + tid * 8;
#pragma unroll
    for (int call = 0; call < ACALLS; ++call) {
      int grow = m0 + h * (BM / 2) + call * 64 + srow;
      gl_lds16(A + (size_t)grow * lda + kt2 * 64 + scol, dst + call * 4096);
    }
  };
  auto stB = [&](int h, int kt2) {
    int pt = kt2 & 1;
    u16* dst = lds + BOFF + (pt * 2 + h) * HTB + tid * 8;
#pragma unroll
    for (int call = 0; call < 2; ++call) {
      int grow = n0 + h * 128 + call * 64 + srow;
      gl_lds16(W + (size_t)grow * ldw + kt2 * 64 + scol, dst + call * 4096);
    }
  };

  f32x4 zero4 = {0.f, 0.f, 0.f, 0.f};
  f32x4 acc[MFR][4];
#pragma unroll
  for (int m = 0; m < MFR; ++m)
#pragma unroll
    for (int n = 0; n < 4; ++n) acc[m][n] = zero4;

  int NT2 = K >> 6;
  stA(0, 0); stA(1, 0); stB(0, 0); stB(1, 0);
  stB(0, 1); stB(1, 1); stA(0, 1);
  wait_vmcnt<VMN>();
  barrier_raw();

  for (int kt = 0; kt < NT2; ++kt) {
    int p = kt & 1;
    const u16* Ah = lds + (p * 2 + wm) * HTA;
    const u16* Bh = lds + BOFF + (p * 2 + (wn >> 1)) * HTB;
    bf16x8 aR[QM][2], bR0[2][2], bR1[2][2];
    bool st1 = (kt + 1) < NT2, st2 = (kt + 2) < NT2;

#pragma unroll
    for (int m = 0; m < QM; ++m) {
      int r = m * 16 + lr;
#pragma unroll
      for (int kk = 0; kk < 2; ++kk)
        aR[m][kk] = *(const bf16x8*)(Ah + r * 64 + (((kk << 2) | lg) ^ xorslot) * 8);
    }
#pragma unroll
    for (int n = 0; n < 2; ++n) {
      int r = bcol + n * 16 + lr;
#pragma unroll
      for (int kk = 0; kk < 2; ++kk)
        bR0[n][kk] = *(const bf16x8*)(Bh + r * 64 + (((kk << 2) | lg) ^ xorslot) * 8);
    }
    if (st1) stA(1, kt + 1);
    lgkm0_pin();
    __builtin_amdgcn_s_setprio(1);
#pragma unroll
    for (int kk = 0; kk < 2; ++kk)
#pragma unroll
      for (int m = 0; m < QM; ++m)
#pragma unroll
        for (int n = 0; n < 2; ++n)
          acc[m][n] = __builtin_amdgcn_mfma_f32_16x16x32_bf16(aR[m][kk], bR0[n][kk], acc[m][n], 0, 0, 0);
    __builtin_amdgcn_s_setprio(0);
    barrier_raw();

#pragma unroll
    for (int n = 0; n < 2; ++n) {
      int r = bcol + 32 + n * 16 + lr;
#pragma unroll
      for (int kk = 0; kk < 2; ++kk)
        bR1[n][kk] = *(const bf16x8*)(Bh + r * 64 + (((kk << 2) | lg) ^ xorslot) * 8);
    }
    lgkm0_pin();
    __builtin_amdgcn_s_setprio(1);
#pragma unroll
    for (int kk = 0; kk < 2; ++kk)
#pragma unroll
      for (int m = 0; m < QM; ++m)
#pragma unroll
        for (int n = 0; n < 2; ++n)
          acc[m][2 + n] = __builtin_amdgcn_mfma_f32_16x16x32_bf16(aR[m][kk], bR1[n][kk], acc[m][2 + n], 0, 0, 0);
    __builtin_amdgcn_s_setprio(0);
    barrier_raw();

#pragma unroll
    for (int m = 0; m < QM; ++m) {
      int r = (BM / 4) + m * 16 + lr;
#pragma unroll
      for (int kk = 0; kk < 2; ++kk)
        aR[m][kk] = *(const bf16x8*)(Ah + r * 64 + (((kk << 2) | lg) ^ xorslot) * 8);
    }
    if (st2) { stB(0, kt + 2); stB(1, kt + 2); }
    lgkm0_pin();
    __builtin_amdgcn_s_setprio(1);
#pragma unroll
    for (int kk = 0; kk < 2; ++kk)
#pragma unroll
      for (int m = 0; m < QM; ++m)
#pragma unroll
        for (int n = 0; n < 2; ++n)
          acc[QM + m][2 + n] = __builtin_amdgcn_mfma_f32_16x16x32_bf16(aR[m][kk], bR1[n][kk], acc[QM + m][2 + n], 0, 0, 0);
    __builtin_amdgcn_s_setprio(0);
    barrier_raw();

    if (st2) stA(0, kt + 2);
    __builtin_amdgcn_s_setprio(1);
#pragma unroll
    for (int kk = 0; kk < 2; ++kk)
#pragma unroll
      for (int m = 0; m < QM; ++m)
#pragma unroll
        for (int n = 0; n < 2; ++n)
          acc[QM + m][n] = __builtin_amdgcn_mfma_f32_16x16x32_bf16(aR[m][kk], bR0[n][kk], acc[QM + m][n], 0, 0, 0);
    __builtin_amdgcn_s_setprio(0);
    if (st2) wait_vmcnt<VMN>(); else wait_vmcnt<0>();
    barrier_raw();
  }

  // ---- epilogue ----
#pragma unroll
  for (int mf = 0; mf < MFR; ++mf) {
    int row0 = m0 + wm * (BM / 2) + mf * 16 + lg * 4;
#pragma unroll
    for (int nf = 0; nf < 4; ++nf) {
      int col = n0 + wn * 64 + nf * 16 + lr;
      if constexpr (EPI == 0) {
        int sec = col >> sec_shift;
        const float* bp = sec == 0 ? bias0 : (sec == 1 ? bias1 : bias2);
        u16* op = sec == 0 ? o0 : (sec == 1 ? o1 : o2);
        int cs = col & ((1 << sec_shift) - 1);
        float bv = bp[cs];
#pragma unroll
        for (int r = 0; r < 4; ++r)
          op[(size_t)(row0 + r) * out_ld + cs] = f2bf(acc[mf][nf][r] + bv);
      } else if constexpr (EPI == 6) {
        float bv = bias0[col];
        float gt = gate_tab[col];
#pragma unroll
        for (int r = 0; r < 4; ++r) {
          int row = row0 + r;
          size_t idx = (size_t)row * N + col;
          float g = gt + gate_t[(size_t)row * (6 * C_DIM) + col];
          o0[idx] = f2bf(resid[idx] + g * (acc[mf][nf][r] + bv));
        }
      } else if constexpr (EPI == 7) {
        float bv = bias0[col];
#pragma unroll
        for (int r = 0; r < 4; ++r) {
          size_t idx = (size_t)(row0 + r) * N + col;
          o0[idx] = f2bf(bf2f(o0[idx]) + acc[mf][nf][r] + bv);
        }
      } else {  // EPI == 8
        float bv = bias0[col];
        float gt = gate_tab[col];
#pragma unroll
        for (int r = 0; r < 4; ++r) {
          int row = row0 + r;
          size_t idx = (size_t)row * N + col;
          float g = gt + gate_t[(size_t)row * (6 * C_DIM) + col];
          outF[idx] = bf2f(((const u16*)o1)[idx]) + g * (acc[mf][nf][r] + bv);
        }
      }
    }
  }
}

// ---------------- RoPE on q and k (in place, bf16; fast sincos) ------------
__global__ void k_rope(u16* __restrict__ q, u16* __restrict__ k,
                       const float* __restrict__ freqs) {
  int idx = blockIdx.x * blockDim.x + threadIdx.x;
  int total = L_ROWS * C_DIM / 8;
  for (; idx < total; idx += gridDim.x * blockDim.x) {
    int e = idx * 8;
    int row = e >> 11;
    int col = e & (C_DIM - 1);
    int s = row & (S_LEN - 1);
    int i0 = (col & (DH - 1)) >> 1;
    float4 fr = *(const float4*)(freqs + s * (DH / 2) + i0);
    float cs[4], sn[4];
    float fv[4] = {fr.x, fr.y, fr.z, fr.w};
#pragma unroll
    for (int j = 0; j < 4; ++j) __sincosf(fv[j], &sn[j], &cs[j]);
    us8 qa = *(us8*)(q + e);
    us8 ka = *(us8*)(k + e);
#pragma unroll
    for (int p = 0; p < 4; ++p) {
      float a = bf2f(qa[2 * p]), b = bf2f(qa[2 * p + 1]);
      qa[2 * p]     = f2bf(a * cs[p] - b * sn[p]);
      qa[2 * p + 1] = f2bf(a * sn[p] + b * cs[p]);
      float a2 = bf2f(ka[2 * p]), b2 = bf2f(ka[2 * p + 1]);
      ka[2 * p]     = f2bf(a2 * cs[p] - b2 * sn[p]);
      ka[2 * p + 1] = f2bf(a2 * sn[p] + b2 * cs[p]);
    }
    *(us8*)(q + e) = qa;
    *(us8*)(k + e) = ka;
  }
}

// ---------------- V transpose: [b*Lkv+kv][h*DH+d] -> [bh][d][kv] ----------------
__global__ void k_transpose_v(const u16* __restrict__ v, u16* __restrict__ vt, int Lkv) {
  __shared__ u16 tile[32][33];
  int bh = blockIdx.x, b = bh >> 4, h = bh & 15;
  int k0 = blockIdx.y * 32, d0 = blockIdx.z * 32;
  int tx = threadIdx.x, ty = threadIdx.y;
  const u16* src = v + (size_t)(b * Lkv) * C_DIM + h * DH;
#pragma unroll
  for (int j = 0; j < 32; j += 8)
    tile[ty + j][tx] = src[(size_t)(k0 + ty + j) * C_DIM + d0 + tx];
  __syncthreads();
  u16* dst = vt + (size_t)bh * DH * Lkv;
#pragma unroll
  for (int j = 0; j < 32; j += 8)
    dst[(size_t)(d0 + ty + j) * Lkv + k0 + tx] = tile[tx][ty + j];
}

// ---------------- flash attention ----------------
__global__ __launch_bounds__(256)
void k_flash(const u16* __restrict__ Q, const u16* __restrict__ K,
             const u16* __restrict__ Vt, u16* __restrict__ O,
             int Lq, int Lkv, float scale) {
  __shared__ __align__(16) u16 lK[64 * 128];
  __shared__ __align__(16) u16 lV[128 * 64];
  __shared__ __align__(16) u16 lP[4][16 * 72];
  int bh = blockIdx.x, b = bh >> 4, h = bh & 15;
  int tid = threadIdx.x, wid = tid >> 6, lane = tid & 63;
  int lr = lane & 15, lg = lane >> 4;
  int q0 = blockIdx.y * 64 + wid * 16;
  const u16* Qb = Q + ((size_t)(b * Lq) + q0) * C_DIM + h * DH;
  const u16* Kb = K + (size_t)(b * Lkv) * C_DIM + h * DH;
  const u16* Vb = Vt + (size_t)bh * DH * Lkv;

  bf16x8 qf[4];
#pragma unroll
  for (int ks = 0; ks < 4; ++ks)
    qf[ks] = *(const bf16x8*)(Qb + (size_t)lr * C_DIM + ks * 32 + lg * 8);

  f32x4 zero4 = {0.f, 0.f, 0.f, 0.f};
  f32x4 o[8];
#pragma unroll
  for (int n = 0; n < 8; ++n) o[n] = zero4;
  float mrow[4] = {-3.0e38f, -3.0e38f, -3.0e38f, -3.0e38f};
  float lrow[4] = {0.f, 0.f, 0.f, 0.f};

  int nsteps = Lkv >> 6;
  for (int kt = 0; kt < nsteps; ++kt) {
#pragma unroll
    for (int i = 0; i < 4; ++i) {
      int flat = i * 4096 + tid * 16;
      int key = flat >> 8, inner = flat & 255;
      int ksrc = inner ^ ((key & 7) << 4);
      gl_lds16((const char*)Kb + ((size_t)(kt * 64 + key) * C_DIM) * 2 + ksrc, (char*)lK + flat);
      int d = flat >> 7, keyb = flat & 127;
      int vsrc = keyb ^ ((d & 7) << 4);
      gl_lds16((const char*)Vb + ((size_t)d * Lkv) * 2 + kt * 128 + vsrc, (char*)lV + flat);
    }
    __syncthreads();

    f32x4 sc[4];
#pragma unroll
    for (int c = 0; c < 4; ++c) sc[c] = zero4;
#pragma unroll
    for (int c = 0; c < 4; ++c) {
      int key = c * 16 + lr;
#pragma unroll
      for (int ks = 0; ks < 4; ++ks) {
        int off = (ks * 64 + lg * 16) ^ ((key & 7) << 4);
        bf16x8 kf = *(const bf16x8*)((const char*)lK + key * 256 + off);
        sc[c] = __builtin_amdgcn_mfma_f32_16x16x32_bf16(qf[ks], kf, sc[c], 0, 0, 0);
      }
    }
#pragma unroll
    for (int r = 0; r < 4; ++r) {
      float s0 = sc[0][r] * scale, s1 = sc[1][r] * scale;
      float s2 = sc[2][r] * scale, s3 = sc[3][r] * scale;
      float mx = fmaxf(fmaxf(s0, s1), fmaxf(s2, s3));
#pragma unroll
      for (int m = 1; m < 16; m <<= 1) mx = fmaxf(mx, __shfl_xor(mx, m));
      float mnew = fmaxf(mrow[r], mx);
      float alpha = exp2f((mrow[r] - mnew) * 1.44269504f);
      mrow[r] = mnew;
      float p0 = exp2f((s0 - mnew) * 1.44269504f);
      float p1 = exp2f((s1 - mnew) * 1.44269504f);
      float p2 = exp2f((s2 - mnew) * 1.44269504f);
      float p3 = exp2f((s3 - mnew) * 1.44269504f);
      float psum = p0 + p1 + p2 + p3;
#pragma unroll
      for (int m = 1; m < 16; m <<= 1) psum += __shfl_xor(psum, m);
      lrow[r] = lrow[r] * alpha + psum;
#pragma unroll
      for (int n = 0; n < 8; ++n) o[n][r] *= alpha;
      u16* pr = lP[wid] + (4 * lg + r) * 72;
      pr[lr]      = f2bf(p0);
      pr[16 + lr] = f2bf(p1);
      pr[32 + lr] = f2bf(p2);
      pr[48 + lr] = f2bf(p3);
    }
    asm volatile("s_waitcnt lgkmcnt(0)" ::: "memory");
    __builtin_amdgcn_sched_barrier(0);
#pragma unroll
    for (int half = 0; half < 2; ++half) {
      bf16x8 pf = *(const bf16x8*)(lP[wid] + lr * 72 + half * 32 + lg * 8);
#pragma unroll
      for (int n = 0; n < 8; ++n) {
        int d = n * 16 + lr;
        int off = (half * 64 + lg * 16) ^ ((d & 7) << 4);
        bf16x8 vf = *(const bf16x8*)((const char*)lV + d * 128 + off);
        o[n] = __builtin_amdgcn_mfma_f32_16x16x32_bf16(pf, vf, o[n], 0, 0, 0);
      }
    }
    __syncthreads();
  }

  u16* Ob = O + ((size_t)(b * Lq) + q0) * C_DIM + h * DH;
#pragma unroll
  for (int n = 0; n < 8; ++n) {
    int d = n * 16 + lr;
#pragma unroll
    for (int r = 0; r < 4; ++r) {
      int qr = 4 * lg + r;
      Ob[(size_t)qr * C_DIM + d] = f2bf(o[n][r] / lrow[r]);
    }
  }
}

// ---------------- host ----------------
extern "C" void kernel_launch(void* const* d_in, const int* in_sizes, int n_in,
                              void* d_out, int out_size, void* d_ws, size_t ws_size,
                              hipStream_t stream) {
  const float* x     = (const float*)d_in[0];
  const float* y     = (const float*)d_in[1];
  const float* t     = (const float*)d_in[2];
  const float* freqs = (const float*)d_in[3];
  const float* tab   = (const float*)d_in[4];
  const float* Wq_s = (const float*)d_in[5];
  const float* bq_s = (const float*)d_in[6];
  const float* Wk_s = (const float*)d_in[7];
  const float* bk_s = (const float*)d_in[8];
  const float* Wv_s = (const float*)d_in[9];
  const float* bv_s = (const float*)d_in[10];
  const float* Wo_s = (const float*)d_in[11];
  const float* bo_s = (const float*)d_in[12];
  const float* Wq_c = (const float*)d_in[13];
  const float* bq_c = (const float*)d_in[14];
  const float* Wk_c = (const float*)d_in[15];
  const float* bk_c = (const float*)d_in[16];
  const float* Wv_c = (const float*)d_in[17];
  const float* bv_c = (const float*)d_in[18];
  const float* Wo_c = (const float*)d_in[19];
  const float* bo_c = (const float*)d_in[20];
  const float* W_fc1 = (const float*)d_in[21];
  const float* b_fc1 = (const float*)d_in[22];
  const float* W_fc2 = (const float*)d_in[23];
  const float* b_fc2 = (const float*)d_in[24];

  const size_t SZ_CC  = (size_t)C_DIM * C_DIM * 2;
  const size_t SZ_FC  = (size_t)F_DIM * C_DIM * 2;
  const size_t SZ_LC  = (size_t)L_ROWS * C_DIM * 2;
  const size_t SZ_YC  = (size_t)LY_ROWS * C_DIM * 2;
  char* ws = (char*)d_ws;
  size_t off = 0;
  u16* wq_s = (u16*)(ws + off); off += SZ_CC;   // wq_s..wv_s contiguous = QKV concat
  u16* wk_s = (u16*)(ws + off); off += SZ_CC;
  u16* wv_s = (u16*)(ws + off); off += SZ_CC;
  u16* wo_s = (u16*)(ws + off); off += SZ_CC;
  u16* wq_c = (u16*)(ws + off); off += SZ_CC;
  u16* wk_c = (u16*)(ws + off); off += SZ_CC;   // wk_c,wv_c contiguous = KV concat
  u16* wv_c = (u16*)(ws + off); off += SZ_CC;
  u16* wo_c = (u16*)(ws + off); off += SZ_CC;
  u16* wfc1 = (u16*)(ws + off); off += SZ_FC;
  u16* wfc2 = (u16*)(ws + off); off += SZ_FC;
  u16* ybf  = (u16*)(ws + off); off += SZ_YC;
  u16* xm   = (u16*)(ws + off); off += SZ_LC;
  u16* qb   = (u16*)(ws + off); off += SZ_LC;
  u16* kb   = (u16*)(ws + off); off += SZ_LC;
  u16* vb   = (u16*)(ws + off); off += SZ_LC;
  u16* ao   = (u16*)(ws + off); off += SZ_LC;
  u16* hbuf = qb;                               // [L, F] bf16 overlay (qb..ao)
  u16* x1bf = (u16*)(ws + off); off += SZ_LC;   // bf16 residual stream
  u16* kc   = (u16*)(ws + off); off += SZ_YC;
  u16* vc   = (u16*)(ws + off); off += SZ_YC;
  u16* vt   = (u16*)(ws + off); off += SZ_LC;
  u16* vtc  = (u16*)(ws + off); off += SZ_YC;
  if (ws_size < off) return;

  auto cvt = [&](const float* s, u16* d, int n) {
    int blocks = (n / 4 + 255) / 256; if (blocks > 4096) blocks = 4096;
    k_cvt<<<blocks, 256, 0, stream>>>(s, d, n);
  };
  cvt(Wq_s, wq_s, C_DIM * C_DIM);
  cvt(Wk_s, wk_s, C_DIM * C_DIM);
  cvt(Wv_s, wv_s, C_DIM * C_DIM);
  cvt(Wo_s, wo_s, C_DIM * C_DIM);
  cvt(Wq_c, wq_c, C_DIM * C_DIM);
  cvt(Wk_c, wk_c, C_DIM * C_DIM);
  cvt(Wv_c, wv_c, C_DIM * C_DIM);
  cvt(Wo_c, wo_c, C_DIM * C_DIM);
  cvt(W_fc1, wfc1, F_DIM * C_DIM);
  cvt(W_fc2, wfc2, F_DIM * C_DIM);
  cvt(y, ybf, LY_ROWS * C_DIM);

  const float ascale = 0.08838834764831845f;

  k_modln<0><<<L_ROWS, 256, 0, stream>>>(x, t, tab, xm, 1, 0);
  // fused self QKV: N = 6144 (8-phase 256x256)
  k_gemm5<0><<<16 * 24, 512, 0, stream>>>(
      xm, wq_s, bq_s, bk_s, bv_s, qb, kb, vb, 11, C_DIM,
      L_ROWS, 6144, C_DIM, C_DIM, C_DIM, 24);
  k_rope<<<2048, 256, 0, stream>>>(qb, kb, freqs);
  k_transpose_v<<<dim3(B_SZ * H_NUM, S_LEN / 32, DH / 32), dim3(32, 8), 0, stream>>>(vb, vt, S_LEN);
  k_flash<<<dim3(B_SZ * H_NUM, S_LEN / 64), 256, 0, stream>>>(qb, kb, vt, ao, S_LEN, S_LEN, ascale);
  // x1bf = bf16(x + gate_msa*(ao@Wo_s^T+bo_s))
  k_gemm3<128, 6><<<32 * 8, 512, 0, stream>>>(
      ao, wo_s, bo_s, nullptr, nullptr, x1bf, nullptr, nullptr, 30, C_DIM,
      nullptr, x, t + 2 * C_DIM, tab + 2 * C_DIM, L_ROWS, C_DIM, C_DIM, C_DIM, C_DIM, 8);
  // cross q
  k_gemm3<128, 0><<<32 * 8, 512, 0, stream>>>(
      x1bf, wq_c, bq_c, nullptr, nullptr, qb, nullptr, nullptr, 30, C_DIM,
      nullptr, nullptr, nullptr, nullptr, L_ROWS, C_DIM, C_DIM, C_DIM, C_DIM, 8);
  // fused cross KV: N = 4096
  k_gemm3<128, 0><<<8 * 16, 512, 0, stream>>>(
      ybf, wk_c, bk_c, bv_c, bv_c, kc, vc, vc, 11, C_DIM,
      nullptr, nullptr, nullptr, nullptr, LY_ROWS, 4096, C_DIM, C_DIM, C_DIM, 16);
  k_transpose_v<<<dim3(B_SZ * H_NUM, T_LEN / 32, DH / 32), dim3(32, 8), 0, stream>>>(vc, vtc, T_LEN);
  k_flash<<<dim3(B_SZ * H_NUM, S_LEN / 64), 256, 0, stream>>>(qb, kc, vtc, ao, S_LEN, T_LEN, ascale);
  // x1bf += ao@Wo_c^T + bo_c  (in-place bf16 RMW)
  k_gemm3<128, 7><<<32 * 8, 512, 0, stream>>>(
      ao, wo_c, bo_c, nullptr, nullptr, x1bf, nullptr, nullptr, 30, C_DIM,
      nullptr, nullptr, nullptr, nullptr, L_ROWS, C_DIM, C_DIM, C_DIM, C_DIM, 8);
  // MLP
  k_modln<1><<<L_ROWS, 256, 0, stream>>>(x1bf, t, tab, xm, 4, 3);
  k_gemm5<1><<<16 * 32, 512, 0, stream>>>(
      xm, wfc1, b_fc1, nullptr, nullptr, hbuf, nullptr, nullptr, 30, F_DIM,
      L_ROWS, F_DIM, C_DIM, C_DIM, C_DIM, 32);
  // fc2 final: d_out = x1bf + gate_mlp*(h@W_fc2^T + b_fc2)  (fp32 out)
  k_gemm3<128, 8><<<32 * 8, 512, 0, stream>>>(
      hbuf, wfc2, b_fc2, nullptr, nullptr, nullptr, x1bf, nullptr, 30, C_DIM,
      (float*)d_out, nullptr, t + 5 * C_DIM, tab + 5 * C_DIM, L_ROWS, C_DIM, F_DIM, F_DIM, F_DIM, 8);
}

// Round 10
// 843.031 us; speedup vs baseline: 1.1336x; 1.0160x over previous
//
#include <hip/hip_runtime.h>
#include <stdint.h>

#define C_DIM 2048
#define H_NUM 16
#define DH    128
#define S_LEN 1024
#define T_LEN 256
#define B_SZ  4
#define L_ROWS 4096   // B*S
#define LY_ROWS 1024  // B*T
#define F_DIM 8192

typedef __attribute__((ext_vector_type(4))) float f32x4;
typedef __attribute__((ext_vector_type(8))) __bf16 bf16x8;
typedef __attribute__((ext_vector_type(4))) unsigned short us4;
typedef __attribute__((ext_vector_type(8))) unsigned short us8;
typedef unsigned short u16;

__device__ __forceinline__ u16 f2bf(float f) {
  union { float f; uint32_t u; } v; v.f = f;
  uint32_t r = v.u + 0x7FFFu + ((v.u >> 16) & 1u);
  return (u16)(r >> 16);
}
__device__ __forceinline__ float bf2f(u16 h) {
  union { uint32_t u; float f; } v; v.u = ((uint32_t)h) << 16;
  return v.f;
}

typedef __attribute__((address_space(1))) void gvoid;
typedef __attribute__((address_space(3))) void lvoid;
__device__ __forceinline__ void gl_lds16(const void* g, void* l) {
  __builtin_amdgcn_global_load_lds((gvoid*)g, (lvoid*)l, 16, 0, 0);
}

template<int N> __device__ __forceinline__ void wait_vmcnt() {
  if constexpr (N == 0) asm volatile("s_waitcnt vmcnt(0)" ::: "memory");
  else if constexpr (N == 4) asm volatile("s_waitcnt vmcnt(4)" ::: "memory");
  else if constexpr (N == 5) asm volatile("s_waitcnt vmcnt(5)" ::: "memory");
  else if constexpr (N == 6) asm volatile("s_waitcnt vmcnt(6)" ::: "memory");
}
__device__ __forceinline__ void barrier_raw() {
  asm volatile("s_barrier" ::: "memory");
}
__device__ __forceinline__ void lgkm0_pin() {
  asm volatile("s_waitcnt lgkmcnt(0)" ::: "memory");
  __builtin_amdgcn_sched_barrier(0);
}

__device__ __forceinline__ float gelu_fast(float val) {
  float z = 0.7978845608f * (val + 0.044715f * val * val * val);
  float e = __expf(2.f * z);
  float th = 1.f - 2.f / (e + 1.f);
  return 0.5f * val * (1.f + th);
}

// ---------------- fp32 -> bf16 conversion ----------------
__global__ void k_cvt(const float* __restrict__ src, u16* __restrict__ dst, int n) {
  int i = (blockIdx.x * blockDim.x + threadIdx.x) * 4;
  int stride = gridDim.x * blockDim.x * 4;
  for (; i < n; i += stride) {
    float4 v = *(const float4*)(src + i);
    us4 o;
    o[0] = f2bf(v.x); o[1] = f2bf(v.y); o[2] = f2bf(v.z); o[3] = f2bf(v.w);
    *(us4*)(dst + i) = o;
  }
}

// 8 C*C (2^22-elem) fp32 tensors -> one contiguous bf16 region
__global__ void k_cvt8(const float* __restrict__ s0, const float* __restrict__ s1,
                       const float* __restrict__ s2, const float* __restrict__ s3,
                       const float* __restrict__ s4, const float* __restrict__ s5,
                       const float* __restrict__ s6, const float* __restrict__ s7,
                       u16* __restrict__ dst) {
  const int PER = C_DIM * C_DIM;          // 2^22
  int i = (blockIdx.x * blockDim.x + threadIdx.x) * 4;
  int stride = gridDim.x * blockDim.x * 4;
  int total = PER * 8;
  for (; i < total; i += stride) {
    int t = i >> 22;
    const float* s;
    switch (t) {
      case 0: s = s0; break; case 1: s = s1; break;
      case 2: s = s2; break; case 3: s = s3; break;
      case 4: s = s4; break; case 5: s = s5; break;
      case 6: s = s6; break; default: s = s7; break;
    }
    float4 v = *(const float4*)(s + (i & (PER - 1)));
    us4 o;
    o[0] = f2bf(v.x); o[1] = f2bf(v.y); o[2] = f2bf(v.z); o[3] = f2bf(v.w);
    *(us4*)(dst + i) = o;
  }
}

// 2 F*C (2^24-elem) fp32 tensors -> contiguous bf16 (wfc1; wfc2)
__global__ void k_cvt2(const float* __restrict__ s0, const float* __restrict__ s1,
                       u16* __restrict__ dst) {
  const int PER = F_DIM * C_DIM;          // 2^24
  int i = (blockIdx.x * blockDim.x + threadIdx.x) * 4;
  int stride = gridDim.x * blockDim.x * 4;
  int total = PER * 2;
  for (; i < total; i += stride) {
    const float* s = (i >> 24) ? s1 : s0;
    float4 v = *(const float4*)(s + (i & (PER - 1)));
    us4 o;
    o[0] = f2bf(v.x); o[1] = f2bf(v.y); o[2] = f2bf(v.z); o[3] = f2bf(v.w);
    *(us4*)(dst + i) = o;
  }
}

// ---------------- LN + adaLN modulation (fp32 or bf16 input) ----------------
template<int INBF>
__global__ __launch_bounds__(256)
void k_modln(const void* __restrict__ xin, const float* __restrict__ t,
             const float* __restrict__ tab, u16* __restrict__ out,
             int scale_idx, int shift_idx) {
  int row = blockIdx.x;
  int tid = threadIdx.x;
  int c0 = tid * 8;
  float v[8];
  if constexpr (INBF) {
    us8 a = *(const us8*)((const u16*)xin + (size_t)row * C_DIM + c0);
#pragma unroll
    for (int j = 0; j < 8; ++j) v[j] = bf2f(a[j]);
  } else {
    const float* xr = (const float*)xin + (size_t)row * C_DIM;
    float4 a = *(const float4*)(xr + c0);
    float4 b = *(const float4*)(xr + c0 + 4);
    v[0] = a.x; v[1] = a.y; v[2] = a.z; v[3] = a.w;
    v[4] = b.x; v[5] = b.y; v[6] = b.z; v[7] = b.w;
  }
  float s = 0.f, ss = 0.f;
#pragma unroll
  for (int j = 0; j < 8; ++j) { s += v[j]; ss += v[j] * v[j]; }
#pragma unroll
  for (int m = 1; m < 64; m <<= 1) { s += __shfl_xor(s, m); ss += __shfl_xor(ss, m); }
  __shared__ float red[8];
  int wid = tid >> 6;
  if ((tid & 63) == 0) { red[wid * 2] = s; red[wid * 2 + 1] = ss; }
  __syncthreads();
  s  = red[0] + red[2] + red[4] + red[6];
  ss = red[1] + red[3] + red[5] + red[7];
  float mean = s * (1.f / C_DIM);
  float var  = ss * (1.f / C_DIM) - mean * mean;
  float rstd = rsqrtf(var + 1e-6f);
  const float* trow = t + (size_t)row * (6 * C_DIM);
  const float* tsc = trow + scale_idx * C_DIM + c0;
  const float* tsh = trow + shift_idx * C_DIM + c0;
  const float* gsc = tab + scale_idx * C_DIM + c0;
  const float* gsh = tab + shift_idx * C_DIM + c0;
  us8 o;
#pragma unroll
  for (int j = 0; j < 8; ++j) {
    float scv = 1.f + gsc[j] + tsc[j];
    float shv = gsh[j] + tsh[j];
    o[j] = f2bf((v[j] - mean) * rstd * scv + shv);
  }
  *(us8*)(out + (size_t)row * C_DIM + c0) = o;
}

// ======== GEMM v5b: 256x256 tile, BK=64, 2 K-tiles/iter, 8-phase ============
// (R8-proven ledger.) EPI 0: bf16(acc+bias)->o{0,1,2}; EPI 1: fast-gelu->o0.
template<int EPI>
__global__ __launch_bounds__(512, 2)
void k_gemm5(const u16* __restrict__ A, const u16* __restrict__ W,
             const float* __restrict__ bias0, const float* __restrict__ bias1,
             const float* __restrict__ bias2,
             u16* __restrict__ o0, u16* __restrict__ o1, u16* __restrict__ o2,
             int sec_shift, int out_ld,
             int M, int N, int K, int lda, int ldw, int nbx) {
  __shared__ __align__(16) u16 lds[65536];

  int tid = threadIdx.x;
  int nwg = gridDim.x;
  int q8 = nwg >> 3, r8 = nwg & 7;
  int xcd = blockIdx.x & 7, local = blockIdx.x >> 3;
  int wgid = (xcd < r8 ? xcd * (q8 + 1) : r8 * (q8 + 1) + (xcd - r8) * q8) + local;
  int bx = wgid % nbx, by = wgid / nbx;
  int m0 = by * 256, n0 = bx * 256;

  int wid = tid >> 6, lane = tid & 63;
  int wm = wid >> 2, wn = wid & 3;
  int lr = lane & 15, lg = lane >> 4;
  int xorslot = lr & 7;
  int bcol = (wn & 1) * 64;

  int srow = tid >> 3;
  int scol = ((tid ^ (tid >> 3)) & 7) * 8;

  auto stA = [&](int buf, int h, int kt) {
    u16* dst = lds + (buf * 2 + h) * 8192 + tid * 8;
#pragma unroll
    for (int call = 0; call < 2; ++call) {
      int grow = m0 + h * 128 + call * 64 + srow;
      gl_lds16(A + (size_t)grow * lda + kt * 64 + scol, dst + call * 4096);
    }
  };
  auto stB = [&](int buf, int h, int kt) {
    u16* dst = lds + 32768 + (buf * 2 + h) * 8192 + tid * 8;
#pragma unroll
    for (int call = 0; call < 2; ++call) {
      int grow = n0 + h * 128 + call * 64 + srow;
      gl_lds16(W + (size_t)grow * ldw + kt * 64 + scol, dst + call * 4096);
    }
  };

  f32x4 zero4 = {0.f, 0.f, 0.f, 0.f};
  f32x4 acc[8][4];
#pragma unroll
  for (int m = 0; m < 8; ++m)
#pragma unroll
    for (int n = 0; n < 4; ++n) acc[m][n] = zero4;

  int NT = K >> 6, NJ = NT >> 1;
  stA(0, 0, 0); stA(0, 1, 0); stB(0, 0, 0); stB(0, 1, 0);
  stB(1, 0, 1); stA(1, 0, 1);
  wait_vmcnt<4>();
  barrier_raw();

  for (int j = 0; j < NJ; ++j) {
    bool nlast = (j + 1 < NJ);
    int t1 = 2 * j + 1, t2 = 2 * j + 2, t3 = 2 * j + 3;
#pragma unroll
    for (int buf = 0; buf < 2; ++buf) {
      const u16* Ah = lds + (buf * 2 + wm) * 8192;
      const u16* Bh = lds + 32768 + (buf * 2 + (wn >> 1)) * 8192;
      bf16x8 aR[4][2], b0[2][2], b1[2][2];

#pragma unroll
      for (int m = 0; m < 4; ++m) {
        int r = m * 16 + lr;
#pragma unroll
        for (int kk = 0; kk < 2; ++kk)
          aR[m][kk] = *(const bf16x8*)(Ah + r * 64 + (((kk << 2) | lg) ^ xorslot) * 8);
      }
#pragma unroll
      for (int n = 0; n < 2; ++n) {
        int r = bcol + n * 16 + lr;
#pragma unroll
        for (int kk = 0; kk < 2; ++kk)
          b0[n][kk] = *(const bf16x8*)(Bh + r * 64 + (((kk << 2) | lg) ^ xorslot) * 8);
      }
      if (buf == 0) stA(1, 1, t1);
      else if (nlast) stA(0, 1, t2);
      barrier_raw();
      lgkm0_pin();
      __builtin_amdgcn_s_setprio(1);
#pragma unroll
      for (int kk = 0; kk < 2; ++kk)
#pragma unroll
        for (int m = 0; m < 4; ++m)
#pragma unroll
          for (int n = 0; n < 2; ++n)
            acc[m][n] = __builtin_amdgcn_mfma_f32_16x16x32_bf16(aR[m][kk], b0[n][kk], acc[m][n], 0, 0, 0);
      __builtin_amdgcn_s_setprio(0);
      barrier_raw();

#pragma unroll
      for (int n = 0; n < 2; ++n) {
        int r = bcol + 32 + n * 16 + lr;
#pragma unroll
        for (int kk = 0; kk < 2; ++kk)
          b1[n][kk] = *(const bf16x8*)(Bh + r * 64 + (((kk << 2) | lg) ^ xorslot) * 8);
      }
      if (buf == 0) stB(1, 1, t1);
      else if (nlast) stB(0, 1, t2);
      barrier_raw();
      lgkm0_pin();
      __builtin_amdgcn_s_setprio(1);
#pragma unroll
      for (int kk = 0; kk < 2; ++kk)
#pragma unroll
        for (int m = 0; m < 4; ++m)
#pragma unroll
          for (int n = 0; n < 2; ++n)
            acc[m][2 + n] = __builtin_amdgcn_mfma_f32_16x16x32_bf16(aR[m][kk], b1[n][kk], acc[m][2 + n], 0, 0, 0);
      __builtin_amdgcn_s_setprio(0);
      barrier_raw();

#pragma unroll
      for (int m = 0; m < 4; ++m) {
        int r = 64 + m * 16 + lr;
#pragma unroll
        for (int kk = 0; kk < 2; ++kk)
          aR[m][kk] = *(const bf16x8*)(Ah + r * 64 + (((kk << 2) | lg) ^ xorslot) * 8);
      }
      if (nlast) { if (buf == 0) stB(0, 0, t2); else stB(1, 0, t3); }
      barrier_raw();
      lgkm0_pin();
      __builtin_amdgcn_s_setprio(1);
#pragma unroll
      for (int kk = 0; kk < 2; ++kk)
#pragma unroll
        for (int m = 0; m < 4; ++m)
#pragma unroll
          for (int n = 0; n < 2; ++n)
            acc[4 + m][2 + n] = __builtin_amdgcn_mfma_f32_16x16x32_bf16(aR[m][kk], b1[n][kk], acc[4 + m][2 + n], 0, 0, 0);
      __builtin_amdgcn_s_setprio(0);
      barrier_raw();

      if (nlast) { if (buf == 0) stA(0, 0, t2); else stA(1, 0, t3); }
      barrier_raw();
      __builtin_amdgcn_s_setprio(1);
#pragma unroll
      for (int kk = 0; kk < 2; ++kk)
#pragma unroll
        for (int m = 0; m < 4; ++m)
#pragma unroll
          for (int n = 0; n < 2; ++n)
            acc[4 + m][n] = __builtin_amdgcn_mfma_f32_16x16x32_bf16(aR[m][kk], b0[n][kk], acc[4 + m][n], 0, 0, 0);
      __builtin_amdgcn_s_setprio(0);
      if (nlast) wait_vmcnt<4>(); else wait_vmcnt<0>();
      barrier_raw();
    }
  }

#pragma unroll
  for (int mf = 0; mf < 8; ++mf) {
    int row0 = m0 + wm * 128 + mf * 16 + lg * 4;
#pragma unroll
    for (int nf = 0; nf < 4; ++nf) {
      int col = n0 + wn * 64 + nf * 16 + lr;
      if constexpr (EPI == 0) {
        int sec = col >> sec_shift;
        const float* bp = sec == 0 ? bias0 : (sec == 1 ? bias1 : bias2);
        u16* op = sec == 0 ? o0 : (sec == 1 ? o1 : o2);
        int cs = col & ((1 << sec_shift) - 1);
        float bv = bp[cs];
#pragma unroll
        for (int r = 0; r < 4; ++r)
          op[(size_t)(row0 + r) * out_ld + cs] = f2bf(acc[mf][nf][r] + bv);
      } else {
        float bv = bias0[col];
#pragma unroll
        for (int r = 0; r < 4; ++r)
          o0[(size_t)(row0 + r) * out_ld + col] = f2bf(gelu_fast(acc[mf][nf][r] + bv));
      }
    }
  }
}

// ======== GEMM v3c: BMx256, BK=64, 4-phase, 3-bit swizzle (R5-proven) ======
// EPI 0: bf16(acc+bias)->o{0,1,2} split by col>>sec_shift
// EPI 6: o0 = bf16(residF + gate*(acc+bias))              (wo_s -> x1bf)
// EPI 7: o0 = bf16(bf2f(o0) + acc + bias)  in-place RMW   (wo_c)
// EPI 8: outF = bf2f(o1[idx]) + gate*(acc+bias)           (fc2 final fp32)
template<int BM, int EPI>
__global__ __launch_bounds__(512, 2)
void k_gemm3(const u16* __restrict__ A, const u16* __restrict__ W,
             const float* __restrict__ bias0, const float* __restrict__ bias1,
             const float* __restrict__ bias2,
             u16* __restrict__ o0, u16* __restrict__ o1, u16* __restrict__ o2,
             int sec_shift, int out_ld,
             float* __restrict__ outF, const float* __restrict__ resid,
             const float* __restrict__ gate_t, const float* __restrict__ gate_tab,
             int M, int N, int K, int lda, int ldw, int nbx) {
  constexpr int HTA = (BM / 2) * 64;
  constexpr int HTB = 128 * 64;
  constexpr int ACALLS = BM / 128;
  constexpr int QM = BM / 64;
  constexpr int MFR = BM / 32;
  constexpr int VMN = 4 + ACALLS;
  constexpr int BOFF = 4 * HTA;
  __shared__ __align__(16) u16 lds[BOFF + 4 * HTB];

  int tid = threadIdx.x;
  int nwg = gridDim.x;
  int q8 = nwg >> 3, r8 = nwg & 7;
  int xcd = blockIdx.x & 7, local = blockIdx.x >> 3;
  int wgid = (xcd < r8 ? xcd * (q8 + 1) : r8 * (q8 + 1) + (xcd - r8) * q8) + local;
  int bx = wgid % nbx, by = wgid / nbx;
  int m0 = by * BM, n0 = bx * 256;

  int wid = tid >> 6, lane = tid & 63;
  int wm = wid >> 2, wn = wid & 3;
  int lr = lane & 15, lg = lane >> 4;
  int xorslot = lr & 7;
  int bcol = (wn & 1) * 64;

  int srow = tid >> 3;
  int scol = ((tid ^ (tid >> 3)) & 7) * 8;

  auto stA = [&](int h, int kt2) {
    int pt = kt2 & 1;
    u16* dst = lds + (pt * 2 + h) * HTA + tid * 8;
#pragma unroll
    for (int call = 0; call < ACALLS; ++call) {
      int grow = m0 + h * (BM / 2) + call * 64 + srow;
      gl_lds16(A + (size_t)grow * lda + kt2 * 64 + scol, dst + call * 4096);
    }
  };
  auto stB = [&](int h, int kt2) {
    int pt = kt2 & 1;
    u16* dst = lds + BOFF + (pt * 2 + h) * HTB + tid * 8;
#pragma unroll
    for (int call = 0; call < 2; ++call) {
      int grow = n0 + h * 128 + call * 64 + srow;
      gl_lds16(W + (size_t)grow * ldw + kt2 * 64 + scol, dst + call * 4096);
    }
  };

  f32x4 zero4 = {0.f, 0.f, 0.f, 0.f};
  f32x4 acc[MFR][4];
#pragma unroll
  for (int m = 0; m < MFR; ++m)
#pragma unroll
    for (int n = 0; n < 4; ++n) acc[m][n] = zero4;

  int NT2 = K >> 6;
  stA(0, 0); stA(1, 0); stB(0, 0); stB(1, 0);
  stB(0, 1); stB(1, 1); stA(0, 1);
  wait_vmcnt<VMN>();
  barrier_raw();

  for (int kt = 0; kt < NT2; ++kt) {
    int p = kt & 1;
    const u16* Ah = lds + (p * 2 + wm) * HTA;
    const u16* Bh = lds + BOFF + (p * 2 + (wn >> 1)) * HTB;
    bf16x8 aR[QM][2], bR0[2][2], bR1[2][2];
    bool st1 = (kt + 1) < NT2, st2 = (kt + 2) < NT2;

#pragma unroll
    for (int m = 0; m < QM; ++m) {
      int r = m * 16 + lr;
#pragma unroll
      for (int kk = 0; kk < 2; ++kk)
        aR[m][kk] = *(const bf16x8*)(Ah + r * 64 + (((kk << 2) | lg) ^ xorslot) * 8);
    }
#pragma unroll
    for (int n = 0; n < 2; ++n) {
      int r = bcol + n * 16 + lr;
#pragma unroll
      for (int kk = 0; kk < 2; ++kk)
        bR0[n][kk] = *(const bf16x8*)(Bh + r * 64 + (((kk << 2) | lg) ^ xorslot) * 8);
    }
    if (st1) stA(1, kt + 1);
    lgkm0_pin();
    __builtin_amdgcn_s_setprio(1);
#pragma unroll
    for (int kk = 0; kk < 2; ++kk)
#pragma unroll
      for (int m = 0; m < QM; ++m)
#pragma unroll
        for (int n = 0; n < 2; ++n)
          acc[m][n] = __builtin_amdgcn_mfma_f32_16x16x32_bf16(aR[m][kk], bR0[n][kk], acc[m][n], 0, 0, 0);
    __builtin_amdgcn_s_setprio(0);
    barrier_raw();

#pragma unroll
    for (int n = 0; n < 2; ++n) {
      int r = bcol + 32 + n * 16 + lr;
#pragma unroll
      for (int kk = 0; kk < 2; ++kk)
        bR1[n][kk] = *(const bf16x8*)(Bh + r * 64 + (((kk << 2) | lg) ^ xorslot) * 8);
    }
    lgkm0_pin();
    __builtin_amdgcn_s_setprio(1);
#pragma unroll
    for (int kk = 0; kk < 2; ++kk)
#pragma unroll
      for (int m = 0; m < QM; ++m)
#pragma unroll
        for (int n = 0; n < 2; ++n)
          acc[m][2 + n] = __builtin_amdgcn_mfma_f32_16x16x32_bf16(aR[m][kk], bR1[n][kk], acc[m][2 + n], 0, 0, 0);
    __builtin_amdgcn_s_setprio(0);
    barrier_raw();

#pragma unroll
    for (int m = 0; m < QM; ++m) {
      int r = (BM / 4) + m * 16 + lr;
#pragma unroll
      for (int kk = 0; kk < 2; ++kk)
        aR[m][kk] = *(const bf16x8*)(Ah + r * 64 + (((kk << 2) | lg) ^ xorslot) * 8);
    }
    if (st2) { stB(0, kt + 2); stB(1, kt + 2); }
    lgkm0_pin();
    __builtin_amdgcn_s_setprio(1);
#pragma unroll
    for (int kk = 0; kk < 2; ++kk)
#pragma unroll
      for (int m = 0; m < QM; ++m)
#pragma unroll
        for (int n = 0; n < 2; ++n)
          acc[QM + m][2 + n] = __builtin_amdgcn_mfma_f32_16x16x32_bf16(aR[m][kk], bR1[n][kk], acc[QM + m][2 + n], 0, 0, 0);
    __builtin_amdgcn_s_setprio(0);
    barrier_raw();

    if (st2) stA(0, kt + 2);
    __builtin_amdgcn_s_setprio(1);
#pragma unroll
    for (int kk = 0; kk < 2; ++kk)
#pragma unroll
      for (int m = 0; m < QM; ++m)
#pragma unroll
        for (int n = 0; n < 2; ++n)
          acc[QM + m][n] = __builtin_amdgcn_mfma_f32_16x16x32_bf16(aR[m][kk], bR0[n][kk], acc[QM + m][n], 0, 0, 0);
    __builtin_amdgcn_s_setprio(0);
    if (st2) wait_vmcnt<VMN>(); else wait_vmcnt<0>();
    barrier_raw();
  }

  // ---- epilogue ----
#pragma unroll
  for (int mf = 0; mf < MFR; ++mf) {
    int row0 = m0 + wm * (BM / 2) + mf * 16 + lg * 4;
#pragma unroll
    for (int nf = 0; nf < 4; ++nf) {
      int col = n0 + wn * 64 + nf * 16 + lr;
      if constexpr (EPI == 0) {
        int sec = col >> sec_shift;
        const float* bp = sec == 0 ? bias0 : (sec == 1 ? bias1 : bias2);
        u16* op = sec == 0 ? o0 : (sec == 1 ? o1 : o2);
        int cs = col & ((1 << sec_shift) - 1);
        float bv = bp[cs];
#pragma unroll
        for (int r = 0; r < 4; ++r)
          op[(size_t)(row0 + r) * out_ld + cs] = f2bf(acc[mf][nf][r] + bv);
      } else if constexpr (EPI == 6) {
        float bv = bias0[col];
        float gt = gate_tab[col];
#pragma unroll
        for (int r = 0; r < 4; ++r) {
          int row = row0 + r;
          size_t idx = (size_t)row * N + col;
          float g = gt + gate_t[(size_t)row * (6 * C_DIM) + col];
          o0[idx] = f2bf(resid[idx] + g * (acc[mf][nf][r] + bv));
        }
      } else if constexpr (EPI == 7) {
        float bv = bias0[col];
#pragma unroll
        for (int r = 0; r < 4; ++r) {
          size_t idx = (size_t)(row0 + r) * N + col;
          o0[idx] = f2bf(bf2f(o0[idx]) + acc[mf][nf][r] + bv);
        }
      } else {  // EPI == 8
        float bv = bias0[col];
        float gt = gate_tab[col];
#pragma unroll
        for (int r = 0; r < 4; ++r) {
          int row = row0 + r;
          size_t idx = (size_t)row * N + col;
          float g = gt + gate_t[(size_t)row * (6 * C_DIM) + col];
          outF[idx] = bf2f(((const u16*)o1)[idx]) + g * (acc[mf][nf][r] + bv);
        }
      }
    }
  }
}

// ---------------- RoPE on q and k (in place, bf16; fast sincos) ------------
__global__ void k_rope(u16* __restrict__ q, u16* __restrict__ k,
                       const float* __restrict__ freqs) {
  int idx = blockIdx.x * blockDim.x + threadIdx.x;
  int total = L_ROWS * C_DIM / 8;
  for (; idx < total; idx += gridDim.x * blockDim.x) {
    int e = idx * 8;
    int row = e >> 11;
    int col = e & (C_DIM - 1);
    int s = row & (S_LEN - 1);
    int i0 = (col & (DH - 1)) >> 1;
    float4 fr = *(const float4*)(freqs + s * (DH / 2) + i0);
    float cs[4], sn[4];
    float fv[4] = {fr.x, fr.y, fr.z, fr.w};
#pragma unroll
    for (int j = 0; j < 4; ++j) __sincosf(fv[j], &sn[j], &cs[j]);
    us8 qa = *(us8*)(q + e);
    us8 ka = *(us8*)(k + e);
#pragma unroll
    for (int p = 0; p < 4; ++p) {
      float a = bf2f(qa[2 * p]), b = bf2f(qa[2 * p + 1]);
      qa[2 * p]     = f2bf(a * cs[p] - b * sn[p]);
      qa[2 * p + 1] = f2bf(a * sn[p] + b * cs[p]);
      float a2 = bf2f(ka[2 * p]), b2 = bf2f(ka[2 * p + 1]);
      ka[2 * p]     = f2bf(a2 * cs[p] - b2 * sn[p]);
      ka[2 * p + 1] = f2bf(a2 * sn[p] + b2 * cs[p]);
    }
    *(us8*)(q + e) = qa;
    *(us8*)(k + e) = ka;
  }
}

// ---------------- V transpose: [b*Lkv+kv][h*DH+d] -> [bh][d][kv] ----------------
__global__ void k_transpose_v(const u16* __restrict__ v, u16* __restrict__ vt, int Lkv) {
  __shared__ u16 tile[32][33];
  int bh = blockIdx.x, b = bh >> 4, h = bh & 15;
  int k0 = blockIdx.y * 32, d0 = blockIdx.z * 32;
  int tx = threadIdx.x, ty = threadIdx.y;
  const u16* src = v + (size_t)(b * Lkv) * C_DIM + h * DH;
#pragma unroll
  for (int j = 0; j < 32; j += 8)
    tile[ty + j][tx] = src[(size_t)(k0 + ty + j) * C_DIM + d0 + tx];
  __syncthreads();
  u16* dst = vt + (size_t)bh * DH * Lkv;
#pragma unroll
  for (int j = 0; j < 32; j += 8)
    dst[(size_t)(d0 + ty + j) * Lkv + k0 + tx] = tile[tx][ty + j];
}

// ---------------- flash attention (scale pre-folded with log2e) ------------
__global__ __launch_bounds__(256)
void k_flash(const u16* __restrict__ Q, const u16* __restrict__ K,
             const u16* __restrict__ Vt, u16* __restrict__ O,
             int Lq, int Lkv, float scale2) {
  __shared__ __align__(16) u16 lK[64 * 128];
  __shared__ __align__(16) u16 lV[128 * 64];
  __shared__ __align__(16) u16 lP[4][16 * 72];
  int bh = blockIdx.x, b = bh >> 4, h = bh & 15;
  int tid = threadIdx.x, wid = tid >> 6, lane = tid & 63;
  int lr = lane & 15, lg = lane >> 4;
  int q0 = blockIdx.y * 64 + wid * 16;
  const u16* Qb = Q + ((size_t)(b * Lq) + q0) * C_DIM + h * DH;
  const u16* Kb = K + (size_t)(b * Lkv) * C_DIM + h * DH;
  const u16* Vb = Vt + (size_t)bh * DH * Lkv;

  bf16x8 qf[4];
#pragma unroll
  for (int ks = 0; ks < 4; ++ks)
    qf[ks] = *(const bf16x8*)(Qb + (size_t)lr * C_DIM + ks * 32 + lg * 8);

  f32x4 zero4 = {0.f, 0.f, 0.f, 0.f};
  f32x4 o[8];
#pragma unroll
  for (int n = 0; n < 8; ++n) o[n] = zero4;
  float mrow[4] = {-3.0e38f, -3.0e38f, -3.0e38f, -3.0e38f};
  float lrow[4] = {0.f, 0.f, 0.f, 0.f};

  int nsteps = Lkv >> 6;
  for (int kt = 0; kt < nsteps; ++kt) {
#pragma unroll
    for (int i = 0; i < 4; ++i) {
      int flat = i * 4096 + tid * 16;
      int key = flat >> 8, inner = flat & 255;
      int ksrc = inner ^ ((key & 7) << 4);
      gl_lds16((const char*)Kb + ((size_t)(kt * 64 + key) * C_DIM) * 2 + ksrc, (char*)lK + flat);
      int d = flat >> 7, keyb = flat & 127;
      int vsrc = keyb ^ ((d & 7) << 4);
      gl_lds16((const char*)Vb + ((size_t)d * Lkv) * 2 + kt * 128 + vsrc, (char*)lV + flat);
    }
    __syncthreads();

    f32x4 sc[4];
#pragma unroll
    for (int c = 0; c < 4; ++c) sc[c] = zero4;
#pragma unroll
    for (int c = 0; c < 4; ++c) {
      int key = c * 16 + lr;
#pragma unroll
      for (int ks = 0; ks < 4; ++ks) {
        int off = (ks * 64 + lg * 16) ^ ((key & 7) << 4);
        bf16x8 kf = *(const bf16x8*)((const char*)lK + key * 256 + off);
        sc[c] = __builtin_amdgcn_mfma_f32_16x16x32_bf16(qf[ks], kf, sc[c], 0, 0, 0);
      }
    }
#pragma unroll
    for (int r = 0; r < 4; ++r) {
      float s0 = sc[0][r] * scale2, s1 = sc[1][r] * scale2;
      float s2 = sc[2][r] * scale2, s3 = sc[3][r] * scale2;
      float mx = fmaxf(fmaxf(s0, s1), fmaxf(s2, s3));
#pragma unroll
      for (int m = 1; m < 16; m <<= 1) mx = fmaxf(mx, __shfl_xor(mx, m));
      float mnew = fmaxf(mrow[r], mx);
      float alpha = exp2f(mrow[r] - mnew);
      mrow[r] = mnew;
      float p0 = exp2f(s0 - mnew);
      float p1 = exp2f(s1 - mnew);
      float p2 = exp2f(s2 - mnew);
      float p3 = exp2f(s3 - mnew);
      float psum = p0 + p1 + p2 + p3;
#pragma unroll
      for (int m = 1; m < 16; m <<= 1) psum += __shfl_xor(psum, m);
      lrow[r] = lrow[r] * alpha + psum;
#pragma unroll
      for (int n = 0; n < 8; ++n) o[n][r] *= alpha;
      u16* pr = lP[wid] + (4 * lg + r) * 72;
      pr[lr]      = f2bf(p0);
      pr[16 + lr] = f2bf(p1);
      pr[32 + lr] = f2bf(p2);
      pr[48 + lr] = f2bf(p3);
    }
    asm volatile("s_waitcnt lgkmcnt(0)" ::: "memory");
    __builtin_amdgcn_sched_barrier(0);
#pragma unroll
    for (int half = 0; half < 2; ++half) {
      bf16x8 pf = *(const bf16x8*)(lP[wid] + lr * 72 + half * 32 + lg * 8);
#pragma unroll
      for (int n = 0; n < 8; ++n) {
        int d = n * 16 + lr;
        int off = (half * 64 + lg * 16) ^ ((d & 7) << 4);
        bf16x8 vf = *(const bf16x8*)((const char*)lV + d * 128 + off);
        o[n] = __builtin_amdgcn_mfma_f32_16x16x32_bf16(pf, vf, o[n], 0, 0, 0);
      }
    }
    __syncthreads();
  }

  u16* Ob = O + ((size_t)(b * Lq) + q0) * C_DIM + h * DH;
#pragma unroll
  for (int n = 0; n < 8; ++n) {
    int d = n * 16 + lr;
#pragma unroll
    for (int r = 0; r < 4; ++r) {
      int qr = 4 * lg + r;
      Ob[(size_t)qr * C_DIM + d] = f2bf(o[n][r] / lrow[r]);
    }
  }
}

// ---------------- host ----------------
extern "C" void kernel_launch(void* const* d_in, const int* in_sizes, int n_in,
                              void* d_out, int out_size, void* d_ws, size_t ws_size,
                              hipStream_t stream) {
  const float* x     = (const float*)d_in[0];
  const float* y     = (const float*)d_in[1];
  const float* t     = (const float*)d_in[2];
  const float* freqs = (const float*)d_in[3];
  const float* tab   = (const float*)d_in[4];
  const float* Wq_s = (const float*)d_in[5];
  const float* bq_s = (const float*)d_in[6];
  const float* Wk_s = (const float*)d_in[7];
  const float* bk_s = (const float*)d_in[8];
  const float* Wv_s = (const float*)d_in[9];
  const float* bv_s = (const float*)d_in[10];
  const float* Wo_s = (const float*)d_in[11];
  const float* bo_s = (const float*)d_in[12];
  const float* Wq_c = (const float*)d_in[13];
  const float* bq_c = (const float*)d_in[14];
  const float* Wk_c = (const float*)d_in[15];
  const float* bk_c = (const float*)d_in[16];
  const float* Wv_c = (const float*)d_in[17];
  const float* bv_c = (const float*)d_in[18];
  const float* Wo_c = (const float*)d_in[19];
  const float* bo_c = (const float*)d_in[20];
  const float* W_fc1 = (const float*)d_in[21];
  const float* b_fc1 = (const float*)d_in[22];
  const float* W_fc2 = (const float*)d_in[23];
  const float* b_fc2 = (const float*)d_in[24];

  const size_t SZ_CC  = (size_t)C_DIM * C_DIM * 2;
  const size_t SZ_FC  = (size_t)F_DIM * C_DIM * 2;
  const size_t SZ_LC  = (size_t)L_ROWS * C_DIM * 2;
  const size_t SZ_YC  = (size_t)LY_ROWS * C_DIM * 2;
  char* ws = (char*)d_ws;
  size_t off = 0;
  u16* wq_s = (u16*)(ws + off); off += SZ_CC;   // wq_s..wo_c contiguous (8 tensors)
  u16* wk_s = (u16*)(ws + off); off += SZ_CC;
  u16* wv_s = (u16*)(ws + off); off += SZ_CC;
  u16* wo_s = (u16*)(ws + off); off += SZ_CC;
  u16* wq_c = (u16*)(ws + off); off += SZ_CC;
  u16* wk_c = (u16*)(ws + off); off += SZ_CC;
  u16* wv_c = (u16*)(ws + off); off += SZ_CC;
  u16* wo_c = (u16*)(ws + off); off += SZ_CC;
  u16* wfc1 = (u16*)(ws + off); off += SZ_FC;   // wfc1,wfc2 contiguous
  u16* wfc2 = (u16*)(ws + off); off += SZ_FC;
  u16* ybf  = (u16*)(ws + off); off += SZ_YC;
  u16* xm   = (u16*)(ws + off); off += SZ_LC;
  u16* qb   = (u16*)(ws + off); off += SZ_LC;
  u16* kb   = (u16*)(ws + off); off += SZ_LC;
  u16* vb   = (u16*)(ws + off); off += SZ_LC;
  u16* ao   = (u16*)(ws + off); off += SZ_LC;
  u16* hbuf = qb;                               // [L, F] bf16 overlay (qb..ao)
  u16* x1bf = (u16*)(ws + off); off += SZ_LC;   // bf16 residual stream
  u16* kc   = (u16*)(ws + off); off += SZ_YC;
  u16* vc   = (u16*)(ws + off); off += SZ_YC;
  u16* vt   = (u16*)(ws + off); off += SZ_LC;
  u16* vtc  = (u16*)(ws + off); off += SZ_YC;
  if (ws_size < off) return;

  // fused weight conversions: 3 launches instead of 11
  k_cvt8<<<4096, 256, 0, stream>>>(Wq_s, Wk_s, Wv_s, Wo_s, Wq_c, Wk_c, Wv_c, Wo_c, wq_s);
  k_cvt2<<<4096, 256, 0, stream>>>(W_fc1, W_fc2, wfc1);
  k_cvt<<<2048, 256, 0, stream>>>(y, ybf, LY_ROWS * C_DIM);

  const float ascale2 = 0.08838834764831845f * 1.44269504f;  // 1/sqrt(128)*log2e

  k_modln<0><<<L_ROWS, 256, 0, stream>>>(x, t, tab, xm, 1, 0);
  // fused self QKV: N = 6144 (gemm3<128>, 768 blocks = 3 full CU-waves)
  k_gemm3<128, 0><<<32 * 24, 512, 0, stream>>>(
      xm, wq_s, bq_s, bk_s, bv_s, qb, kb, vb, 11, C_DIM,
      nullptr, nullptr, nullptr, nullptr, L_ROWS, 6144, C_DIM, C_DIM, C_DIM, 24);
  k_rope<<<2048, 256, 0, stream>>>(qb, kb, freqs);
  k_transpose_v<<<dim3(B_SZ * H_NUM, S_LEN / 32, DH / 32), dim3(32, 8), 0, stream>>>(vb, vt, S_LEN);
  k_flash<<<dim3(B_SZ * H_NUM, S_LEN / 64), 256, 0, stream>>>(qb, kb, vt, ao, S_LEN, S_LEN, ascale2);
  // x1bf = bf16(x + gate_msa*(ao@Wo_s^T+bo_s))
  k_gemm3<128, 6><<<32 * 8, 512, 0, stream>>>(
      ao, wo_s, bo_s, nullptr, nullptr, x1bf, nullptr, nullptr, 30, C_DIM,
      nullptr, x, t + 2 * C_DIM, tab + 2 * C_DIM, L_ROWS, C_DIM, C_DIM, C_DIM, C_DIM, 8);
  // cross q
  k_gemm3<128, 0><<<32 * 8, 512, 0, stream>>>(
      x1bf, wq_c, bq_c, nullptr, nullptr, qb, nullptr, nullptr, 30, C_DIM,
      nullptr, nullptr, nullptr, nullptr, L_ROWS, C_DIM, C_DIM, C_DIM, C_DIM, 8);
  // fused cross KV: N = 4096
  k_gemm3<128, 0><<<8 * 16, 512, 0, stream>>>(
      ybf, wk_c, bk_c, bv_c, bv_c, kc, vc, vc, 11, C_DIM,
      nullptr, nullptr, nullptr, nullptr, LY_ROWS, 4096, C_DIM, C_DIM, C_DIM, 16);
  k_transpose_v<<<dim3(B_SZ * H_NUM, T_LEN / 32, DH / 32), dim3(32, 8), 0, stream>>>(vc, vtc, T_LEN);
  k_flash<<<dim3(B_SZ * H_NUM, S_LEN / 64), 256, 0, stream>>>(qb, kc, vtc, ao, S_LEN, T_LEN, ascale2);
  // x1bf += ao@Wo_c^T + bo_c  (in-place bf16 RMW)
  k_gemm3<128, 7><<<32 * 8, 512, 0, stream>>>(
      ao, wo_c, bo_c, nullptr, nullptr, x1bf, nullptr, nullptr, 30, C_DIM,
      nullptr, nullptr, nullptr, nullptr, L_ROWS, C_DIM, C_DIM, C_DIM, C_DIM, 8);
  // MLP
  k_modln<1><<<L_ROWS, 256, 0, stream>>>(x1bf, t, tab, xm, 4, 3);
  k_gemm5<1><<<16 * 32, 512, 0, stream>>>(
      xm, wfc1, b_fc1, nullptr, nullptr, hbuf, nullptr, nullptr, 30, F_DIM,
      L_ROWS, F_DIM, C_DIM, C_DIM, C_DIM, 32);
  // fc2 final: d_out = x1bf + gate_mlp*(h@W_fc2^T + b_fc2)  (fp32 out)
  k_gemm3<128, 8><<<32 * 8, 512, 0, stream>>>(
      hbuf, wfc2, b_fc2, nullptr, nullptr, nullptr, x1bf, nullptr, 30, C_DIM,
      (float*)d_out, nullptr, t + 5 * C_DIM, tab + 5 * C_DIM, L_ROWS, C_DIM, F_DIM, F_DIM, F_DIM, 8);
}

// Round 11
// 835.189 us; speedup vs baseline: 1.1442x; 1.0094x over previous
//
#include <hip/hip_runtime.h>
#include <stdint.h>

#define C_DIM 2048
#define H_NUM 16
#define DH    128
#define S_LEN 1024
#define T_LEN 256
#define B_SZ  4
#define L_ROWS 4096   // B*S
#define LY_ROWS 1024  // B*T
#define F_DIM 8192

typedef __attribute__((ext_vector_type(4))) float f32x4;
typedef __attribute__((ext_vector_type(8))) __bf16 bf16x8;
typedef __attribute__((ext_vector_type(4))) unsigned short us4;
typedef __attribute__((ext_vector_type(8))) unsigned short us8;
typedef unsigned short u16;

__device__ __forceinline__ u16 f2bf(float f) {
  union { float f; uint32_t u; } v; v.f = f;
  uint32_t r = v.u + 0x7FFFu + ((v.u >> 16) & 1u);
  return (u16)(r >> 16);
}
__device__ __forceinline__ float bf2f(u16 h) {
  union { uint32_t u; float f; } v; v.u = ((uint32_t)h) << 16;
  return v.f;
}

typedef __attribute__((address_space(1))) void gvoid;
typedef __attribute__((address_space(3))) void lvoid;
__device__ __forceinline__ void gl_lds16(const void* g, void* l) {
  __builtin_amdgcn_global_load_lds((gvoid*)g, (lvoid*)l, 16, 0, 0);
}

template<int N> __device__ __forceinline__ void wait_vmcnt() {
  if constexpr (N == 0) asm volatile("s_waitcnt vmcnt(0)" ::: "memory");
  else if constexpr (N == 4) asm volatile("s_waitcnt vmcnt(4)" ::: "memory");
  else if constexpr (N == 5) asm volatile("s_waitcnt vmcnt(5)" ::: "memory");
  else if constexpr (N == 6) asm volatile("s_waitcnt vmcnt(6)" ::: "memory");
}
__device__ __forceinline__ void barrier_raw() {
  asm volatile("s_barrier" ::: "memory");
}
__device__ __forceinline__ void lgkm0_pin() {
  asm volatile("s_waitcnt lgkmcnt(0)" ::: "memory");
  __builtin_amdgcn_sched_barrier(0);
}

__device__ __forceinline__ float gelu_fast(float val) {
  float z = 0.7978845608f * (val + 0.044715f * val * val * val);
  float e = __expf(2.f * z);
  float th = 1.f - 2.f / (e + 1.f);
  return 0.5f * val * (1.f + th);
}

// ---------------- fp32 -> bf16 conversion ----------------
__global__ void k_cvt(const float* __restrict__ src, u16* __restrict__ dst, int n) {
  int i = (blockIdx.x * blockDim.x + threadIdx.x) * 4;
  int stride = gridDim.x * blockDim.x * 4;
  for (; i < n; i += stride) {
    float4 v = *(const float4*)(src + i);
    us4 o;
    o[0] = f2bf(v.x); o[1] = f2bf(v.y); o[2] = f2bf(v.z); o[3] = f2bf(v.w);
    *(us4*)(dst + i) = o;
  }
}

// 8 C*C (2^22-elem) fp32 tensors -> one contiguous bf16 region
__global__ void k_cvt8(const float* __restrict__ s0, const float* __restrict__ s1,
                       const float* __restrict__ s2, const float* __restrict__ s3,
                       const float* __restrict__ s4, const float* __restrict__ s5,
                       const float* __restrict__ s6, const float* __restrict__ s7,
                       u16* __restrict__ dst) {
  const int PER = C_DIM * C_DIM;          // 2^22
  int i = (blockIdx.x * blockDim.x + threadIdx.x) * 4;
  int stride = gridDim.x * blockDim.x * 4;
  int total = PER * 8;
  for (; i < total; i += stride) {
    int t = i >> 22;
    const float* s;
    switch (t) {
      case 0: s = s0; break; case 1: s = s1; break;
      case 2: s = s2; break; case 3: s = s3; break;
      case 4: s = s4; break; case 5: s = s5; break;
      case 6: s = s6; break; default: s = s7; break;
    }
    float4 v = *(const float4*)(s + (i & (PER - 1)));
    us4 o;
    o[0] = f2bf(v.x); o[1] = f2bf(v.y); o[2] = f2bf(v.z); o[3] = f2bf(v.w);
    *(us4*)(dst + i) = o;
  }
}

// 2 F*C (2^24-elem) fp32 tensors -> contiguous bf16 (wfc1; wfc2)
__global__ void k_cvt2(const float* __restrict__ s0, const float* __restrict__ s1,
                       u16* __restrict__ dst) {
  const int PER = F_DIM * C_DIM;          // 2^24
  int i = (blockIdx.x * blockDim.x + threadIdx.x) * 4;
  int stride = gridDim.x * blockDim.x * 4;
  int total = PER * 2;
  for (; i < total; i += stride) {
    const float* s = (i >> 24) ? s1 : s0;
    float4 v = *(const float4*)(s + (i & (PER - 1)));
    us4 o;
    o[0] = f2bf(v.x); o[1] = f2bf(v.y); o[2] = f2bf(v.z); o[3] = f2bf(v.w);
    *(us4*)(dst + i) = o;
  }
}

// ---------------- LN + adaLN modulation (fp32 or bf16 input) ----------------
template<int INBF>
__global__ __launch_bounds__(256)
void k_modln(const void* __restrict__ xin, const float* __restrict__ t,
             const float* __restrict__ tab, u16* __restrict__ out,
             int scale_idx, int shift_idx) {
  int row = blockIdx.x;
  int tid = threadIdx.x;
  int c0 = tid * 8;
  float v[8];
  if constexpr (INBF) {
    us8 a = *(const us8*)((const u16*)xin + (size_t)row * C_DIM + c0);
#pragma unroll
    for (int j = 0; j < 8; ++j) v[j] = bf2f(a[j]);
  } else {
    const float* xr = (const float*)xin + (size_t)row * C_DIM;
    float4 a = *(const float4*)(xr + c0);
    float4 b = *(const float4*)(xr + c0 + 4);
    v[0] = a.x; v[1] = a.y; v[2] = a.z; v[3] = a.w;
    v[4] = b.x; v[5] = b.y; v[6] = b.z; v[7] = b.w;
  }
  float s = 0.f, ss = 0.f;
#pragma unroll
  for (int j = 0; j < 8; ++j) { s += v[j]; ss += v[j] * v[j]; }
#pragma unroll
  for (int m = 1; m < 64; m <<= 1) { s += __shfl_xor(s, m); ss += __shfl_xor(ss, m); }
  __shared__ float red[8];
  int wid = tid >> 6;
  if ((tid & 63) == 0) { red[wid * 2] = s; red[wid * 2 + 1] = ss; }
  __syncthreads();
  s  = red[0] + red[2] + red[4] + red[6];
  ss = red[1] + red[3] + red[5] + red[7];
  float mean = s * (1.f / C_DIM);
  float var  = ss * (1.f / C_DIM) - mean * mean;
  float rstd = rsqrtf(var + 1e-6f);
  const float* trow = t + (size_t)row * (6 * C_DIM);
  const float* tsc = trow + scale_idx * C_DIM + c0;
  const float* tsh = trow + shift_idx * C_DIM + c0;
  const float* gsc = tab + scale_idx * C_DIM + c0;
  const float* gsh = tab + shift_idx * C_DIM + c0;
  us8 o;
#pragma unroll
  for (int j = 0; j < 8; ++j) {
    float scv = 1.f + gsc[j] + tsc[j];
    float shv = gsh[j] + tsh[j];
    o[j] = f2bf((v[j] - mean) * rstd * scv + shv);
  }
  *(us8*)(out + (size_t)row * C_DIM + c0) = o;
}

// ======== GEMM v5b: 256x256 tile, BK=64, 2 K-tiles/iter, 8-phase ============
// (R8-proven ledger.) EPI 1: fast-gelu->o0.
template<int EPI>
__global__ __launch_bounds__(512, 2)
void k_gemm5(const u16* __restrict__ A, const u16* __restrict__ W,
             const float* __restrict__ bias0,
             u16* __restrict__ o0, int out_ld,
             int M, int N, int K, int lda, int ldw, int nbx) {
  __shared__ __align__(16) u16 lds[65536];

  int tid = threadIdx.x;
  int nwg = gridDim.x;
  int q8 = nwg >> 3, r8 = nwg & 7;
  int xcd = blockIdx.x & 7, local = blockIdx.x >> 3;
  int wgid = (xcd < r8 ? xcd * (q8 + 1) : r8 * (q8 + 1) + (xcd - r8) * q8) + local;
  int bx = wgid % nbx, by = wgid / nbx;
  int m0 = by * 256, n0 = bx * 256;

  int wid = tid >> 6, lane = tid & 63;
  int wm = wid >> 2, wn = wid & 3;
  int lr = lane & 15, lg = lane >> 4;
  int xorslot = lr & 7;
  int bcol = (wn & 1) * 64;

  int srow = tid >> 3;
  int scol = ((tid ^ (tid >> 3)) & 7) * 8;

  auto stA = [&](int buf, int h, int kt) {
    u16* dst = lds + (buf * 2 + h) * 8192 + tid * 8;
#pragma unroll
    for (int call = 0; call < 2; ++call) {
      int grow = m0 + h * 128 + call * 64 + srow;
      gl_lds16(A + (size_t)grow * lda + kt * 64 + scol, dst + call * 4096);
    }
  };
  auto stB = [&](int buf, int h, int kt) {
    u16* dst = lds + 32768 + (buf * 2 + h) * 8192 + tid * 8;
#pragma unroll
    for (int call = 0; call < 2; ++call) {
      int grow = n0 + h * 128 + call * 64 + srow;
      gl_lds16(W + (size_t)grow * ldw + kt * 64 + scol, dst + call * 4096);
    }
  };

  f32x4 zero4 = {0.f, 0.f, 0.f, 0.f};
  f32x4 acc[8][4];
#pragma unroll
  for (int m = 0; m < 8; ++m)
#pragma unroll
    for (int n = 0; n < 4; ++n) acc[m][n] = zero4;

  int NT = K >> 6, NJ = NT >> 1;
  stA(0, 0, 0); stA(0, 1, 0); stB(0, 0, 0); stB(0, 1, 0);
  stB(1, 0, 1); stA(1, 0, 1);
  wait_vmcnt<4>();
  barrier_raw();

  for (int j = 0; j < NJ; ++j) {
    bool nlast = (j + 1 < NJ);
    int t1 = 2 * j + 1, t2 = 2 * j + 2, t3 = 2 * j + 3;
#pragma unroll
    for (int buf = 0; buf < 2; ++buf) {
      const u16* Ah = lds + (buf * 2 + wm) * 8192;
      const u16* Bh = lds + 32768 + (buf * 2 + (wn >> 1)) * 8192;
      bf16x8 aR[4][2], b0[2][2], b1[2][2];

#pragma unroll
      for (int m = 0; m < 4; ++m) {
        int r = m * 16 + lr;
#pragma unroll
        for (int kk = 0; kk < 2; ++kk)
          aR[m][kk] = *(const bf16x8*)(Ah + r * 64 + (((kk << 2) | lg) ^ xorslot) * 8);
      }
#pragma unroll
      for (int n = 0; n < 2; ++n) {
        int r = bcol + n * 16 + lr;
#pragma unroll
        for (int kk = 0; kk < 2; ++kk)
          b0[n][kk] = *(const bf16x8*)(Bh + r * 64 + (((kk << 2) | lg) ^ xorslot) * 8);
      }
      if (buf == 0) stA(1, 1, t1);
      else if (nlast) stA(0, 1, t2);
      barrier_raw();
      lgkm0_pin();
      __builtin_amdgcn_s_setprio(1);
#pragma unroll
      for (int kk = 0; kk < 2; ++kk)
#pragma unroll
        for (int m = 0; m < 4; ++m)
#pragma unroll
          for (int n = 0; n < 2; ++n)
            acc[m][n] = __builtin_amdgcn_mfma_f32_16x16x32_bf16(aR[m][kk], b0[n][kk], acc[m][n], 0, 0, 0);
      __builtin_amdgcn_s_setprio(0);
      barrier_raw();

#pragma unroll
      for (int n = 0; n < 2; ++n) {
        int r = bcol + 32 + n * 16 + lr;
#pragma unroll
        for (int kk = 0; kk < 2; ++kk)
          b1[n][kk] = *(const bf16x8*)(Bh + r * 64 + (((kk << 2) | lg) ^ xorslot) * 8);
      }
      if (buf == 0) stB(1, 1, t1);
      else if (nlast) stB(0, 1, t2);
      barrier_raw();
      lgkm0_pin();
      __builtin_amdgcn_s_setprio(1);
#pragma unroll
      for (int kk = 0; kk < 2; ++kk)
#pragma unroll
        for (int m = 0; m < 4; ++m)
#pragma unroll
          for (int n = 0; n < 2; ++n)
            acc[m][2 + n] = __builtin_amdgcn_mfma_f32_16x16x32_bf16(aR[m][kk], b1[n][kk], acc[m][2 + n], 0, 0, 0);
      __builtin_amdgcn_s_setprio(0);
      barrier_raw();

#pragma unroll
      for (int m = 0; m < 4; ++m) {
        int r = 64 + m * 16 + lr;
#pragma unroll
        for (int kk = 0; kk < 2; ++kk)
          aR[m][kk] = *(const bf16x8*)(Ah + r * 64 + (((kk << 2) | lg) ^ xorslot) * 8);
      }
      if (nlast) { if (buf == 0) stB(0, 0, t2); else stB(1, 0, t3); }
      barrier_raw();
      lgkm0_pin();
      __builtin_amdgcn_s_setprio(1);
#pragma unroll
      for (int kk = 0; kk < 2; ++kk)
#pragma unroll
        for (int m = 0; m < 4; ++m)
#pragma unroll
          for (int n = 0; n < 2; ++n)
            acc[4 + m][2 + n] = __builtin_amdgcn_mfma_f32_16x16x32_bf16(aR[m][kk], b1[n][kk], acc[4 + m][2 + n], 0, 0, 0);
      __builtin_amdgcn_s_setprio(0);
      barrier_raw();

      if (nlast) { if (buf == 0) stA(0, 0, t2); else stA(1, 0, t3); }
      barrier_raw();
      __builtin_amdgcn_s_setprio(1);
#pragma unroll
      for (int kk = 0; kk < 2; ++kk)
#pragma unroll
        for (int m = 0; m < 4; ++m)
#pragma unroll
          for (int n = 0; n < 2; ++n)
            acc[4 + m][n] = __builtin_amdgcn_mfma_f32_16x16x32_bf16(aR[m][kk], b0[n][kk], acc[4 + m][n], 0, 0, 0);
      __builtin_amdgcn_s_setprio(0);
      if (nlast) wait_vmcnt<4>(); else wait_vmcnt<0>();
      barrier_raw();
    }
  }

#pragma unroll
  for (int mf = 0; mf < 8; ++mf) {
    int row0 = m0 + wm * 128 + mf * 16 + lg * 4;
#pragma unroll
    for (int nf = 0; nf < 4; ++nf) {
      int col = n0 + wn * 64 + nf * 16 + lr;
      float bv = bias0[col];
#pragma unroll
      for (int r = 0; r < 4; ++r)
        o0[(size_t)(row0 + r) * out_ld + col] = f2bf(gelu_fast(acc[mf][nf][r] + bv));
    }
  }
}

// ======== GEMM v3c: BMx256, BK=64, 4-phase, 3-bit swizzle (R5-proven) ======
// EPI 0: bf16(acc+bias)->o{0,1,2} split by col>>sec_shift
// EPI 6: o0 = bf16(residF + gate*(acc+bias))              (wo_s -> x1bf)
// EPI 7: o0 = bf16(bf2f(o0) + acc + bias)  in-place RMW   (wo_c)
// EPI 8: outF = bf2f(o1[idx]) + gate*(acc+bias)           (fc2 final fp32)
// EPI 9: fused QKV: q,k -> rope (freqs via gate_t); v -> o2 transposed
// EPI 10: fused cross-KV: k -> o0; v -> o1 transposed (Lkv=256)
template<int BM, int EPI>
__global__ __launch_bounds__(512, 2)
void k_gemm3(const u16* __restrict__ A, const u16* __restrict__ W,
             const float* __restrict__ bias0, const float* __restrict__ bias1,
             const float* __restrict__ bias2,
             u16* __restrict__ o0, u16* __restrict__ o1, u16* __restrict__ o2,
             int sec_shift, int out_ld,
             float* __restrict__ outF, const float* __restrict__ resid,
             const float* __restrict__ gate_t, const float* __restrict__ gate_tab,
             int M, int N, int K, int lda, int ldw, int nbx) {
  constexpr int HTA = (BM / 2) * 64;
  constexpr int HTB = 128 * 64;
  constexpr int ACALLS = BM / 128;
  constexpr int QM = BM / 64;
  constexpr int MFR = BM / 32;
  constexpr int VMN = 4 + ACALLS;
  constexpr int BOFF = 4 * HTA;
  __shared__ __align__(16) u16 lds[BOFF + 4 * HTB];

  int tid = threadIdx.x;
  int nwg = gridDim.x;
  int q8 = nwg >> 3, r8 = nwg & 7;
  int xcd = blockIdx.x & 7, local = blockIdx.x >> 3;
  int wgid = (xcd < r8 ? xcd * (q8 + 1) : r8 * (q8 + 1) + (xcd - r8) * q8) + local;
  int bx = wgid % nbx, by = wgid / nbx;
  int m0 = by * BM, n0 = bx * 256;

  int wid = tid >> 6, lane = tid & 63;
  int wm = wid >> 2, wn = wid & 3;
  int lr = lane & 15, lg = lane >> 4;
  int xorslot = lr & 7;
  int bcol = (wn & 1) * 64;

  int srow = tid >> 3;
  int scol = ((tid ^ (tid >> 3)) & 7) * 8;

  auto stA = [&](int h, int kt2) {
    int pt = kt2 & 1;
    u16* dst = lds + (pt * 2 + h) * HTA + tid * 8;
#pragma unroll
    for (int call = 0; call < ACALLS; ++call) {
      int grow = m0 + h * (BM / 2) + call * 64 + srow;
      gl_lds16(A + (size_t)grow * lda + kt2 * 64 + scol, dst + call * 4096);
    }
  };
  auto stB = [&](int h, int kt2) {
    int pt = kt2 & 1;
    u16* dst = lds + BOFF + (pt * 2 + h) * HTB + tid * 8;
#pragma unroll
    for (int call = 0; call < 2; ++call) {
      int grow = n0 + h * 128 + call * 64 + srow;
      gl_lds16(W + (size_t)grow * ldw + kt2 * 64 + scol, dst + call * 4096);
    }
  };

  f32x4 zero4 = {0.f, 0.f, 0.f, 0.f};
  f32x4 acc[MFR][4];
#pragma unroll
  for (int m = 0; m < MFR; ++m)
#pragma unroll
    for (int n = 0; n < 4; ++n) acc[m][n] = zero4;

  int NT2 = K >> 6;
  stA(0, 0); stA(1, 0); stB(0, 0); stB(1, 0);
  stB(0, 1); stB(1, 1); stA(0, 1);
  wait_vmcnt<VMN>();
  barrier_raw();

  for (int kt = 0; kt < NT2; ++kt) {
    int p = kt & 1;
    const u16* Ah = lds + (p * 2 + wm) * HTA;
    const u16* Bh = lds + BOFF + (p * 2 + (wn >> 1)) * HTB;
    bf16x8 aR[QM][2], bR0[2][2], bR1[2][2];
    bool st1 = (kt + 1) < NT2, st2 = (kt + 2) < NT2;

#pragma unroll
    for (int m = 0; m < QM; ++m) {
      int r = m * 16 + lr;
#pragma unroll
      for (int kk = 0; kk < 2; ++kk)
        aR[m][kk] = *(const bf16x8*)(Ah + r * 64 + (((kk << 2) | lg) ^ xorslot) * 8);
    }
#pragma unroll
    for (int n = 0; n < 2; ++n) {
      int r = bcol + n * 16 + lr;
#pragma unroll
      for (int kk = 0; kk < 2; ++kk)
        bR0[n][kk] = *(const bf16x8*)(Bh + r * 64 + (((kk << 2) | lg) ^ xorslot) * 8);
    }
    if (st1) stA(1, kt + 1);
    lgkm0_pin();
    __builtin_amdgcn_s_setprio(1);
#pragma unroll
    for (int kk = 0; kk < 2; ++kk)
#pragma unroll
      for (int m = 0; m < QM; ++m)
#pragma unroll
        for (int n = 0; n < 2; ++n)
          acc[m][n] = __builtin_amdgcn_mfma_f32_16x16x32_bf16(aR[m][kk], bR0[n][kk], acc[m][n], 0, 0, 0);
    __builtin_amdgcn_s_setprio(0);
    barrier_raw();

#pragma unroll
    for (int n = 0; n < 2; ++n) {
      int r = bcol + 32 + n * 16 + lr;
#pragma unroll
      for (int kk = 0; kk < 2; ++kk)
        bR1[n][kk] = *(const bf16x8*)(Bh + r * 64 + (((kk << 2) | lg) ^ xorslot) * 8);
    }
    lgkm0_pin();
    __builtin_amdgcn_s_setprio(1);
#pragma unroll
    for (int kk = 0; kk < 2; ++kk)
#pragma unroll
      for (int m = 0; m < QM; ++m)
#pragma unroll
        for (int n = 0; n < 2; ++n)
          acc[m][2 + n] = __builtin_amdgcn_mfma_f32_16x16x32_bf16(aR[m][kk], bR1[n][kk], acc[m][2 + n], 0, 0, 0);
    __builtin_amdgcn_s_setprio(0);
    barrier_raw();

#pragma unroll
    for (int m = 0; m < QM; ++m) {
      int r = (BM / 4) + m * 16 + lr;
#pragma unroll
      for (int kk = 0; kk < 2; ++kk)
        aR[m][kk] = *(const bf16x8*)(Ah + r * 64 + (((kk << 2) | lg) ^ xorslot) * 8);
    }
    if (st2) { stB(0, kt + 2); stB(1, kt + 2); }
    lgkm0_pin();
    __builtin_amdgcn_s_setprio(1);
#pragma unroll
    for (int kk = 0; kk < 2; ++kk)
#pragma unroll
      for (int m = 0; m < QM; ++m)
#pragma unroll
        for (int n = 0; n < 2; ++n)
          acc[QM + m][2 + n] = __builtin_amdgcn_mfma_f32_16x16x32_bf16(aR[m][kk], bR1[n][kk], acc[QM + m][2 + n], 0, 0, 0);
    __builtin_amdgcn_s_setprio(0);
    barrier_raw();

    if (st2) stA(0, kt + 2);
    __builtin_amdgcn_s_setprio(1);
#pragma unroll
    for (int kk = 0; kk < 2; ++kk)
#pragma unroll
      for (int m = 0; m < QM; ++m)
#pragma unroll
        for (int n = 0; n < 2; ++n)
          acc[QM + m][n] = __builtin_amdgcn_mfma_f32_16x16x32_bf16(aR[m][kk], bR0[n][kk], acc[QM + m][n], 0, 0, 0);
    __builtin_amdgcn_s_setprio(0);
    if (st2) wait_vmcnt<VMN>(); else wait_vmcnt<0>();
    barrier_raw();
  }

  // ---- epilogue ----
#pragma unroll
  for (int mf = 0; mf < MFR; ++mf) {
    int row0 = m0 + wm * (BM / 2) + mf * 16 + lg * 4;
#pragma unroll
    for (int nf = 0; nf < 4; ++nf) {
      int col = n0 + wn * 64 + nf * 16 + lr;
      if constexpr (EPI == 0) {
        int sec = col >> sec_shift;
        const float* bp = sec == 0 ? bias0 : (sec == 1 ? bias1 : bias2);
        u16* op = sec == 0 ? o0 : (sec == 1 ? o1 : o2);
        int cs = col & ((1 << sec_shift) - 1);
        float bv = bp[cs];
#pragma unroll
        for (int r = 0; r < 4; ++r)
          op[(size_t)(row0 + r) * out_ld + cs] = f2bf(acc[mf][nf][r] + bv);
      } else if constexpr (EPI == 6) {
        float bv = bias0[col];
        float gt = gate_tab[col];
#pragma unroll
        for (int r = 0; r < 4; ++r) {
          int row = row0 + r;
          size_t idx = (size_t)row * N + col;
          float g = gt + gate_t[(size_t)row * (6 * C_DIM) + col];
          o0[idx] = f2bf(resid[idx] + g * (acc[mf][nf][r] + bv));
        }
      } else if constexpr (EPI == 7) {
        float bv = bias0[col];
#pragma unroll
        for (int r = 0; r < 4; ++r) {
          size_t idx = (size_t)(row0 + r) * N + col;
          o0[idx] = f2bf(bf2f(o0[idx]) + acc[mf][nf][r] + bv);
        }
      } else if constexpr (EPI == 8) {
        float bv = bias0[col];
        float gt = gate_tab[col];
#pragma unroll
        for (int r = 0; r < 4; ++r) {
          int row = row0 + r;
          size_t idx = (size_t)row * N + col;
          float g = gt + gate_t[(size_t)row * (6 * C_DIM) + col];
          outF[idx] = bf2f(((const u16*)o1)[idx]) + g * (acc[mf][nf][r] + bv);
        }
      } else if constexpr (EPI == 9) {
        // fused QKV: sec 0=q(rope), 1=k(rope), 2=v(transposed store)
        int sec = col >> 11;            // wave-uniform (col spans 16)
        int cs = col & 2047;
        const float* bp = sec == 0 ? bias0 : (sec == 1 ? bias1 : bias2);
        float bv = bp[cs];
        if (sec < 2) {
          u16* op = sec == 0 ? o0 : o1;
          int i0 = (cs & (DH - 1)) >> 1;
          bool even = (cs & 1) == 0;
#pragma unroll
          for (int r = 0; r < 4; ++r) {
            float val = acc[mf][nf][r] + bv;
            float pv = __shfl_xor(val, 1);  // pair partner (col^1) = lane^1
            int sr = (row0 + r) & (S_LEN - 1);
            float ang = gate_t[sr * (DH / 2) + i0];   // gate_t carries freqs
            float sn, csn;
            __sincosf(ang, &sn, &csn);
            float outv = even ? (val * csn - pv * sn) : (pv * sn + val * csn);
            op[(size_t)(row0 + r) * out_ld + cs] = f2bf(outv);
          }
        } else {
          int h = cs >> 7, d = cs & (DH - 1);
#pragma unroll
          for (int r = 0; r < 4; ++r) {
            int row = row0 + r;
            int b = row >> 10, kv = row & (S_LEN - 1);
            o2[(((size_t)(b * H_NUM + h) * DH + d) << 10) + kv] =
                f2bf(acc[mf][nf][r] + bv);
          }
        }
      } else {  // EPI == 10: fused cross-KV: sec 0=k, 1=v(transposed, Lkv=256)
        int sec = col >> 11;
        int cs = col & 2047;
        float bv = (sec == 0 ? bias0 : bias1)[cs];
        if (sec == 0) {
#pragma unroll
          for (int r = 0; r < 4; ++r)
            o0[(size_t)(row0 + r) * out_ld + cs] = f2bf(acc[mf][nf][r] + bv);
        } else {
          int h = cs >> 7, d = cs & (DH - 1);
#pragma unroll
          for (int r = 0; r < 4; ++r) {
            int row = row0 + r;
            int b = row >> 8, kv = row & (T_LEN - 1);
            o1[(((size_t)(b * H_NUM + h) * DH + d) << 8) + kv] =
                f2bf(acc[mf][nf][r] + bv);
          }
        }
      }
    }
  }
}

// ---------------- flash attention (scale pre-folded with log2e) ------------
__global__ __launch_bounds__(256)
void k_flash(const u16* __restrict__ Q, const u16* __restrict__ K,
             const u16* __restrict__ Vt, u16* __restrict__ O,
             int Lq, int Lkv, float scale2) {
  __shared__ __align__(16) u16 lK[64 * 128];
  __shared__ __align__(16) u16 lV[128 * 64];
  __shared__ __align__(16) u16 lP[4][16 * 72];
  int bh = blockIdx.x, b = bh >> 4, h = bh & 15;
  int tid = threadIdx.x, wid = tid >> 6, lane = tid & 63;
  int lr = lane & 15, lg = lane >> 4;
  int q0 = blockIdx.y * 64 + wid * 16;
  const u16* Qb = Q + ((size_t)(b * Lq) + q0) * C_DIM + h * DH;
  const u16* Kb = K + (size_t)(b * Lkv) * C_DIM + h * DH;
  const u16* Vb = Vt + (size_t)bh * DH * Lkv;

  bf16x8 qf[4];
#pragma unroll
  for (int ks = 0; ks < 4; ++ks)
    qf[ks] = *(const bf16x8*)(Qb + (size_t)lr * C_DIM + ks * 32 + lg * 8);

  f32x4 zero4 = {0.f, 0.f, 0.f, 0.f};
  f32x4 o[8];
#pragma unroll
  for (int n = 0; n < 8; ++n) o[n] = zero4;
  float mrow[4] = {-3.0e38f, -3.0e38f, -3.0e38f, -3.0e38f};
  float lrow[4] = {0.f, 0.f, 0.f, 0.f};

  int nsteps = Lkv >> 6;
  for (int kt = 0; kt < nsteps; ++kt) {
#pragma unroll
    for (int i = 0; i < 4; ++i) {
      int flat = i * 4096 + tid * 16;
      int key = flat >> 8, inner = flat & 255;
      int ksrc = inner ^ ((key & 7) << 4);
      gl_lds16((const char*)Kb + ((size_t)(kt * 64 + key) * C_DIM) * 2 + ksrc, (char*)lK + flat);
      int d = flat >> 7, keyb = flat & 127;
      int vsrc = keyb ^ ((d & 7) << 4);
      gl_lds16((const char*)Vb + ((size_t)d * Lkv) * 2 + kt * 128 + vsrc, (char*)lV + flat);
    }
    __syncthreads();

    f32x4 sc[4];
#pragma unroll
    for (int c = 0; c < 4; ++c) sc[c] = zero4;
#pragma unroll
    for (int c = 0; c < 4; ++c) {
      int key = c * 16 + lr;
#pragma unroll
      for (int ks = 0; ks < 4; ++ks) {
        int off = (ks * 64 + lg * 16) ^ ((key & 7) << 4);
        bf16x8 kf = *(const bf16x8*)((const char*)lK + key * 256 + off);
        sc[c] = __builtin_amdgcn_mfma_f32_16x16x32_bf16(qf[ks], kf, sc[c], 0, 0, 0);
      }
    }
#pragma unroll
    for (int r = 0; r < 4; ++r) {
      float s0 = sc[0][r] * scale2, s1 = sc[1][r] * scale2;
      float s2 = sc[2][r] * scale2, s3 = sc[3][r] * scale2;
      float mx = fmaxf(fmaxf(s0, s1), fmaxf(s2, s3));
#pragma unroll
      for (int m = 1; m < 16; m <<= 1) mx = fmaxf(mx, __shfl_xor(mx, m));
      float mnew = fmaxf(mrow[r], mx);
      float alpha = exp2f(mrow[r] - mnew);
      mrow[r] = mnew;
      float p0 = exp2f(s0 - mnew);
      float p1 = exp2f(s1 - mnew);
      float p2 = exp2f(s2 - mnew);
      float p3 = exp2f(s3 - mnew);
      float psum = p0 + p1 + p2 + p3;
#pragma unroll
      for (int m = 1; m < 16; m <<= 1) psum += __shfl_xor(psum, m);
      lrow[r] = lrow[r] * alpha + psum;
#pragma unroll
      for (int n = 0; n < 8; ++n) o[n][r] *= alpha;
      u16* pr = lP[wid] + (4 * lg + r) * 72;
      pr[lr]      = f2bf(p0);
      pr[16 + lr] = f2bf(p1);
      pr[32 + lr] = f2bf(p2);
      pr[48 + lr] = f2bf(p3);
    }
    asm volatile("s_waitcnt lgkmcnt(0)" ::: "memory");
    __builtin_amdgcn_sched_barrier(0);
#pragma unroll
    for (int half = 0; half < 2; ++half) {
      bf16x8 pf = *(const bf16x8*)(lP[wid] + lr * 72 + half * 32 + lg * 8);
#pragma unroll
      for (int n = 0; n < 8; ++n) {
        int d = n * 16 + lr;
        int off = (half * 64 + lg * 16) ^ ((d & 7) << 4);
        bf16x8 vf = *(const bf16x8*)((const char*)lV + d * 128 + off);
        o[n] = __builtin_amdgcn_mfma_f32_16x16x32_bf16(pf, vf, o[n], 0, 0, 0);
      }
    }
    __syncthreads();
  }

  u16* Ob = O + ((size_t)(b * Lq) + q0) * C_DIM + h * DH;
#pragma unroll
  for (int n = 0; n < 8; ++n) {
    int d = n * 16 + lr;
#pragma unroll
    for (int r = 0; r < 4; ++r) {
      int qr = 4 * lg + r;
      Ob[(size_t)qr * C_DIM + d] = f2bf(o[n][r] / lrow[r]);
    }
  }
}

// ---------------- host ----------------
extern "C" void kernel_launch(void* const* d_in, const int* in_sizes, int n_in,
                              void* d_out, int out_size, void* d_ws, size_t ws_size,
                              hipStream_t stream) {
  const float* x     = (const float*)d_in[0];
  const float* y     = (const float*)d_in[1];
  const float* t     = (const float*)d_in[2];
  const float* freqs = (const float*)d_in[3];
  const float* tab   = (const float*)d_in[4];
  const float* Wq_s = (const float*)d_in[5];
  const float* bq_s = (const float*)d_in[6];
  const float* Wk_s = (const float*)d_in[7];
  const float* bk_s = (const float*)d_in[8];
  const float* Wv_s = (const float*)d_in[9];
  const float* bv_s = (const float*)d_in[10];
  const float* Wo_s = (const float*)d_in[11];
  const float* bo_s = (const float*)d_in[12];
  const float* Wq_c = (const float*)d_in[13];
  const float* bq_c = (const float*)d_in[14];
  const float* Wk_c = (const float*)d_in[15];
  const float* bk_c = (const float*)d_in[16];
  const float* Wv_c = (const float*)d_in[17];
  const float* bv_c = (const float*)d_in[18];
  const float* Wo_c = (const float*)d_in[19];
  const float* bo_c = (const float*)d_in[20];
  const float* W_fc1 = (const float*)d_in[21];
  const float* b_fc1 = (const float*)d_in[22];
  const float* W_fc2 = (const float*)d_in[23];
  const float* b_fc2 = (const float*)d_in[24];

  const size_t SZ_CC  = (size_t)C_DIM * C_DIM * 2;
  const size_t SZ_FC  = (size_t)F_DIM * C_DIM * 2;
  const size_t SZ_LC  = (size_t)L_ROWS * C_DIM * 2;
  const size_t SZ_YC  = (size_t)LY_ROWS * C_DIM * 2;
  char* ws = (char*)d_ws;
  size_t off = 0;
  u16* wq_s = (u16*)(ws + off); off += SZ_CC;   // wq_s..wo_c contiguous (8 tensors)
  u16* wk_s = (u16*)(ws + off); off += SZ_CC;
  u16* wv_s = (u16*)(ws + off); off += SZ_CC;
  u16* wo_s = (u16*)(ws + off); off += SZ_CC;
  u16* wq_c = (u16*)(ws + off); off += SZ_CC;
  u16* wk_c = (u16*)(ws + off); off += SZ_CC;
  u16* wv_c = (u16*)(ws + off); off += SZ_CC;
  u16* wo_c = (u16*)(ws + off); off += SZ_CC;
  u16* wfc1 = (u16*)(ws + off); off += SZ_FC;   // wfc1,wfc2 contiguous
  u16* wfc2 = (u16*)(ws + off); off += SZ_FC;
  u16* ybf  = (u16*)(ws + off); off += SZ_YC;
  u16* xm   = (u16*)(ws + off); off += SZ_LC;
  u16* qb   = (u16*)(ws + off); off += SZ_LC;
  u16* kb   = (u16*)(ws + off); off += SZ_LC;
  u16* vb   = (u16*)(ws + off); off += SZ_LC;   // unused (kept for hbuf overlay)
  u16* ao   = (u16*)(ws + off); off += SZ_LC;
  u16* hbuf = qb;                               // [L, F] bf16 overlay (qb..ao)
  u16* x1bf = (u16*)(ws + off); off += SZ_LC;   // bf16 residual stream
  u16* kc   = (u16*)(ws + off); off += SZ_YC;
  u16* vc   = (u16*)(ws + off); off += SZ_YC;   // unused
  u16* vt   = (u16*)(ws + off); off += SZ_LC;
  u16* vtc  = (u16*)(ws + off); off += SZ_YC;
  if (ws_size < off) return;
  (void)vb; (void)vc;

  // fused weight conversions: 3 launches
  k_cvt8<<<4096, 256, 0, stream>>>(Wq_s, Wk_s, Wv_s, Wo_s, Wq_c, Wk_c, Wv_c, Wo_c, wq_s);
  k_cvt2<<<4096, 256, 0, stream>>>(W_fc1, W_fc2, wfc1);
  k_cvt<<<2048, 256, 0, stream>>>(y, ybf, LY_ROWS * C_DIM);

  const float ascale2 = 0.08838834764831845f * 1.44269504f;  // 1/sqrt(128)*log2e

  k_modln<0><<<L_ROWS, 256, 0, stream>>>(x, t, tab, xm, 1, 0);
  // fused self QKV + rope + V-transpose: N = 6144
  k_gemm3<128, 9><<<32 * 24, 512, 0, stream>>>(
      xm, wq_s, bq_s, bk_s, bv_s, qb, kb, vt, 11, C_DIM,
      nullptr, nullptr, freqs, nullptr, L_ROWS, 6144, C_DIM, C_DIM, C_DIM, 24);
  k_flash<<<dim3(B_SZ * H_NUM, S_LEN / 64), 256, 0, stream>>>(qb, kb, vt, ao, S_LEN, S_LEN, ascale2);
  // x1bf = bf16(x + gate_msa*(ao@Wo_s^T+bo_s))
  k_gemm3<128, 6><<<32 * 8, 512, 0, stream>>>(
      ao, wo_s, bo_s, nullptr, nullptr, x1bf, nullptr, nullptr, 30, C_DIM,
      nullptr, x, t + 2 * C_DIM, tab + 2 * C_DIM, L_ROWS, C_DIM, C_DIM, C_DIM, C_DIM, 8);
  // cross q (no rope)
  k_gemm3<128, 0><<<32 * 8, 512, 0, stream>>>(
      x1bf, wq_c, bq_c, nullptr, nullptr, qb, nullptr, nullptr, 30, C_DIM,
      nullptr, nullptr, nullptr, nullptr, L_ROWS, C_DIM, C_DIM, C_DIM, C_DIM, 8);
  // fused cross KV + V-transpose: N = 4096
  k_gemm3<128, 10><<<8 * 16, 512, 0, stream>>>(
      ybf, wk_c, bk_c, bv_c, nullptr, kc, vtc, nullptr, 11, C_DIM,
      nullptr, nullptr, nullptr, nullptr, LY_ROWS, 4096, C_DIM, C_DIM, C_DIM, 16);
  k_flash<<<dim3(B_SZ * H_NUM, S_LEN / 64), 256, 0, stream>>>(qb, kc, vtc, ao, S_LEN, T_LEN, ascale2);
  // x1bf += ao@Wo_c^T + bo_c  (in-place bf16 RMW)
  k_gemm3<128, 7><<<32 * 8, 512, 0, stream>>>(
      ao, wo_c, bo_c, nullptr, nullptr, x1bf, nullptr, nullptr, 30, C_DIM,
      nullptr, nullptr, nullptr, nullptr, L_ROWS, C_DIM, C_DIM, C_DIM, C_DIM, 8);
  // MLP
  k_modln<1><<<L_ROWS, 256, 0, stream>>>(x1bf, t, tab, xm, 4, 3);
  k_gemm5<1><<<16 * 32, 512, 0, stream>>>(
      xm, wfc1, b_fc1, hbuf, F_DIM, L_ROWS, F_DIM, C_DIM, C_DIM, C_DIM, 32);
  // fc2 final: d_out = x1bf + gate_mlp*(h@W_fc2^T + b_fc2)  (fp32 out)
  k_gemm3<128, 8><<<32 * 8, 512, 0, stream>>>(
      hbuf, wfc2, b_fc2, nullptr, nullptr, nullptr, x1bf, nullptr, 30, C_DIM,
      (float*)d_out, nullptr, t + 5 * C_DIM, tab + 5 * C_DIM, L_ROWS, C_DIM, F_DIM, F_DIM, F_DIM, 8);
}

// Round 12
// 833.469 us; speedup vs baseline: 1.1466x; 1.0021x over previous
//
#include <hip/hip_runtime.h>
#include <stdint.h>

#define C_DIM 2048
#define H_NUM 16
#define DH    128
#define S_LEN 1024
#define T_LEN 256
#define B_SZ  4
#define L_ROWS 4096   // B*S
#define LY_ROWS 1024  // B*T
#define F_DIM 8192

typedef __attribute__((ext_vector_type(4))) float f32x4;
typedef __attribute__((ext_vector_type(8))) __bf16 bf16x8;
typedef __attribute__((ext_vector_type(4))) unsigned short us4;
typedef __attribute__((ext_vector_type(8))) unsigned short us8;
typedef unsigned short u16;

__device__ __forceinline__ u16 f2bf(float f) {
  union { float f; uint32_t u; } v; v.f = f;
  uint32_t r = v.u + 0x7FFFu + ((v.u >> 16) & 1u);
  return (u16)(r >> 16);
}
__device__ __forceinline__ float bf2f(u16 h) {
  union { uint32_t u; float f; } v; v.u = ((uint32_t)h) << 16;
  return v.f;
}

typedef __attribute__((address_space(1))) void gvoid;
typedef __attribute__((address_space(3))) void lvoid;
__device__ __forceinline__ void gl_lds16(const void* g, void* l) {
  __builtin_amdgcn_global_load_lds((gvoid*)g, (lvoid*)l, 16, 0, 0);
}

template<int N> __device__ __forceinline__ void wait_vmcnt() {
  if constexpr (N == 0) asm volatile("s_waitcnt vmcnt(0)" ::: "memory");
  else if constexpr (N == 4) asm volatile("s_waitcnt vmcnt(4)" ::: "memory");
  else if constexpr (N == 5) asm volatile("s_waitcnt vmcnt(5)" ::: "memory");
  else if constexpr (N == 6) asm volatile("s_waitcnt vmcnt(6)" ::: "memory");
}
__device__ __forceinline__ void barrier_raw() {
  asm volatile("s_barrier" ::: "memory");
}
__device__ __forceinline__ void lgkm0_pin() {
  asm volatile("s_waitcnt lgkmcnt(0)" ::: "memory");
  __builtin_amdgcn_sched_barrier(0);
}

__device__ __forceinline__ float gelu_fast(float val) {
  float z = 0.7978845608f * (val + 0.044715f * val * val * val);
  float e = __expf(2.f * z);
  float th = 1.f - 2.f / (e + 1.f);
  return 0.5f * val * (1.f + th);
}

// ---------------- fp32 -> bf16 conversion ----------------
__global__ void k_cvt(const float* __restrict__ src, u16* __restrict__ dst, int n) {
  int i = (blockIdx.x * blockDim.x + threadIdx.x) * 4;
  int stride = gridDim.x * blockDim.x * 4;
  for (; i < n; i += stride) {
    float4 v = *(const float4*)(src + i);
    us4 o;
    o[0] = f2bf(v.x); o[1] = f2bf(v.y); o[2] = f2bf(v.z); o[3] = f2bf(v.w);
    *(us4*)(dst + i) = o;
  }
}

// 8 C*C (2^22-elem) fp32 tensors -> one contiguous bf16 region
__global__ void k_cvt8(const float* __restrict__ s0, const float* __restrict__ s1,
                       const float* __restrict__ s2, const float* __restrict__ s3,
                       const float* __restrict__ s4, const float* __restrict__ s5,
                       const float* __restrict__ s6, const float* __restrict__ s7,
                       u16* __restrict__ dst) {
  const int PER = C_DIM * C_DIM;          // 2^22
  int i = (blockIdx.x * blockDim.x + threadIdx.x) * 4;
  int stride = gridDim.x * blockDim.x * 4;
  int total = PER * 8;
  for (; i < total; i += stride) {
    int t = i >> 22;
    const float* s;
    switch (t) {
      case 0: s = s0; break; case 1: s = s1; break;
      case 2: s = s2; break; case 3: s = s3; break;
      case 4: s = s4; break; case 5: s = s5; break;
      case 6: s = s6; break; default: s = s7; break;
    }
    float4 v = *(const float4*)(s + (i & (PER - 1)));
    us4 o;
    o[0] = f2bf(v.x); o[1] = f2bf(v.y); o[2] = f2bf(v.z); o[3] = f2bf(v.w);
    *(us4*)(dst + i) = o;
  }
}

// 2 F*C (2^24-elem) fp32 tensors -> contiguous bf16 (wfc1; wfc2)
__global__ void k_cvt2(const float* __restrict__ s0, const float* __restrict__ s1,
                       u16* __restrict__ dst) {
  const int PER = F_DIM * C_DIM;          // 2^24
  int i = (blockIdx.x * blockDim.x + threadIdx.x) * 4;
  int stride = gridDim.x * blockDim.x * 4;
  int total = PER * 2;
  for (; i < total; i += stride) {
    const float* s = (i >> 24) ? s1 : s0;
    float4 v = *(const float4*)(s + (i & (PER - 1)));
    us4 o;
    o[0] = f2bf(v.x); o[1] = f2bf(v.y); o[2] = f2bf(v.z); o[3] = f2bf(v.w);
    *(us4*)(dst + i) = o;
  }
}

// ---------------- LN + adaLN modulation (fp32 or bf16 input) ----------------
template<int INBF>
__global__ __launch_bounds__(256)
void k_modln(const void* __restrict__ xin, const float* __restrict__ t,
             const float* __restrict__ tab, u16* __restrict__ out,
             int scale_idx, int shift_idx) {
  int row = blockIdx.x;
  int tid = threadIdx.x;
  int c0 = tid * 8;
  float v[8];
  if constexpr (INBF) {
    us8 a = *(const us8*)((const u16*)xin + (size_t)row * C_DIM + c0);
#pragma unroll
    for (int j = 0; j < 8; ++j) v[j] = bf2f(a[j]);
  } else {
    const float* xr = (const float*)xin + (size_t)row * C_DIM;
    float4 a = *(const float4*)(xr + c0);
    float4 b = *(const float4*)(xr + c0 + 4);
    v[0] = a.x; v[1] = a.y; v[2] = a.z; v[3] = a.w;
    v[4] = b.x; v[5] = b.y; v[6] = b.z; v[7] = b.w;
  }
  float s = 0.f, ss = 0.f;
#pragma unroll
  for (int j = 0; j < 8; ++j) { s += v[j]; ss += v[j] * v[j]; }
#pragma unroll
  for (int m = 1; m < 64; m <<= 1) { s += __shfl_xor(s, m); ss += __shfl_xor(ss, m); }
  __shared__ float red[8];
  int wid = tid >> 6;
  if ((tid & 63) == 0) { red[wid * 2] = s; red[wid * 2 + 1] = ss; }
  __syncthreads();
  s  = red[0] + red[2] + red[4] + red[6];
  ss = red[1] + red[3] + red[5] + red[7];
  float mean = s * (1.f / C_DIM);
  float var  = ss * (1.f / C_DIM) - mean * mean;
  float rstd = rsqrtf(var + 1e-6f);
  const float* trow = t + (size_t)row * (6 * C_DIM);
  const float* tsc = trow + scale_idx * C_DIM + c0;
  const float* tsh = trow + shift_idx * C_DIM + c0;
  const float* gsc = tab + scale_idx * C_DIM + c0;
  const float* gsh = tab + shift_idx * C_DIM + c0;
  us8 o;
#pragma unroll
  for (int j = 0; j < 8; ++j) {
    float scv = 1.f + gsc[j] + tsc[j];
    float shv = gsh[j] + tsh[j];
    o[j] = f2bf((v[j] - mean) * rstd * scv + shv);
  }
  *(us8*)(out + (size_t)row * C_DIM + c0) = o;
}

// ======== GEMM v5b: 256x256 tile, BK=64, 2 K-tiles/iter, 8-phase ============
// (R8-proven ledger.) EPI 1: fast-gelu->o0.
// XCD mapping: by fast-varying (B-panel L2-resident per XCD).
template<int EPI>
__global__ __launch_bounds__(512, 2)
void k_gemm5(const u16* __restrict__ A, const u16* __restrict__ W,
             const float* __restrict__ bias0,
             u16* __restrict__ o0, int out_ld,
             int M, int N, int K, int lda, int ldw, int nby) {
  __shared__ __align__(16) u16 lds[65536];

  int tid = threadIdx.x;
  int nwg = gridDim.x;
  int q8 = nwg >> 3, r8 = nwg & 7;
  int xcd = blockIdx.x & 7, local = blockIdx.x >> 3;
  int wgid = (xcd < r8 ? xcd * (q8 + 1) : r8 * (q8 + 1) + (xcd - r8) * q8) + local;
  int by = wgid % nby, bx = wgid / nby;
  int m0 = by * 256, n0 = bx * 256;

  int wid = tid >> 6, lane = tid & 63;
  int wm = wid >> 2, wn = wid & 3;
  int lr = lane & 15, lg = lane >> 4;
  int xorslot = lr & 7;
  int bcol = (wn & 1) * 64;

  int srow = tid >> 3;
  int scol = ((tid ^ (tid >> 3)) & 7) * 8;

  auto stA = [&](int buf, int h, int kt) {
    u16* dst = lds + (buf * 2 + h) * 8192 + tid * 8;
#pragma unroll
    for (int call = 0; call < 2; ++call) {
      int grow = m0 + h * 128 + call * 64 + srow;
      gl_lds16(A + (size_t)grow * lda + kt * 64 + scol, dst + call * 4096);
    }
  };
  auto stB = [&](int buf, int h, int kt) {
    u16* dst = lds + 32768 + (buf * 2 + h) * 8192 + tid * 8;
#pragma unroll
    for (int call = 0; call < 2; ++call) {
      int grow = n0 + h * 128 + call * 64 + srow;
      gl_lds16(W + (size_t)grow * ldw + kt * 64 + scol, dst + call * 4096);
    }
  };

  f32x4 zero4 = {0.f, 0.f, 0.f, 0.f};
  f32x4 acc[8][4];
#pragma unroll
  for (int m = 0; m < 8; ++m)
#pragma unroll
    for (int n = 0; n < 4; ++n) acc[m][n] = zero4;

  int NT = K >> 6, NJ = NT >> 1;
  stA(0, 0, 0); stA(0, 1, 0); stB(0, 0, 0); stB(0, 1, 0);
  stB(1, 0, 1); stA(1, 0, 1);
  wait_vmcnt<4>();
  barrier_raw();

  for (int j = 0; j < NJ; ++j) {
    bool nlast = (j + 1 < NJ);
    int t1 = 2 * j + 1, t2 = 2 * j + 2, t3 = 2 * j + 3;
#pragma unroll
    for (int buf = 0; buf < 2; ++buf) {
      const u16* Ah = lds + (buf * 2 + wm) * 8192;
      const u16* Bh = lds + 32768 + (buf * 2 + (wn >> 1)) * 8192;
      bf16x8 aR[4][2], b0[2][2], b1[2][2];

#pragma unroll
      for (int m = 0; m < 4; ++m) {
        int r = m * 16 + lr;
#pragma unroll
        for (int kk = 0; kk < 2; ++kk)
          aR[m][kk] = *(const bf16x8*)(Ah + r * 64 + (((kk << 2) | lg) ^ xorslot) * 8);
      }
#pragma unroll
      for (int n = 0; n < 2; ++n) {
        int r = bcol + n * 16 + lr;
#pragma unroll
        for (int kk = 0; kk < 2; ++kk)
          b0[n][kk] = *(const bf16x8*)(Bh + r * 64 + (((kk << 2) | lg) ^ xorslot) * 8);
      }
      if (buf == 0) stA(1, 1, t1);
      else if (nlast) stA(0, 1, t2);
      barrier_raw();
      lgkm0_pin();
      __builtin_amdgcn_s_setprio(1);
#pragma unroll
      for (int kk = 0; kk < 2; ++kk)
#pragma unroll
        for (int m = 0; m < 4; ++m)
#pragma unroll
          for (int n = 0; n < 2; ++n)
            acc[m][n] = __builtin_amdgcn_mfma_f32_16x16x32_bf16(aR[m][kk], b0[n][kk], acc[m][n], 0, 0, 0);
      __builtin_amdgcn_s_setprio(0);
      barrier_raw();

#pragma unroll
      for (int n = 0; n < 2; ++n) {
        int r = bcol + 32 + n * 16 + lr;
#pragma unroll
        for (int kk = 0; kk < 2; ++kk)
          b1[n][kk] = *(const bf16x8*)(Bh + r * 64 + (((kk << 2) | lg) ^ xorslot) * 8);
      }
      if (buf == 0) stB(1, 1, t1);
      else if (nlast) stB(0, 1, t2);
      barrier_raw();
      lgkm0_pin();
      __builtin_amdgcn_s_setprio(1);
#pragma unroll
      for (int kk = 0; kk < 2; ++kk)
#pragma unroll
        for (int m = 0; m < 4; ++m)
#pragma unroll
          for (int n = 0; n < 2; ++n)
            acc[m][2 + n] = __builtin_amdgcn_mfma_f32_16x16x32_bf16(aR[m][kk], b1[n][kk], acc[m][2 + n], 0, 0, 0);
      __builtin_amdgcn_s_setprio(0);
      barrier_raw();

#pragma unroll
      for (int m = 0; m < 4; ++m) {
        int r = 64 + m * 16 + lr;
#pragma unroll
        for (int kk = 0; kk < 2; ++kk)
          aR[m][kk] = *(const bf16x8*)(Ah + r * 64 + (((kk << 2) | lg) ^ xorslot) * 8);
      }
      if (nlast) { if (buf == 0) stB(0, 0, t2); else stB(1, 0, t3); }
      barrier_raw();
      lgkm0_pin();
      __builtin_amdgcn_s_setprio(1);
#pragma unroll
      for (int kk = 0; kk < 2; ++kk)
#pragma unroll
        for (int m = 0; m < 4; ++m)
#pragma unroll
          for (int n = 0; n < 2; ++n)
            acc[4 + m][2 + n] = __builtin_amdgcn_mfma_f32_16x16x32_bf16(aR[m][kk], b1[n][kk], acc[4 + m][2 + n], 0, 0, 0);
      __builtin_amdgcn_s_setprio(0);
      barrier_raw();

      if (nlast) { if (buf == 0) stA(0, 0, t2); else stA(1, 0, t3); }
      barrier_raw();
      __builtin_amdgcn_s_setprio(1);
#pragma unroll
      for (int kk = 0; kk < 2; ++kk)
#pragma unroll
        for (int m = 0; m < 4; ++m)
#pragma unroll
          for (int n = 0; n < 2; ++n)
            acc[4 + m][n] = __builtin_amdgcn_mfma_f32_16x16x32_bf16(aR[m][kk], b0[n][kk], acc[4 + m][n], 0, 0, 0);
      __builtin_amdgcn_s_setprio(0);
      if (nlast) wait_vmcnt<4>(); else wait_vmcnt<0>();
      barrier_raw();
    }
  }

#pragma unroll
  for (int mf = 0; mf < 8; ++mf) {
    int row0 = m0 + wm * 128 + mf * 16 + lg * 4;
#pragma unroll
    for (int nf = 0; nf < 4; ++nf) {
      int col = n0 + wn * 64 + nf * 16 + lr;
      float bv = bias0[col];
#pragma unroll
      for (int r = 0; r < 4; ++r)
        o0[(size_t)(row0 + r) * out_ld + col] = f2bf(gelu_fast(acc[mf][nf][r] + bv));
    }
  }
}

// ======== GEMM v3c: BMx256, BK=64, 4-phase, 3-bit swizzle (R5-proven) ======
// XCD mapping: by fast-varying (B-panel L2-resident per XCD).
// EPI 0: bf16(acc+bias)->o{0,1,2} split by col>>sec_shift
// EPI 6: o0 = bf16(residF + gate*(acc+bias))              (wo_s -> x1bf)
// EPI 7: o0 = bf16(bf2f(o0) + acc + bias)  in-place RMW   (wo_c)
// EPI 8: outF = bf2f(o1[idx]) + gate*(acc+bias)           (fc2 final fp32)
// EPI 9: fused QKV: q,k -> rope (freqs via gate_t); v -> o2 transposed
// EPI 10: fused cross-KV: k -> o0; v -> o1 transposed (Lkv=256)
template<int BM, int EPI>
__global__ __launch_bounds__(512, 2)
void k_gemm3(const u16* __restrict__ A, const u16* __restrict__ W,
             const float* __restrict__ bias0, const float* __restrict__ bias1,
             const float* __restrict__ bias2,
             u16* __restrict__ o0, u16* __restrict__ o1, u16* __restrict__ o2,
             int sec_shift, int out_ld,
             float* __restrict__ outF, const float* __restrict__ resid,
             const float* __restrict__ gate_t, const float* __restrict__ gate_tab,
             int M, int N, int K, int lda, int ldw, int nby) {
  constexpr int HTA = (BM / 2) * 64;
  constexpr int HTB = 128 * 64;
  constexpr int ACALLS = BM / 128;
  constexpr int QM = BM / 64;
  constexpr int MFR = BM / 32;
  constexpr int VMN = 4 + ACALLS;
  constexpr int BOFF = 4 * HTA;
  __shared__ __align__(16) u16 lds[BOFF + 4 * HTB];

  int tid = threadIdx.x;
  int nwg = gridDim.x;
  int q8 = nwg >> 3, r8 = nwg & 7;
  int xcd = blockIdx.x & 7, local = blockIdx.x >> 3;
  int wgid = (xcd < r8 ? xcd * (q8 + 1) : r8 * (q8 + 1) + (xcd - r8) * q8) + local;
  int by = wgid % nby, bx = wgid / nby;
  int m0 = by * BM, n0 = bx * 256;

  int wid = tid >> 6, lane = tid & 63;
  int wm = wid >> 2, wn = wid & 3;
  int lr = lane & 15, lg = lane >> 4;
  int xorslot = lr & 7;
  int bcol = (wn & 1) * 64;

  int srow = tid >> 3;
  int scol = ((tid ^ (tid >> 3)) & 7) * 8;

  auto stA = [&](int h, int kt2) {
    int pt = kt2 & 1;
    u16* dst = lds + (pt * 2 + h) * HTA + tid * 8;
#pragma unroll
    for (int call = 0; call < ACALLS; ++call) {
      int grow = m0 + h * (BM / 2) + call * 64 + srow;
      gl_lds16(A + (size_t)grow * lda + kt2 * 64 + scol, dst + call * 4096);
    }
  };
  auto stB = [&](int h, int kt2) {
    int pt = kt2 & 1;
    u16* dst = lds + BOFF + (pt * 2 + h) * HTB + tid * 8;
#pragma unroll
    for (int call = 0; call < 2; ++call) {
      int grow = n0 + h * 128 + call * 64 + srow;
      gl_lds16(W + (size_t)grow * ldw + kt2 * 64 + scol, dst + call * 4096);
    }
  };

  f32x4 zero4 = {0.f, 0.f, 0.f, 0.f};
  f32x4 acc[MFR][4];
#pragma unroll
  for (int m = 0; m < MFR; ++m)
#pragma unroll
    for (int n = 0; n < 4; ++n) acc[m][n] = zero4;

  int NT2 = K >> 6;
  stA(0, 0); stA(1, 0); stB(0, 0); stB(1, 0);
  stB(0, 1); stB(1, 1); stA(0, 1);
  wait_vmcnt<VMN>();
  barrier_raw();

  for (int kt = 0; kt < NT2; ++kt) {
    int p = kt & 1;
    const u16* Ah = lds + (p * 2 + wm) * HTA;
    const u16* Bh = lds + BOFF + (p * 2 + (wn >> 1)) * HTB;
    bf16x8 aR[QM][2], bR0[2][2], bR1[2][2];
    bool st1 = (kt + 1) < NT2, st2 = (kt + 2) < NT2;

#pragma unroll
    for (int m = 0; m < QM; ++m) {
      int r = m * 16 + lr;
#pragma unroll
      for (int kk = 0; kk < 2; ++kk)
        aR[m][kk] = *(const bf16x8*)(Ah + r * 64 + (((kk << 2) | lg) ^ xorslot) * 8);
    }
#pragma unroll
    for (int n = 0; n < 2; ++n) {
      int r = bcol + n * 16 + lr;
#pragma unroll
      for (int kk = 0; kk < 2; ++kk)
        bR0[n][kk] = *(const bf16x8*)(Bh + r * 64 + (((kk << 2) | lg) ^ xorslot) * 8);
    }
    if (st1) stA(1, kt + 1);
    lgkm0_pin();
    __builtin_amdgcn_s_setprio(1);
#pragma unroll
    for (int kk = 0; kk < 2; ++kk)
#pragma unroll
      for (int m = 0; m < QM; ++m)
#pragma unroll
        for (int n = 0; n < 2; ++n)
          acc[m][n] = __builtin_amdgcn_mfma_f32_16x16x32_bf16(aR[m][kk], bR0[n][kk], acc[m][n], 0, 0, 0);
    __builtin_amdgcn_s_setprio(0);
    barrier_raw();

#pragma unroll
    for (int n = 0; n < 2; ++n) {
      int r = bcol + 32 + n * 16 + lr;
#pragma unroll
      for (int kk = 0; kk < 2; ++kk)
        bR1[n][kk] = *(const bf16x8*)(Bh + r * 64 + (((kk << 2) | lg) ^ xorslot) * 8);
    }
    lgkm0_pin();
    __builtin_amdgcn_s_setprio(1);
#pragma unroll
    for (int kk = 0; kk < 2; ++kk)
#pragma unroll
      for (int m = 0; m < QM; ++m)
#pragma unroll
        for (int n = 0; n < 2; ++n)
          acc[m][2 + n] = __builtin_amdgcn_mfma_f32_16x16x32_bf16(aR[m][kk], bR1[n][kk], acc[m][2 + n], 0, 0, 0);
    __builtin_amdgcn_s_setprio(0);
    barrier_raw();

#pragma unroll
    for (int m = 0; m < QM; ++m) {
      int r = (BM / 4) + m * 16 + lr;
#pragma unroll
      for (int kk = 0; kk < 2; ++kk)
        aR[m][kk] = *(const bf16x8*)(Ah + r * 64 + (((kk << 2) | lg) ^ xorslot) * 8);
    }
    if (st2) { stB(0, kt + 2); stB(1, kt + 2); }
    lgkm0_pin();
    __builtin_amdgcn_s_setprio(1);
#pragma unroll
    for (int kk = 0; kk < 2; ++kk)
#pragma unroll
      for (int m = 0; m < QM; ++m)
#pragma unroll
        for (int n = 0; n < 2; ++n)
          acc[QM + m][2 + n] = __builtin_amdgcn_mfma_f32_16x16x32_bf16(aR[m][kk], bR1[n][kk], acc[QM + m][2 + n], 0, 0, 0);
    __builtin_amdgcn_s_setprio(0);
    barrier_raw();

    if (st2) stA(0, kt + 2);
    __builtin_amdgcn_s_setprio(1);
#pragma unroll
    for (int kk = 0; kk < 2; ++kk)
#pragma unroll
      for (int m = 0; m < QM; ++m)
#pragma unroll
        for (int n = 0; n < 2; ++n)
          acc[QM + m][n] = __builtin_amdgcn_mfma_f32_16x16x32_bf16(aR[m][kk], bR0[n][kk], acc[QM + m][n], 0, 0, 0);
    __builtin_amdgcn_s_setprio(0);
    if (st2) wait_vmcnt<VMN>(); else wait_vmcnt<0>();
    barrier_raw();
  }

  // ---- epilogue ----
#pragma unroll
  for (int mf = 0; mf < MFR; ++mf) {
    int row0 = m0 + wm * (BM / 2) + mf * 16 + lg * 4;
#pragma unroll
    for (int nf = 0; nf < 4; ++nf) {
      int col = n0 + wn * 64 + nf * 16 + lr;
      if constexpr (EPI == 0) {
        int sec = col >> sec_shift;
        const float* bp = sec == 0 ? bias0 : (sec == 1 ? bias1 : bias2);
        u16* op = sec == 0 ? o0 : (sec == 1 ? o1 : o2);
        int cs = col & ((1 << sec_shift) - 1);
        float bv = bp[cs];
#pragma unroll
        for (int r = 0; r < 4; ++r)
          op[(size_t)(row0 + r) * out_ld + cs] = f2bf(acc[mf][nf][r] + bv);
      } else if constexpr (EPI == 6) {
        float bv = bias0[col];
        float gt = gate_tab[col];
#pragma unroll
        for (int r = 0; r < 4; ++r) {
          int row = row0 + r;
          size_t idx = (size_t)row * N + col;
          float g = gt + gate_t[(size_t)row * (6 * C_DIM) + col];
          o0[idx] = f2bf(resid[idx] + g * (acc[mf][nf][r] + bv));
        }
      } else if constexpr (EPI == 7) {
        float bv = bias0[col];
#pragma unroll
        for (int r = 0; r < 4; ++r) {
          size_t idx = (size_t)(row0 + r) * N + col;
          o0[idx] = f2bf(bf2f(o0[idx]) + acc[mf][nf][r] + bv);
        }
      } else if constexpr (EPI == 8) {
        float bv = bias0[col];
        float gt = gate_tab[col];
#pragma unroll
        for (int r = 0; r < 4; ++r) {
          int row = row0 + r;
          size_t idx = (size_t)row * N + col;
          float g = gt + gate_t[(size_t)row * (6 * C_DIM) + col];
          outF[idx] = bf2f(((const u16*)o1)[idx]) + g * (acc[mf][nf][r] + bv);
        }
      } else if constexpr (EPI == 9) {
        // fused QKV: sec 0=q(rope), 1=k(rope), 2=v(transposed store)
        int sec = col >> 11;            // wave-uniform (col spans 16)
        int cs = col & 2047;
        const float* bp = sec == 0 ? bias0 : (sec == 1 ? bias1 : bias2);
        float bv = bp[cs];
        if (sec < 2) {
          u16* op = sec == 0 ? o0 : o1;
          int i0 = (cs & (DH - 1)) >> 1;
          bool even = (cs & 1) == 0;
#pragma unroll
          for (int r = 0; r < 4; ++r) {
            float val = acc[mf][nf][r] + bv;
            float pv = __shfl_xor(val, 1);  // pair partner (col^1) = lane^1
            int sr = (row0 + r) & (S_LEN - 1);
            float ang = gate_t[sr * (DH / 2) + i0];   // gate_t carries freqs
            float sn, csn;
            __sincosf(ang, &sn, &csn);
            float outv = even ? (val * csn - pv * sn) : (pv * sn + val * csn);
            op[(size_t)(row0 + r) * out_ld + cs] = f2bf(outv);
          }
        } else {
          int h = cs >> 7, d = cs & (DH - 1);
#pragma unroll
          for (int r = 0; r < 4; ++r) {
            int row = row0 + r;
            int b = row >> 10, kv = row & (S_LEN - 1);
            o2[(((size_t)(b * H_NUM + h) * DH + d) << 10) + kv] =
                f2bf(acc[mf][nf][r] + bv);
          }
        }
      } else {  // EPI == 10: fused cross-KV: sec 0=k, 1=v(transposed, Lkv=256)
        int sec = col >> 11;
        int cs = col & 2047;
        float bv = (sec == 0 ? bias0 : bias1)[cs];
        if (sec == 0) {
#pragma unroll
          for (int r = 0; r < 4; ++r)
            o0[(size_t)(row0 + r) * out_ld + cs] = f2bf(acc[mf][nf][r] + bv);
        } else {
          int h = cs >> 7, d = cs & (DH - 1);
#pragma unroll
          for (int r = 0; r < 4; ++r) {
            int row = row0 + r;
            int b = row >> 8, kv = row & (T_LEN - 1);
            o1[(((size_t)(b * H_NUM + h) * DH + d) << 8) + kv] =
                f2bf(acc[mf][nf][r] + bv);
          }
        }
      }
    }
  }
}

// ---------------- flash attention (scale pre-folded with log2e) ------------
__global__ __launch_bounds__(256)
void k_flash(const u16* __restrict__ Q, const u16* __restrict__ K,
             const u16* __restrict__ Vt, u16* __restrict__ O,
             int Lq, int Lkv, float scale2) {
  __shared__ __align__(16) u16 lK[64 * 128];
  __shared__ __align__(16) u16 lV[128 * 64];
  __shared__ __align__(16) u16 lP[4][16 * 72];
  int bh = blockIdx.x, b = bh >> 4, h = bh & 15;
  int tid = threadIdx.x, wid = tid >> 6, lane = tid & 63;
  int lr = lane & 15, lg = lane >> 4;
  int q0 = blockIdx.y * 64 + wid * 16;
  const u16* Qb = Q + ((size_t)(b * Lq) + q0) * C_DIM + h * DH;
  const u16* Kb = K + (size_t)(b * Lkv) * C_DIM + h * DH;
  const u16* Vb = Vt + (size_t)bh * DH * Lkv;

  bf16x8 qf[4];
#pragma unroll
  for (int ks = 0; ks < 4; ++ks)
    qf[ks] = *(const bf16x8*)(Qb + (size_t)lr * C_DIM + ks * 32 + lg * 8);

  f32x4 zero4 = {0.f, 0.f, 0.f, 0.f};
  f32x4 o[8];
#pragma unroll
  for (int n = 0; n < 8; ++n) o[n] = zero4;
  float mrow[4] = {-3.0e38f, -3.0e38f, -3.0e38f, -3.0e38f};
  float lrow[4] = {0.f, 0.f, 0.f, 0.f};

  int nsteps = Lkv >> 6;
  for (int kt = 0; kt < nsteps; ++kt) {
#pragma unroll
    for (int i = 0; i < 4; ++i) {
      int flat = i * 4096 + tid * 16;
      int key = flat >> 8, inner = flat & 255;
      int ksrc = inner ^ ((key & 7) << 4);
      gl_lds16((const char*)Kb + ((size_t)(kt * 64 + key) * C_DIM) * 2 + ksrc, (char*)lK + flat);
      int d = flat >> 7, keyb = flat & 127;
      int vsrc = keyb ^ ((d & 7) << 4);
      gl_lds16((const char*)Vb + ((size_t)d * Lkv) * 2 + kt * 128 + vsrc, (char*)lV + flat);
    }
    __syncthreads();

    f32x4 sc[4];
#pragma unroll
    for (int c = 0; c < 4; ++c) sc[c] = zero4;
#pragma unroll
    for (int c = 0; c < 4; ++c) {
      int key = c * 16 + lr;
#pragma unroll
      for (int ks = 0; ks < 4; ++ks) {
        int off = (ks * 64 + lg * 16) ^ ((key & 7) << 4);
        bf16x8 kf = *(const bf16x8*)((const char*)lK + key * 256 + off);
        sc[c] = __builtin_amdgcn_mfma_f32_16x16x32_bf16(qf[ks], kf, sc[c], 0, 0, 0);
      }
    }
#pragma unroll
    for (int r = 0; r < 4; ++r) {
      float s0 = sc[0][r] * scale2, s1 = sc[1][r] * scale2;
      float s2 = sc[2][r] * scale2, s3 = sc[3][r] * scale2;
      float mx = fmaxf(fmaxf(s0, s1), fmaxf(s2, s3));
#pragma unroll
      for (int m = 1; m < 16; m <<= 1) mx = fmaxf(mx, __shfl_xor(mx, m));
      float mnew = fmaxf(mrow[r], mx);
      float alpha = exp2f(mrow[r] - mnew);
      mrow[r] = mnew;
      float p0 = exp2f(s0 - mnew);
      float p1 = exp2f(s1 - mnew);
      float p2 = exp2f(s2 - mnew);
      float p3 = exp2f(s3 - mnew);
      float psum = p0 + p1 + p2 + p3;
#pragma unroll
      for (int m = 1; m < 16; m <<= 1) psum += __shfl_xor(psum, m);
      lrow[r] = lrow[r] * alpha + psum;
#pragma unroll
      for (int n = 0; n < 8; ++n) o[n][r] *= alpha;
      u16* pr = lP[wid] + (4 * lg + r) * 72;
      pr[lr]      = f2bf(p0);
      pr[16 + lr] = f2bf(p1);
      pr[32 + lr] = f2bf(p2);
      pr[48 + lr] = f2bf(p3);
    }
    asm volatile("s_waitcnt lgkmcnt(0)" ::: "memory");
    __builtin_amdgcn_sched_barrier(0);
#pragma unroll
    for (int half = 0; half < 2; ++half) {
      bf16x8 pf = *(const bf16x8*)(lP[wid] + lr * 72 + half * 32 + lg * 8);
#pragma unroll
      for (int n = 0; n < 8; ++n) {
        int d = n * 16 + lr;
        int off = (half * 64 + lg * 16) ^ ((d & 7) << 4);
        bf16x8 vf = *(const bf16x8*)((const char*)lV + d * 128 + off);
        o[n] = __builtin_amdgcn_mfma_f32_16x16x32_bf16(pf, vf, o[n], 0, 0, 0);
      }
    }
    __syncthreads();
  }

  u16* Ob = O + ((size_t)(b * Lq) + q0) * C_DIM + h * DH;
#pragma unroll
  for (int n = 0; n < 8; ++n) {
    int d = n * 16 + lr;
#pragma unroll
    for (int r = 0; r < 4; ++r) {
      int qr = 4 * lg + r;
      Ob[(size_t)qr * C_DIM + d] = f2bf(o[n][r] / lrow[r]);
    }
  }
}

// ---------------- host ----------------
extern "C" void kernel_launch(void* const* d_in, const int* in_sizes, int n_in,
                              void* d_out, int out_size, void* d_ws, size_t ws_size,
                              hipStream_t stream) {
  const float* x     = (const float*)d_in[0];
  const float* y     = (const float*)d_in[1];
  const float* t     = (const float*)d_in[2];
  const float* freqs = (const float*)d_in[3];
  const float* tab   = (const float*)d_in[4];
  const float* Wq_s = (const float*)d_in[5];
  const float* bq_s = (const float*)d_in[6];
  const float* Wk_s = (const float*)d_in[7];
  const float* bk_s = (const float*)d_in[8];
  const float* Wv_s = (const float*)d_in[9];
  const float* bv_s = (const float*)d_in[10];
  const float* Wo_s = (const float*)d_in[11];
  const float* bo_s = (const float*)d_in[12];
  const float* Wq_c = (const float*)d_in[13];
  const float* bq_c = (const float*)d_in[14];
  const float* Wk_c = (const float*)d_in[15];
  const float* bk_c = (const float*)d_in[16];
  const float* Wv_c = (const float*)d_in[17];
  const float* bv_c = (const float*)d_in[18];
  const float* Wo_c = (const float*)d_in[19];
  const float* bo_c = (const float*)d_in[20];
  const float* W_fc1 = (const float*)d_in[21];
  const float* b_fc1 = (const float*)d_in[22];
  const float* W_fc2 = (const float*)d_in[23];
  const float* b_fc2 = (const float*)d_in[24];

  const size_t SZ_CC  = (size_t)C_DIM * C_DIM * 2;
  const size_t SZ_FC  = (size_t)F_DIM * C_DIM * 2;
  const size_t SZ_LC  = (size_t)L_ROWS * C_DIM * 2;
  const size_t SZ_YC  = (size_t)LY_ROWS * C_DIM * 2;
  char* ws = (char*)d_ws;
  size_t off = 0;
  u16* wq_s = (u16*)(ws + off); off += SZ_CC;   // wq_s..wo_c contiguous (8 tensors)
  u16* wk_s = (u16*)(ws + off); off += SZ_CC;
  u16* wv_s = (u16*)(ws + off); off += SZ_CC;
  u16* wo_s = (u16*)(ws + off); off += SZ_CC;
  u16* wq_c = (u16*)(ws + off); off += SZ_CC;
  u16* wk_c = (u16*)(ws + off); off += SZ_CC;
  u16* wv_c = (u16*)(ws + off); off += SZ_CC;
  u16* wo_c = (u16*)(ws + off); off += SZ_CC;
  u16* wfc1 = (u16*)(ws + off); off += SZ_FC;   // wfc1,wfc2 contiguous
  u16* wfc2 = (u16*)(ws + off); off += SZ_FC;
  u16* ybf  = (u16*)(ws + off); off += SZ_YC;
  u16* xm   = (u16*)(ws + off); off += SZ_LC;
  u16* qb   = (u16*)(ws + off); off += SZ_LC;
  u16* kb   = (u16*)(ws + off); off += SZ_LC;
  u16* vb   = (u16*)(ws + off); off += SZ_LC;   // reserved (hbuf overlay)
  u16* ao   = (u16*)(ws + off); off += SZ_LC;
  u16* hbuf = qb;                               // [L, F] bf16 overlay (qb..ao)
  u16* x1bf = (u16*)(ws + off); off += SZ_LC;   // bf16 residual stream
  u16* kc   = (u16*)(ws + off); off += SZ_YC;
  u16* vc   = (u16*)(ws + off); off += SZ_YC;   // reserved
  u16* vt   = (u16*)(ws + off); off += SZ_LC;
  u16* vtc  = (u16*)(ws + off); off += SZ_YC;
  if (ws_size < off) return;
  (void)vb; (void)vc;

  // fused weight conversions: 3 launches
  k_cvt8<<<4096, 256, 0, stream>>>(Wq_s, Wk_s, Wv_s, Wo_s, Wq_c, Wk_c, Wv_c, Wo_c, wq_s);
  k_cvt2<<<4096, 256, 0, stream>>>(W_fc1, W_fc2, wfc1);
  k_cvt<<<2048, 256, 0, stream>>>(y, ybf, LY_ROWS * C_DIM);

  const float ascale2 = 0.08838834764831845f * 1.44269504f;  // 1/sqrt(128)*log2e

  k_modln<0><<<L_ROWS, 256, 0, stream>>>(x, t, tab, xm, 1, 0);
  // fused self QKV + rope + V-transpose: N = 6144 (nby=32)
  k_gemm3<128, 9><<<32 * 24, 512, 0, stream>>>(
      xm, wq_s, bq_s, bk_s, bv_s, qb, kb, vt, 11, C_DIM,
      nullptr, nullptr, freqs, nullptr, L_ROWS, 6144, C_DIM, C_DIM, C_DIM, 32);
  k_flash<<<dim3(B_SZ * H_NUM, S_LEN / 64), 256, 0, stream>>>(qb, kb, vt, ao, S_LEN, S_LEN, ascale2);
  // x1bf = bf16(x + gate_msa*(ao@Wo_s^T+bo_s))
  k_gemm3<128, 6><<<32 * 8, 512, 0, stream>>>(
      ao, wo_s, bo_s, nullptr, nullptr, x1bf, nullptr, nullptr, 30, C_DIM,
      nullptr, x, t + 2 * C_DIM, tab + 2 * C_DIM, L_ROWS, C_DIM, C_DIM, C_DIM, C_DIM, 32);
  // cross q (no rope)
  k_gemm3<128, 0><<<32 * 8, 512, 0, stream>>>(
      x1bf, wq_c, bq_c, nullptr, nullptr, qb, nullptr, nullptr, 30, C_DIM,
      nullptr, nullptr, nullptr, nullptr, L_ROWS, C_DIM, C_DIM, C_DIM, C_DIM, 32);
  // fused cross KV + V-transpose: N = 4096 (nby=8)
  k_gemm3<128, 10><<<8 * 16, 512, 0, stream>>>(
      ybf, wk_c, bk_c, bv_c, nullptr, kc, vtc, nullptr, 11, C_DIM,
      nullptr, nullptr, nullptr, nullptr, LY_ROWS, 4096, C_DIM, C_DIM, C_DIM, 8);
  k_flash<<<dim3(B_SZ * H_NUM, S_LEN / 64), 256, 0, stream>>>(qb, kc, vtc, ao, S_LEN, T_LEN, ascale2);
  // x1bf += ao@Wo_c^T + bo_c  (in-place bf16 RMW)
  k_gemm3<128, 7><<<32 * 8, 512, 0, stream>>>(
      ao, wo_c, bo_c, nullptr, nullptr, x1bf, nullptr, nullptr, 30, C_DIM,
      nullptr, nullptr, nullptr, nullptr, L_ROWS, C_DIM, C_DIM, C_DIM, C_DIM, 32);
  // MLP
  k_modln<1><<<L_ROWS, 256, 0, stream>>>(x1bf, t, tab, xm, 4, 3);
  k_gemm5<1><<<16 * 32, 512, 0, stream>>>(
      xm, wfc1, b_fc1, hbuf, F_DIM, L_ROWS, F_DIM, C_DIM, C_DIM, C_DIM, 16);
  // fc2 final: d_out = x1bf + gate_mlp*(h@W_fc2^T + b_fc2)  (fp32 out)
  k_gemm3<128, 8><<<32 * 8, 512, 0, stream>>>(
      hbuf, wfc2, b_fc2, nullptr, nullptr, nullptr, x1bf, nullptr, 30, C_DIM,
      (float*)d_out, nullptr, t + 5 * C_DIM, tab + 5 * C_DIM, L_ROWS, C_DIM, F_DIM, F_DIM, F_DIM, 32);
}